// Round 3
// baseline (195.155 us; speedup 1.0000x reference)
//
#include <hip/hip_runtime.h>
#include <math.h>

#define B_ 4
#define C_ 256
#define N_ 4096   // H*W
#define LDE 132   // ET row stride (ushorts); 66 dwords ≡ 2 mod 32 — same bank algebra as verified 68
#define LDX 72    // prep LDS tile stride (ushorts)

typedef __attribute__((ext_vector_type(8))) short short8;
typedef __attribute__((ext_vector_type(4))) float f32x4;

__device__ inline ushort f2bf(float f) {
    uint u = __float_as_uint(f);
    return (ushort)((u + 0x7fffu + ((u >> 16) & 1u)) >> 16);   // RNE
}
__device__ inline float bf2f(ushort h) { return __uint_as_float(((uint)h) << 16); }

__device__ inline f32x4 mfma16(short8 a, short8 b, f32x4 c) {
    return __builtin_amdgcn_mfma_f32_16x16x32_bf16(a, b, c, 0, 0, 0);
}
__device__ inline f32x4 mfma8(long a, long b, f32x4 c) {
    return __builtin_amdgcn_mfma_f32_16x16x32_fp8_fp8(a, b, c, 0, 0, 0);
}

// Fragment-order layouts (lane l <-> (row l&15, k-group l>>4)):
//   xfrag8[b][nt=0..255][kk=0..7][lane][8 fp8]      (X = fp8(fm+fd), k=c, 512 B/tile)
//   ffrag [b][nc=0..63][ct=0..15][k2=0..1][lane][8] (Fd bf16, k=n within chunk)
__device__ inline size_t xfi8(int b, int nt, int kk) {   // BYTE offset
    return (((size_t)(b * 256 + nt)) * 8 + kk) * 512;
}
__device__ inline size_t ffi(int b, int nc, int ct, int k2) {   // ushort offset
    return ((((size_t)(b * 64 + nc)) * 16 + ct) * 2 + k2) * 512;
}

// ---------------------------------------------------------------------------
// P0: build xfrag8 (fp8, MFMA-native) + ffrag (bf16) + dg (diag shift, fused).
// ---------------------------------------------------------------------------
__global__ __launch_bounds__(256) void prep_kernel(const float* __restrict__ fm,
                                                   const float* __restrict__ fd,
                                                   uchar* __restrict__ xfrag8,
                                                   ushort* __restrict__ ffrag,
                                                   float* __restrict__ dg) {
    __shared__ ushort xl[64][LDX];   // [c-local][n-local] bf16 X
    __shared__ ushort fl[64][LDX];   // [c-local][n-local] bf16 Fd
    const int b = blockIdx.z, c0 = blockIdx.y * 64, n0 = blockIdx.x * 64;
    const int t = threadIdx.x;
    const int n4 = (t & 15) * 4, cl = t >> 4;
    const size_t base = (size_t)b * C_ * N_;
    float dsum[4] = {0.f, 0.f, 0.f, 0.f};
    #pragma unroll
    for (int p = 0; p < 4; ++p) {
        const int cr = 16 * p + cl;
        const float4 m4 = *(const float4*)(fm + base + (size_t)(c0 + cr) * N_ + n0 + n4);
        const float4 d4 = *(const float4*)(fd + base + (size_t)(c0 + cr) * N_ + n0 + n4);
        ushort4 fo;
        fo.x = f2bf(d4.x); fo.y = f2bf(d4.y); fo.z = f2bf(d4.z); fo.w = f2bf(d4.w);
        *(ushort4*)(&fl[cr][n4]) = fo;
        ushort4 xo;
        xo.x = f2bf(m4.x + d4.x); xo.y = f2bf(m4.y + d4.y);
        xo.z = f2bf(m4.z + d4.z); xo.w = f2bf(m4.w + d4.w);
        *(ushort4*)(&xl[cr][n4]) = xo;
        float r0 = bf2f(xo.x), r1 = bf2f(xo.y), r2 = bf2f(xo.z), r3 = bf2f(xo.w);
        dsum[0] = fmaf(r0, r0, dsum[0]); dsum[1] = fmaf(r1, r1, dsum[1]);
        dsum[2] = fmaf(r2, r2, dsum[2]); dsum[3] = fmaf(r3, r3, dsum[3]);
    }
    #pragma unroll
    for (int j = 0; j < 4; ++j) {
        dsum[j] += __shfl_xor(dsum[j], 16, 64);
        dsum[j] += __shfl_xor(dsum[j], 32, 64);
    }
    if (((t >> 4) & 3) == 0) {
        #pragma unroll
        for (int j = 0; j < 4; ++j)
            atomicAdd(dg + b * N_ + n0 + n4 + j, dsum[j]);
    }
    __syncthreads();
    const int l = t & 63, tl = t >> 6;     // tl = local tile index 0..3
    {   // xfrag8: lane l <- n-row 16*tl+(l&15), c bytes 32*kk+8*(l>>4), fp8 pack
        const int nl = 16 * tl + (l & 15);
        #pragma unroll
        for (int j = 0; j < 2; ++j) {
            const int kk = (c0 >> 5) + j;
            const int cb = 32 * j + 8 * (l >> 4);
            float f[8];
            #pragma unroll
            for (int i = 0; i < 8; ++i) f[i] = bf2f(xl[cb + i][nl]);
            int d0 = __builtin_amdgcn_cvt_pk_fp8_f32(f[0], f[1], 0, 0);
            d0 = __builtin_amdgcn_cvt_pk_fp8_f32(f[2], f[3], d0, 1);
            int d1 = __builtin_amdgcn_cvt_pk_fp8_f32(f[4], f[5], 0, 0);
            d1 = __builtin_amdgcn_cvt_pk_fp8_f32(f[6], f[7], d1, 1);
            uint* dst = (uint*)(xfrag8 + xfi8(b, (n0 >> 4) + tl, kk) + (size_t)l * 8);
            dst[0] = (uint)d0; dst[1] = (uint)d1;
        }
    }
    {   // ffrag: lane l <- c-row 16*tl+(l&15), n ushorts 32*k2+8*(l>>4)
        const int row = 16 * tl + (l & 15);
        #pragma unroll
        for (int k2 = 0; k2 < 2; ++k2) {
            const int col = 32 * k2 + 8 * (l >> 4);
            const ushort4 a0 = *(const ushort4*)(&fl[row][col]);
            const ushort4 a1 = *(const ushort4*)(&fl[row][col + 4]);
            ushort* dst = ffrag + ffi(b, n0 >> 6, (c0 >> 4) + tl, k2) + l * 8;
            *(ushort4*)(dst) = a0; *(ushort4*)(dst + 4) = a1;
        }
    }
}

// ---------------------------------------------------------------------------
// K2 v2: lg[n] = dg[n] + log( sum_m exp(S[n,m]-dg[n]) ).  FP8 Gram, zero dup.
// 1024 thr (16 waves, 4/SIMD — 2x latency hiding vs round-0), grid 256.
// Wave holds ALL 64 n-rows' A-frags persistent and owns m-stream w: 16
// distinct streams, 256 m per block-iter, 16 iters, no loop barriers,
// bn 1-ahead rotation. ILP unchanged (4 chains of 8).
// ---------------------------------------------------------------------------
__global__ __launch_bounds__(1024, 4) void lsum_kernel(const uchar* __restrict__ xfrag8,
                                                       const float* __restrict__ dg,
                                                       float* __restrict__ lg) {
    __shared__ float red[16][64];
    const int bid = blockIdx.x;
    const int b = (bid >> 1) & 3;
    const int n0 = ((((bid >> 3) << 1) | (bid & 1))) * 64;
    const int t = threadIdx.x, lane = t & 63, w = t >> 6;   // w 0..15
    const int l15 = lane & 15, q = lane >> 4;

    long af[4][8];
    #pragma unroll
    for (int ns = 0; ns < 4; ++ns)
        #pragma unroll
        for (int kk = 0; kk < 8; ++kk)
            af[ns][kk] = *(const long*)(xfrag8 + xfi8(b, (n0 >> 4) + ns, kk) + (size_t)lane * 8);
    float dv[4][4];
    #pragma unroll
    for (int ns = 0; ns < 4; ++ns)
        #pragma unroll
        for (int r = 0; r < 4; ++r)
            dv[ns][r] = dg[b * N_ + n0 + 16 * ns + 4 * q + r];

    long bn[8];
    #pragma unroll
    for (int kk = 0; kk < 8; ++kk)
        bn[kk] = *(const long*)(xfrag8 + xfi8(b, w, kk) + (size_t)lane * 8);

    float rs[4][4] = {};
    for (int mc = 0; mc < 16; ++mc) {
        const int mtn = (mc + 1 < 16) ? (mc + 1) * 16 + w : w;   // harmless wrap
        f32x4 a0 = {0.f,0.f,0.f,0.f}, a1 = {0.f,0.f,0.f,0.f};
        f32x4 a2 = {0.f,0.f,0.f,0.f}, a3 = {0.f,0.f,0.f,0.f};
        #pragma unroll
        for (int kk = 0; kk < 8; ++kk) {
            const long bc = bn[kk];
            a0 = mfma8(af[0][kk], bc, a0);
            a1 = mfma8(af[1][kk], bc, a1);
            a2 = mfma8(af[2][kk], bc, a2);
            a3 = mfma8(af[3][kk], bc, a3);
            bn[kk] = *(const long*)(xfrag8 + xfi8(b, mtn, kk) + (size_t)lane * 8);
        }
        #pragma unroll
        for (int r = 0; r < 4; ++r) {
            rs[0][r] += __expf(a0[r] - dv[0][r]);
            rs[1][r] += __expf(a1[r] - dv[1][r]);
            rs[2][r] += __expf(a2[r] - dv[2][r]);
            rs[3][r] += __expf(a3[r] - dv[3][r]);
        }
    }
    #pragma unroll
    for (int off = 1; off < 16; off <<= 1)
        #pragma unroll
        for (int ns = 0; ns < 4; ++ns)
            #pragma unroll
            for (int r = 0; r < 4; ++r)
                rs[ns][r] += __shfl_xor(rs[ns][r], off, 64);
    if (l15 == 0) {
        #pragma unroll
        for (int ns = 0; ns < 4; ++ns)
            #pragma unroll
            for (int r = 0; r < 4; ++r)
                red[w][16 * ns + 4 * q + r] = rs[ns][r];
    }
    __syncthreads();
    if (t < 64) {
        float s = 0.f;
        #pragma unroll
        for (int ww = 0; ww < 16; ++ww) s += red[ww][t];
        const int gi = b * N_ + n0 + t;
        lg[gi] = dg[gi] + __logf(s);
    }
}

// ---------------------------------------------------------------------------
// K3 v4: out[c,m] = sum_n fd[c,n]*exp(S[n,m]-g[n]) + fd[c,m]
// 512 thr (8 waves), grid 512, launch_bounds(512,4) -> 2 blocks/CU: TWO
// independent barrier groups per CU so one block's MFMA fills the other's
// phase-B VALU / barrier bubbles. m-tile 32, n-chunk 128. Per-wave shape
// matches v3 (32 MFMA per barrier, 2-chain phase A, 4-acc phase C); per-CU
// L2 traffic and total MFMA identical to v3 — only barrier-group count
// changes. Phase A FP8; Xm B-frags persistent; Xn A-frags 1-chunk rotation;
// Fd bf16 top-of-chunk; ET dbuf LDS; ONE lgkm-only barrier per chunk.
// ---------------------------------------------------------------------------
__global__ __launch_bounds__(512, 4) void out_kernel(const uchar* __restrict__ xfrag8,
                                                     const ushort* __restrict__ ffrag,
                                                     const float* __restrict__ gg,
                                                     const float* __restrict__ fd32,
                                                     float* __restrict__ outp) {
    __shared__ ushort ET[2][32][LDE];   // [buf][m-local 32][n-local 128]
    const int bid = blockIdx.x;
    const int b = (bid >> 1) & 3;
    const int m0 = ((((bid >> 3) << 1) | (bid & 1))) * 32;
    const int t = threadIdx.x, lane = t & 63, w = t >> 6;   // w 0..7
    const int l15 = lane & 15, q = lane >> 4;
    const int a = w;                     // phase A: n-subtile a (0..7)
    const size_t fb = (size_t)b * C_ * N_;

    long bfr[2][8];                      // persistent Xm B-frags (fp8), m-subtiles 0,1
    #pragma unroll
    for (int jt = 0; jt < 2; ++jt)
        #pragma unroll
        for (int kk = 0; kk < 8; ++kk)
            bfr[jt][kk] = *(const long*)(xfrag8 + xfi8(b, (m0 >> 4) + jt, kk) + (size_t)lane * 8);

    f32x4 acc[2][2];                     // [ct][mt]; wave owns c-rows 32w..32w+31
    #pragma unroll
    for (int ct = 0; ct < 2; ++ct)
        #pragma unroll
        for (int mt = 0; mt < 2; ++mt)
            acc[ct][mt] = (f32x4){0.f, 0.f, 0.f, 0.f};

    long an[8];                          // Xn A-frags (fp8), chunk 0, subtile a
    #pragma unroll
    for (int kk = 0; kk < 8; ++kk)
        an[kk] = *(const long*)(xfrag8 + xfi8(b, a, kk) + (size_t)lane * 8);
    float gn[4];
    #pragma unroll
    for (int r = 0; r < 4; ++r) gn[r] = gg[b * N_ + 16 * a + 4 * q + r];

    int p = 0;
    for (int n0c = 0; n0c < N_; n0c += 128, p ^= 1) {
        const int nc = n0c >> 6;         // 64-chunk index (steps of 2)
        // Fd A-frags (bf16) for THIS chunk — used in phase C, far away
        short8 fn[2][4];                 // [ct][j: n-slice of 32]
        #pragma unroll
        for (int ct = 0; ct < 2; ++ct)
            #pragma unroll
            for (int j = 0; j < 4; ++j)
                fn[ct][j] = *(const short8*)(ffrag + ffi(b, nc + (j >> 1), 2 * w + ct, j & 1) + lane * 8);
        float gv[4];
        #pragma unroll
        for (int r = 0; r < 4; ++r) gv[r] = gn[r];
        const int nx = (n0c + 128 < N_) ? n0c + 128 : 0;   // harmless wrap
        #pragma unroll
        for (int r = 0; r < 4; ++r) gn[r] = gg[b * N_ + nx + 16 * a + 4 * q + r];

        // ---- phase A (fp8): S tiles (a, mt=0), (a, mt=1); rotate an[] ----
        f32x4 s0 = {0.f, 0.f, 0.f, 0.f}, s1 = {0.f, 0.f, 0.f, 0.f};
        #pragma unroll
        for (int kk = 0; kk < 8; ++kk) {
            s0 = mfma8(an[kk], bfr[0][kk], s0);
            s1 = mfma8(an[kk], bfr[1][kk], s1);
            an[kk] = *(const long*)(xfrag8 + xfi8(b, (nx >> 4) + a, kk) + (size_t)lane * 8);
        }
        // ---- phase B: E^T = bf16(exp(S-g)) -> ET[p][m][n] ----
        ushort4 e0, e1;
        e0.x = f2bf(__expf(s0[0] - gv[0])); e0.y = f2bf(__expf(s0[1] - gv[1]));
        e0.z = f2bf(__expf(s0[2] - gv[2])); e0.w = f2bf(__expf(s0[3] - gv[3]));
        e1.x = f2bf(__expf(s1[0] - gv[0])); e1.y = f2bf(__expf(s1[1] - gv[1]));
        e1.z = f2bf(__expf(s1[2] - gv[2])); e1.w = f2bf(__expf(s1[3] - gv[3]));
        *(ushort4*)(&ET[p][l15][16 * a + 4 * q])      = e0;
        *(ushort4*)(&ET[p][16 + l15][16 * a + 4 * q]) = e1;

        // lgkm-only barrier: ds ops drained, prefetch vmem stays in flight
        asm volatile("s_waitcnt lgkmcnt(0)\n\ts_barrier" ::: "memory");

        // ---- phase C (bf16): out[32w..+32][m0..+32] += Fd * E ----
        #pragma unroll
        for (int j = 0; j < 4; ++j) {
            #pragma unroll
            for (int mt = 0; mt < 2; ++mt) {
                const short8 be = *(const short8*)(&ET[p][16 * mt + l15][32 * j + 8 * q]);
                acc[0][mt] = mfma16(fn[0][j], be, acc[0][mt]);
                acc[1][mt] = mfma16(fn[1][j], be, acc[1][mt]);
            }
        }
    }
    // ---- epilogue: + fp32 residual ----
    #pragma unroll
    for (int ct = 0; ct < 2; ++ct)
        #pragma unroll
        for (int mt = 0; mt < 2; ++mt)
            #pragma unroll
            for (int r = 0; r < 4; ++r) {
                const int c = 32 * w + 16 * ct + 4 * q + r;
                const int m = m0 + 16 * mt + l15;
                const size_t o = fb + (size_t)c * N_ + m;
                outp[o] = acc[ct][mt][r] + fd32[o];
            }
}

// ---------------------------------------------------------------------------
extern "C" void kernel_launch(void* const* d_in, const int* in_sizes, int n_in,
                              void* d_out, int out_size, void* d_ws, size_t ws_size,
                              hipStream_t stream) {
    const float* fm = (const float*)d_in[0];
    const float* fd = (const float*)d_in[1];
    float* outp = (float*)d_out;

    const size_t xb_elts = (size_t)B_ * N_ * C_;                    // 4.19M
    const size_t need = xb_elts + xb_elts * 2 + (size_t)B_ * N_ * 8; // ~12.7 MB
    if (ws_size < need) return;

    uchar*  xfrag8 = (uchar*)d_ws;                    // fp8, 4.19 MB
    ushort* ffrag  = (ushort*)(xfrag8 + xb_elts);     // bf16, 8.39 MB
    float*  dg     = (float*)(ffrag + xb_elts);
    float*  lg     = dg + (size_t)B_ * N_;

    hipMemsetAsync(dg, 0, (size_t)B_ * N_ * sizeof(float), stream);
    prep_kernel<<<dim3(N_ / 64, C_ / 64, B_), 256, 0, stream>>>(fm, fd, xfrag8, ffrag, dg);
    lsum_kernel<<<dim3(256), 1024, 0, stream>>>(xfrag8, dg, lg);
    out_kernel<<<dim3(512), 512, 0, stream>>>(xfrag8, ffrag, lg, fd, outp);
}

// Round 4
// 178.560 us; speedup vs baseline: 1.0929x; 1.0929x over previous
//
#include <hip/hip_runtime.h>
#include <math.h>

#define B_ 4
#define C_ 256
#define N_ 4096   // H*W
#define LDE 68    // ET row stride (ushorts) — verified, 0 conflicts
#define LDX 72    // prep LDS tile stride (ushorts)

typedef __attribute__((ext_vector_type(8))) short short8;
typedef __attribute__((ext_vector_type(4))) float f32x4;

__device__ inline ushort f2bf(float f) {
    uint u = __float_as_uint(f);
    return (ushort)((u + 0x7fffu + ((u >> 16) & 1u)) >> 16);   // RNE
}
__device__ inline float bf2f(ushort h) { return __uint_as_float(((uint)h) << 16); }

__device__ inline f32x4 mfma16(short8 a, short8 b, f32x4 c) {
    return __builtin_amdgcn_mfma_f32_16x16x32_bf16(a, b, c, 0, 0, 0);
}
__device__ inline f32x4 mfma8(long a, long b, f32x4 c) {
    return __builtin_amdgcn_mfma_f32_16x16x32_fp8_fp8(a, b, c, 0, 0, 0);
}

// Fragment-order layouts (lane l <-> (row l&15, k-group l>>4)):
//   xfrag8[b][nt=0..255][kk=0..7][lane][8 fp8]      (X = fp8(fm+fd), k=c, 512 B/tile)
//   ffrag [b][nc=0..63][ct=0..15][k2=0..1][lane][8] (Fd bf16, k=n within chunk)
__device__ inline size_t xfi8(int b, int nt, int kk) {   // BYTE offset
    return (((size_t)(b * 256 + nt)) * 8 + kk) * 512;
}
__device__ inline size_t ffi(int b, int nc, int ct, int k2) {   // ushort offset
    return ((((size_t)(b * 64 + nc)) * 16 + ct) * 2 + k2) * 512;
}

// ---------------------------------------------------------------------------
// P0 v2: build xfrag8 (fp8, MFMA-native) + ffrag (bf16). NO dg pass anymore —
// the softmax shift is computed in lsum from the fp8 Gram diagonal itself
// (numerically cleaner: exp(S[n,n]-dg[n]) == 1 exactly). No atomics, no
// memset, no prep->lsum dependency through dg.
// ---------------------------------------------------------------------------
__global__ __launch_bounds__(256) void prep_kernel(const float* __restrict__ fm,
                                                   const float* __restrict__ fd,
                                                   uchar* __restrict__ xfrag8,
                                                   ushort* __restrict__ ffrag) {
    __shared__ ushort xl[64][LDX];   // [c-local][n-local] bf16 X
    __shared__ ushort fl[64][LDX];   // [c-local][n-local] bf16 Fd
    const int b = blockIdx.z, c0 = blockIdx.y * 64, n0 = blockIdx.x * 64;
    const int t = threadIdx.x;
    const int n4 = (t & 15) * 4, cl = t >> 4;
    const size_t base = (size_t)b * C_ * N_;
    #pragma unroll
    for (int p = 0; p < 4; ++p) {
        const int cr = 16 * p + cl;
        const float4 m4 = *(const float4*)(fm + base + (size_t)(c0 + cr) * N_ + n0 + n4);
        const float4 d4 = *(const float4*)(fd + base + (size_t)(c0 + cr) * N_ + n0 + n4);
        ushort4 fo;
        fo.x = f2bf(d4.x); fo.y = f2bf(d4.y); fo.z = f2bf(d4.z); fo.w = f2bf(d4.w);
        *(ushort4*)(&fl[cr][n4]) = fo;
        ushort4 xo;
        xo.x = f2bf(m4.x + d4.x); xo.y = f2bf(m4.y + d4.y);
        xo.z = f2bf(m4.z + d4.z); xo.w = f2bf(m4.w + d4.w);
        *(ushort4*)(&xl[cr][n4]) = xo;
    }
    __syncthreads();
    const int l = t & 63, tl = t >> 6;     // tl = local tile index 0..3
    {   // xfrag8: lane l <- n-row 16*tl+(l&15), c bytes 32*kk+8*(l>>4), fp8 pack
        const int nl = 16 * tl + (l & 15);
        #pragma unroll
        for (int j = 0; j < 2; ++j) {
            const int kk = (c0 >> 5) + j;
            const int cb = 32 * j + 8 * (l >> 4);
            float f[8];
            #pragma unroll
            for (int i = 0; i < 8; ++i) f[i] = bf2f(xl[cb + i][nl]);
            int d0 = __builtin_amdgcn_cvt_pk_fp8_f32(f[0], f[1], 0, 0);
            d0 = __builtin_amdgcn_cvt_pk_fp8_f32(f[2], f[3], d0, 1);
            int d1 = __builtin_amdgcn_cvt_pk_fp8_f32(f[4], f[5], 0, 0);
            d1 = __builtin_amdgcn_cvt_pk_fp8_f32(f[6], f[7], d1, 1);
            uint* dst = (uint*)(xfrag8 + xfi8(b, (n0 >> 4) + tl, kk) + (size_t)l * 8);
            dst[0] = (uint)d0; dst[1] = (uint)d1;
        }
    }
    {   // ffrag: lane l <- c-row 16*tl+(l&15), n ushorts 32*k2+8*(l>>4)
        const int row = 16 * tl + (l & 15);
        #pragma unroll
        for (int k2 = 0; k2 < 2; ++k2) {
            const int col = 32 * k2 + 8 * (l >> 4);
            const ushort4 a0 = *(const ushort4*)(&fl[row][col]);
            const ushort4 a1 = *(const ushort4*)(&fl[row][col + 4]);
            ushort* dst = ffrag + ffi(b, n0 >> 6, (c0 >> 4) + tl, k2) + l * 8;
            *(ushort4*)(dst) = a0; *(ushort4*)(dst + 4) = a1;
        }
    }
}

// ---------------------------------------------------------------------------
// K2 v3: lg[n] = dg[n] + log( sum_m exp(S[n,m]-dg[n]) ),  dg[n] = S[n,n]
// computed IN-KERNEL from the block's own af[] fragments (32 extra MFMAs,
// block-uniform) — no dg array, no atomics, no memset.
// Round-0 proven loop: 512 thr (8 waves), grid 256 (XCD-swizzled). Wave
// holds ALL 64 n-rows' A-frags persistent and owns m-stream w: 8 distinct
// streams, 128 m per iter, 32 iters, no loop barriers, bn 1-ahead rotation.
// ---------------------------------------------------------------------------
__global__ __launch_bounds__(512, 2) void lsum_kernel(const uchar* __restrict__ xfrag8,
                                                      float* __restrict__ lg) {
    __shared__ float red[8][64];
    __shared__ float dgl[64];
    const int bid = blockIdx.x;
    const int b = (bid >> 1) & 3;
    const int n0 = ((((bid >> 3) << 1) | (bid & 1))) * 64;
    const int t = threadIdx.x, lane = t & 63, w = t >> 6;
    const int l15 = lane & 15, q = lane >> 4;

    long af[4][8];
    #pragma unroll
    for (int ns = 0; ns < 4; ++ns)
        #pragma unroll
        for (int kk = 0; kk < 8; ++kk)
            af[ns][kk] = *(const long*)(xfrag8 + xfi8(b, (n0 >> 4) + ns, kk) + (size_t)lane * 8);

    // ---- diag shift dg = S[n,n] from af x af (C/D layout: col=l&15, row=4*(l>>4)+r)
    // diag element 4q'+r of tile ns lives in lane 20q'+r, reg r.
    float dv[4][4];
    #pragma unroll
    for (int ns = 0; ns < 4; ++ns) {
        f32x4 dacc = {0.f, 0.f, 0.f, 0.f};
        #pragma unroll
        for (int kk = 0; kk < 8; ++kk)
            dacc = mfma8(af[ns][kk], af[ns][kk], dacc);
        #pragma unroll
        for (int r = 0; r < 4; ++r)
            dv[ns][r] = __shfl(dacc[r], 20 * q + r, 64);
    }
    if (w == 0 && l15 == 0) {   // lanes 0,16,32,48 cover q=0..3 (identical across waves)
        #pragma unroll
        for (int ns = 0; ns < 4; ++ns)
            #pragma unroll
            for (int r = 0; r < 4; ++r)
                dgl[16 * ns + 4 * q + r] = dv[ns][r];
    }

    long bn[8];
    #pragma unroll
    for (int kk = 0; kk < 8; ++kk)
        bn[kk] = *(const long*)(xfrag8 + xfi8(b, w, kk) + (size_t)lane * 8);

    float rs[4][4] = {};
    for (int mc = 0; mc < 32; ++mc) {
        const int mtn = (mc + 1 < 32) ? (mc + 1) * 8 + w : w;   // harmless wrap
        f32x4 a0 = {0.f,0.f,0.f,0.f}, a1 = {0.f,0.f,0.f,0.f};
        f32x4 a2 = {0.f,0.f,0.f,0.f}, a3 = {0.f,0.f,0.f,0.f};
        #pragma unroll
        for (int kk = 0; kk < 8; ++kk) {
            const long bc = bn[kk];
            a0 = mfma8(af[0][kk], bc, a0);
            a1 = mfma8(af[1][kk], bc, a1);
            a2 = mfma8(af[2][kk], bc, a2);
            a3 = mfma8(af[3][kk], bc, a3);
            bn[kk] = *(const long*)(xfrag8 + xfi8(b, mtn, kk) + (size_t)lane * 8);
        }
        #pragma unroll
        for (int r = 0; r < 4; ++r) {
            rs[0][r] += __expf(a0[r] - dv[0][r]);
            rs[1][r] += __expf(a1[r] - dv[1][r]);
            rs[2][r] += __expf(a2[r] - dv[2][r]);
            rs[3][r] += __expf(a3[r] - dv[3][r]);
        }
    }
    #pragma unroll
    for (int off = 1; off < 16; off <<= 1)
        #pragma unroll
        for (int ns = 0; ns < 4; ++ns)
            #pragma unroll
            for (int r = 0; r < 4; ++r)
                rs[ns][r] += __shfl_xor(rs[ns][r], off, 64);
    if (l15 == 0) {
        #pragma unroll
        for (int ns = 0; ns < 4; ++ns)
            #pragma unroll
            for (int r = 0; r < 4; ++r)
                red[w][16 * ns + 4 * q + r] = rs[ns][r];
    }
    __syncthreads();
    if (t < 64) {
        float s = 0.f;
        #pragma unroll
        for (int ww = 0; ww < 8; ++ww) s += red[ww][t];
        lg[b * N_ + n0 + t] = dgl[t] + __logf(s);
    }
}

// ---------------------------------------------------------------------------
// K3: out[c,m] = sum_n fd[c,n]*exp(S[n,m]-g[n]) + fd[c,m]
// Round-0 proven structure (best measured: 85.7 µs): 512 thr, grid 256
// (XCD-swizzled), m-tile 64, n-chunk 64. Phase A FP8; Xm B-frags persistent;
// Xn A-frags 1-chunk rotation; Fd bf16 top-of-chunk; ET dbuf LDS; ONE
// lgkm-only barrier per chunk (prefetch vmem stays in flight).
// ---------------------------------------------------------------------------
__global__ __launch_bounds__(512, 2) void out_kernel(const uchar* __restrict__ xfrag8,
                                                     const ushort* __restrict__ ffrag,
                                                     const float* __restrict__ gg,
                                                     const float* __restrict__ fd32,
                                                     float* __restrict__ outp) {
    __shared__ ushort ET[2][64][LDE];   // [buf][m-local][n-local]
    const int bid = blockIdx.x;
    const int b = (bid >> 1) & 3;
    const int m0 = ((((bid >> 3) << 1) | (bid & 1))) * 64;
    const int t = threadIdx.x, lane = t & 63, w = t >> 6;
    const int l15 = lane & 15, q = lane >> 4;
    const int a = w & 3, h = w >> 2;     // phase A: n-subtile a, m-pair h
    const size_t fb = (size_t)b * C_ * N_;

    long bfr[2][8];                      // persistent Xm B-frags (fp8)
    #pragma unroll
    for (int jt = 0; jt < 2; ++jt)
        #pragma unroll
        for (int kk = 0; kk < 8; ++kk)
            bfr[jt][kk] = *(const long*)(xfrag8 + xfi8(b, (m0 >> 4) + 2 * h + jt, kk) + (size_t)lane * 8);

    f32x4 acc[2][4];
    #pragma unroll
    for (int ct = 0; ct < 2; ++ct)
        #pragma unroll
        for (int mt = 0; mt < 4; ++mt)
            acc[ct][mt] = (f32x4){0.f, 0.f, 0.f, 0.f};

    long an[8];                          // Xn A-frags (fp8), chunk 0
    #pragma unroll
    for (int kk = 0; kk < 8; ++kk)
        an[kk] = *(const long*)(xfrag8 + xfi8(b, a, kk) + (size_t)lane * 8);
    float gn[4];
    #pragma unroll
    for (int r = 0; r < 4; ++r) gn[r] = gg[b * N_ + 16 * a + 4 * q + r];

    int p = 0;
    for (int n0c = 0; n0c < N_; n0c += 64, p ^= 1) {
        const int nc = n0c >> 6;
        // Fd A-frags (bf16) for THIS chunk — used in phase C, far away
        short8 fn[2][2];
        #pragma unroll
        for (int ct = 0; ct < 2; ++ct)
            #pragma unroll
            for (int k2 = 0; k2 < 2; ++k2)
                fn[ct][k2] = *(const short8*)(ffrag + ffi(b, nc, 2 * w + ct, k2) + lane * 8);
        float gv[4];
        #pragma unroll
        for (int r = 0; r < 4; ++r) gv[r] = gn[r];
        const int nx = (n0c + 64 < N_) ? n0c + 64 : 0;   // harmless wrap
        #pragma unroll
        for (int r = 0; r < 4; ++r) gn[r] = gg[b * N_ + nx + 16 * a + 4 * q + r];

        // ---- phase A (fp8): S tiles (a, 2h), (a, 2h+1); rotate an[] ----
        f32x4 s0 = {0.f, 0.f, 0.f, 0.f}, s1 = {0.f, 0.f, 0.f, 0.f};
        #pragma unroll
        for (int kk = 0; kk < 8; ++kk) {
            s0 = mfma8(an[kk], bfr[0][kk], s0);
            s1 = mfma8(an[kk], bfr[1][kk], s1);
            an[kk] = *(const long*)(xfrag8 + xfi8(b, (nx >> 4) + a, kk) + (size_t)lane * 8);
        }
        // ---- phase B: E^T = bf16(exp(S-g)) -> ET[p][m][n] ----
        ushort4 e0, e1;
        e0.x = f2bf(__expf(s0[0] - gv[0])); e0.y = f2bf(__expf(s0[1] - gv[1]));
        e0.z = f2bf(__expf(s0[2] - gv[2])); e0.w = f2bf(__expf(s0[3] - gv[3]));
        e1.x = f2bf(__expf(s1[0] - gv[0])); e1.y = f2bf(__expf(s1[1] - gv[1]));
        e1.z = f2bf(__expf(s1[2] - gv[2])); e1.w = f2bf(__expf(s1[3] - gv[3]));
        *(ushort4*)(&ET[p][32 * h + l15][16 * a + 4 * q])      = e0;
        *(ushort4*)(&ET[p][32 * h + 16 + l15][16 * a + 4 * q]) = e1;

        // lgkm-only barrier: ds ops drained, prefetch vmem stays in flight
        asm volatile("s_waitcnt lgkmcnt(0)\n\ts_barrier" ::: "memory");

        // ---- phase C (bf16): out[32w..+32][m0..+64] += Fd * E ----
        #pragma unroll
        for (int k2 = 0; k2 < 2; ++k2) {
            #pragma unroll
            for (int mt = 0; mt < 4; ++mt) {
                const short8 be = *(const short8*)(&ET[p][16 * mt + l15][32 * k2 + 8 * q]);
                acc[0][mt] = mfma16(fn[0][k2], be, acc[0][mt]);
                acc[1][mt] = mfma16(fn[1][k2], be, acc[1][mt]);
            }
        }
    }
    // ---- epilogue: + fp32 residual ----
    #pragma unroll
    for (int ct = 0; ct < 2; ++ct)
        #pragma unroll
        for (int mt = 0; mt < 4; ++mt)
            #pragma unroll
            for (int r = 0; r < 4; ++r) {
                const int c = 32 * w + 16 * ct + 4 * q + r;
                const int m = m0 + 16 * mt + l15;
                const size_t o = fb + (size_t)c * N_ + m;
                outp[o] = acc[ct][mt][r] + fd32[o];
            }
}

// ---------------------------------------------------------------------------
extern "C" void kernel_launch(void* const* d_in, const int* in_sizes, int n_in,
                              void* d_out, int out_size, void* d_ws, size_t ws_size,
                              hipStream_t stream) {
    const float* fm = (const float*)d_in[0];
    const float* fd = (const float*)d_in[1];
    float* outp = (float*)d_out;

    const size_t xb_elts = (size_t)B_ * N_ * C_;                    // 4.19M
    const size_t need = xb_elts + xb_elts * 2 + (size_t)B_ * N_ * 4; // ~12.6 MB
    if (ws_size < need) return;

    uchar*  xfrag8 = (uchar*)d_ws;                    // fp8, 4.19 MB
    ushort* ffrag  = (ushort*)(xfrag8 + xb_elts);     // bf16, 8.39 MB
    float*  lg     = (float*)(ffrag + xb_elts);

    prep_kernel<<<dim3(N_ / 64, C_ / 64, B_), 256, 0, stream>>>(fm, fd, xfrag8, ffrag);
    lsum_kernel<<<dim3(256), 512, 0, stream>>>(xfrag8, lg);
    out_kernel<<<dim3(256), 512, 0, stream>>>(xfrag8, ffrag, lg, fd, outp);
}

// Round 5
// 164.709 us; speedup vs baseline: 1.1848x; 1.0841x over previous
//
#include <hip/hip_runtime.h>
#include <math.h>

#define B_ 4
#define C_ 256
#define N_ 4096   // H*W
#define LDE 68    // ET row stride (ushorts) — verified, 0 conflicts (fallback path)
#define LDX 72    // prep LDS tile stride (ushorts)

typedef __attribute__((ext_vector_type(8))) short short8;
typedef __attribute__((ext_vector_type(4))) float f32x4;
typedef __attribute__((ext_vector_type(2))) float f32x2;

__device__ inline ushort f2bf(float f) {
    uint u = __float_as_uint(f);
    return (ushort)((u + 0x7fffu + ((u >> 16) & 1u)) >> 16);   // RNE
}
__device__ inline float bf2f(ushort h) { return __uint_as_float(((uint)h) << 16); }

__device__ inline f32x4 mfma16(short8 a, short8 b, f32x4 c) {
    return __builtin_amdgcn_mfma_f32_16x16x32_bf16(a, b, c, 0, 0, 0);
}
__device__ inline f32x4 mfma8(long a, long b, f32x4 c) {
    return __builtin_amdgcn_mfma_f32_16x16x32_fp8_fp8(a, b, c, 0, 0, 0);
}

// Fragment-order layouts (lane l <-> (row l&15, k-group l>>4)):
//   xfrag8[b][nt=0..255][kk=0..7][lane][8 fp8]      (X = fp8(fm+fd), k=c, 512 B/tile)
//   ffrag [b][nc=0..63][ct=0..15][k2=0..1][lane][8] (Fd bf16, k=n within chunk)
//   E8    [b][mt=0..255][ng=0..511][ml=0..15][8]    (E^T fp8: (b, m=16mt+ml, n=8ng+i))
__device__ inline size_t xfi8(int b, int nt, int kk) {   // BYTE offset
    return (((size_t)(b * 256 + nt)) * 8 + kk) * 512;
}
__device__ inline size_t ffi(int b, int nc, int ct, int k2) {   // ushort offset
    return ((((size_t)(b * 64 + nc)) * 16 + ct) * 2 + k2) * 512;
}
__device__ inline size_t eti(int b, int mt, int ng) {    // BYTE offset
    return (((size_t)(b * 256 + mt)) * 512 + (size_t)ng) * 128;
}

// ---------------------------------------------------------------------------
// P0: build xfrag8 (fp8, MFMA-native) + ffrag (bf16). Softmax shift comes
// from the fp8 Gram diagonal in lsum (exp(S[n,n]-dg[n]) == 1 exactly).
// ---------------------------------------------------------------------------
__global__ __launch_bounds__(256) void prep_kernel(const float* __restrict__ fm,
                                                   const float* __restrict__ fd,
                                                   uchar* __restrict__ xfrag8,
                                                   ushort* __restrict__ ffrag) {
    __shared__ ushort xl[64][LDX];   // [c-local][n-local] bf16 X
    __shared__ ushort fl[64][LDX];   // [c-local][n-local] bf16 Fd
    const int b = blockIdx.z, c0 = blockIdx.y * 64, n0 = blockIdx.x * 64;
    const int t = threadIdx.x;
    const int n4 = (t & 15) * 4, cl = t >> 4;
    const size_t base = (size_t)b * C_ * N_;
    #pragma unroll
    for (int p = 0; p < 4; ++p) {
        const int cr = 16 * p + cl;
        const float4 m4 = *(const float4*)(fm + base + (size_t)(c0 + cr) * N_ + n0 + n4);
        const float4 d4 = *(const float4*)(fd + base + (size_t)(c0 + cr) * N_ + n0 + n4);
        ushort4 fo;
        fo.x = f2bf(d4.x); fo.y = f2bf(d4.y); fo.z = f2bf(d4.z); fo.w = f2bf(d4.w);
        *(ushort4*)(&fl[cr][n4]) = fo;
        ushort4 xo;
        xo.x = f2bf(m4.x + d4.x); xo.y = f2bf(m4.y + d4.y);
        xo.z = f2bf(m4.z + d4.z); xo.w = f2bf(m4.w + d4.w);
        *(ushort4*)(&xl[cr][n4]) = xo;
    }
    __syncthreads();
    const int l = t & 63, tl = t >> 6;     // tl = local tile index 0..3
    {   // xfrag8: lane l <- n-row 16*tl+(l&15), c bytes 32*kk+8*(l>>4), fp8 pack
        const int nl = 16 * tl + (l & 15);
        #pragma unroll
        for (int j = 0; j < 2; ++j) {
            const int kk = (c0 >> 5) + j;
            const int cb = 32 * j + 8 * (l >> 4);
            float f[8];
            #pragma unroll
            for (int i = 0; i < 8; ++i) f[i] = bf2f(xl[cb + i][nl]);
            int d0 = __builtin_amdgcn_cvt_pk_fp8_f32(f[0], f[1], 0, 0);
            d0 = __builtin_amdgcn_cvt_pk_fp8_f32(f[2], f[3], d0, 1);
            int d1 = __builtin_amdgcn_cvt_pk_fp8_f32(f[4], f[5], 0, 0);
            d1 = __builtin_amdgcn_cvt_pk_fp8_f32(f[6], f[7], d1, 1);
            uint* dst = (uint*)(xfrag8 + xfi8(b, (n0 >> 4) + tl, kk) + (size_t)l * 8);
            dst[0] = (uint)d0; dst[1] = (uint)d1;
        }
    }
    {   // ffrag: lane l <- c-row 16*tl+(l&15), n ushorts 32*k2+8*(l>>4)
        const int row = 16 * tl + (l & 15);
        #pragma unroll
        for (int k2 = 0; k2 < 2; ++k2) {
            const int col = 32 * k2 + 8 * (l >> 4);
            const ushort4 a0 = *(const ushort4*)(&fl[row][col]);
            const ushort4 a1 = *(const ushort4*)(&fl[row][col + 4]);
            ushort* dst = ffrag + ffi(b, n0 >> 6, (c0 >> 4) + tl, k2) + l * 8;
            *(ushort4*)(dst) = a0; *(ushort4*)(dst + 4) = a1;
        }
    }
}

// ---------------------------------------------------------------------------
// K2e: compute S once. Writes E^T = fp8(exp(S[n,m]-dg[n])) to E8, then
// rescales its own ffrag n-slice by s[n] = 1/sum_m exp(S[n,m]-dg[n])
// (folds softmax normalization into the PV A-operand). No lg array.
// 512 thr (8 waves), grid 256 (XCD-swizzled); wave holds all 64 n-rows'
// A-frags persistent, owns m-stream w; no loop barriers; bn 1-ahead.
// ---------------------------------------------------------------------------
__global__ __launch_bounds__(512, 2) void lsum_e_kernel(const uchar* __restrict__ xfrag8,
                                                        ushort* __restrict__ ffrag,
                                                        uchar* __restrict__ E8) {
    __shared__ float red[8][64];
    __shared__ float s_sh[64];
    const int bid = blockIdx.x;
    const int b = (bid >> 1) & 3;
    const int n0 = ((((bid >> 3) << 1) | (bid & 1))) * 64;
    const int t = threadIdx.x, lane = t & 63, w = t >> 6;
    const int l15 = lane & 15, q = lane >> 4;

    long af[4][8];
    #pragma unroll
    for (int ns = 0; ns < 4; ++ns)
        #pragma unroll
        for (int kk = 0; kk < 8; ++kk)
            af[ns][kk] = *(const long*)(xfrag8 + xfi8(b, (n0 >> 4) + ns, kk) + (size_t)lane * 8);

    // diag shift dg = S[n,n] (C/D layout: col=l&15, row=4*(l>>4)+r →
    // diag elem 4q'+r of tile ns lives in lane 20q'+r, reg r)
    float dv[4][4];
    #pragma unroll
    for (int ns = 0; ns < 4; ++ns) {
        f32x4 dacc = {0.f, 0.f, 0.f, 0.f};
        #pragma unroll
        for (int kk = 0; kk < 8; ++kk)
            dacc = mfma8(af[ns][kk], af[ns][kk], dacc);
        #pragma unroll
        for (int r = 0; r < 4; ++r)
            dv[ns][r] = __shfl(dacc[r], 20 * q + r, 64);
    }

    long bn[8];
    #pragma unroll
    for (int kk = 0; kk < 8; ++kk)
        bn[kk] = *(const long*)(xfrag8 + xfi8(b, w, kk) + (size_t)lane * 8);

    const size_t ebl = (size_t)l15 * 8 + 4 * (q & 1);   // lane's byte slot in E8 block
    const int ngb = (n0 >> 3) + (q >> 1);               // lane's base n-group

    float rs[4][4] = {};
    for (int mc = 0; mc < 32; ++mc) {
        const int mtn = (mc + 1 < 32) ? (mc + 1) * 8 + w : w;   // harmless wrap
        f32x4 a0 = {0.f,0.f,0.f,0.f}, a1 = {0.f,0.f,0.f,0.f};
        f32x4 a2 = {0.f,0.f,0.f,0.f}, a3 = {0.f,0.f,0.f,0.f};
        #pragma unroll
        for (int kk = 0; kk < 8; ++kk) {
            const long bc = bn[kk];
            a0 = mfma8(af[0][kk], bc, a0);
            a1 = mfma8(af[1][kk], bc, a1);
            a2 = mfma8(af[2][kk], bc, a2);
            a3 = mfma8(af[3][kk], bc, a3);
            bn[kk] = *(const long*)(xfrag8 + xfi8(b, mtn, kk) + (size_t)lane * 8);
        }
        const int mt = mc * 8 + w;   // this wave's m-tile (16 m)
#define EPACK(AA, NS)                                                                  \
        {                                                                              \
            float e0 = __expf(AA[0] - dv[NS][0]), e1 = __expf(AA[1] - dv[NS][1]);      \
            float e2 = __expf(AA[2] - dv[NS][2]), e3 = __expf(AA[3] - dv[NS][3]);      \
            rs[NS][0] += e0; rs[NS][1] += e1; rs[NS][2] += e2; rs[NS][3] += e3;        \
            int d = __builtin_amdgcn_cvt_pk_fp8_f32(e0, e1, 0, 0);                     \
            d = __builtin_amdgcn_cvt_pk_fp8_f32(e2, e3, d, 1);                         \
            *(uint*)(E8 + eti(b, mt, ngb + 2 * NS) + ebl) = (uint)d;                   \
        }
        EPACK(a0, 0) EPACK(a1, 1) EPACK(a2, 2) EPACK(a3, 3)
#undef EPACK
    }
    #pragma unroll
    for (int off = 1; off < 16; off <<= 1)
        #pragma unroll
        for (int ns = 0; ns < 4; ++ns)
            #pragma unroll
            for (int r = 0; r < 4; ++r)
                rs[ns][r] += __shfl_xor(rs[ns][r], off, 64);
    if (l15 == 0) {
        #pragma unroll
        for (int ns = 0; ns < 4; ++ns)
            #pragma unroll
            for (int r = 0; r < 4; ++r)
                red[w][16 * ns + 4 * q + r] = rs[ns][r];
    }
    __syncthreads();
    if (t < 64) {
        float s = 0.f;
        #pragma unroll
        for (int ww = 0; ww < 8; ++ww) s += red[ww][t];
        s_sh[t] = 1.0f / s;
    }
    __syncthreads();
    // rescale this block's ffrag n-slice: fn'[c,n] = bf16(fn[c,n] * s[n])
    const int nc = n0 >> 6;
    #pragma unroll
    for (int ct2 = 0; ct2 < 2; ++ct2) {
        const int ct = 2 * w + ct2;
        #pragma unroll
        for (int k2 = 0; k2 < 2; ++k2) {
            ushort* fp = ffrag + ffi(b, nc, ct, k2) + (size_t)lane * 8;
            ushort4 u0 = *(ushort4*)fp;
            ushort4 u1 = *(ushort4*)(fp + 4);
            const int nb = 32 * k2 + 8 * q;
            ushort4 o0, o1;
            o0.x = f2bf(bf2f(u0.x) * s_sh[nb + 0]);
            o0.y = f2bf(bf2f(u0.y) * s_sh[nb + 1]);
            o0.z = f2bf(bf2f(u0.z) * s_sh[nb + 2]);
            o0.w = f2bf(bf2f(u0.w) * s_sh[nb + 3]);
            o1.x = f2bf(bf2f(u1.x) * s_sh[nb + 4]);
            o1.y = f2bf(bf2f(u1.y) * s_sh[nb + 5]);
            o1.z = f2bf(bf2f(u1.z) * s_sh[nb + 6]);
            o1.w = f2bf(bf2f(u1.w) * s_sh[nb + 7]);
            *(ushort4*)fp = o0;
            *(ushort4*)(fp + 4) = o1;
        }
    }
}

// ---------------------------------------------------------------------------
// K3e: pure PV GEMM — out[c,m] = sum_n fn'[c,n] * E[n,m] + fd[c,m].
// No S recompute, no exp, no LDS, no barriers. E^T fp8 frags loaded from
// global (written once by lsum_e, read exactly once here → L2/L3-resident),
// converted fp8→bf16 in-register (v_cvt_pk_f32_fp8 + v_cvt_pk_bf16_f32).
// 512 thr, grid 256 (XCD-swizzled), m-tile 64, 8 indep acc chains/wave.
// ---------------------------------------------------------------------------
__global__ __launch_bounds__(512, 2) void out_e_kernel(const uchar* __restrict__ E8,
                                                       const ushort* __restrict__ ffrag,
                                                       const float* __restrict__ fd32,
                                                       float* __restrict__ outp) {
    const int bid = blockIdx.x;
    const int b = (bid >> 1) & 3;
    const int m0 = ((((bid >> 3) << 1) | (bid & 1))) * 64;
    const int t = threadIdx.x, lane = t & 63, w = t >> 6;
    const int l15 = lane & 15, q = lane >> 4;
    const size_t fb = (size_t)b * C_ * N_;

    f32x4 acc[2][4];
    #pragma unroll
    for (int ct = 0; ct < 2; ++ct)
        #pragma unroll
        for (int mt = 0; mt < 4; ++mt)
            acc[ct][mt] = (f32x4){0.f, 0.f, 0.f, 0.f};

    for (int n0c = 0; n0c < N_; n0c += 64) {
        const int nc = n0c >> 6;
        short8 fn[2][2];
        #pragma unroll
        for (int ct = 0; ct < 2; ++ct)
            #pragma unroll
            for (int k2 = 0; k2 < 2; ++k2)
                fn[ct][k2] = *(const short8*)(ffrag + ffi(b, nc, 2 * w + ct, k2) + (size_t)lane * 8);
        #pragma unroll
        for (int k2 = 0; k2 < 2; ++k2) {
            #pragma unroll
            for (int mt = 0; mt < 4; ++mt) {
                const long e8 = *(const long*)(E8 + eti(b, (m0 >> 4) + mt, (n0c >> 3) + 4 * k2 + q) + (size_t)l15 * 8);
                const uint lo = (uint)(unsigned long)e8;
                const uint hi = (uint)((unsigned long)e8 >> 32);
                const f32x2 f01 = __builtin_amdgcn_cvt_pk_f32_fp8((int)lo, false);
                const f32x2 f23 = __builtin_amdgcn_cvt_pk_f32_fp8((int)lo, true);
                const f32x2 f45 = __builtin_amdgcn_cvt_pk_f32_fp8((int)hi, false);
                const f32x2 f67 = __builtin_amdgcn_cvt_pk_f32_fp8((int)hi, true);
                union { uint u[4]; short8 v; } be;
                asm("v_cvt_pk_bf16_f32 %0, %1, %2" : "=v"(be.u[0]) : "v"(f01.x), "v"(f01.y));
                asm("v_cvt_pk_bf16_f32 %0, %1, %2" : "=v"(be.u[1]) : "v"(f23.x), "v"(f23.y));
                asm("v_cvt_pk_bf16_f32 %0, %1, %2" : "=v"(be.u[2]) : "v"(f45.x), "v"(f45.y));
                asm("v_cvt_pk_bf16_f32 %0, %1, %2" : "=v"(be.u[3]) : "v"(f67.x), "v"(f67.y));
                acc[0][mt] = mfma16(fn[0][k2], be.v, acc[0][mt]);
                acc[1][mt] = mfma16(fn[1][k2], be.v, acc[1][mt]);
            }
        }
    }
    #pragma unroll
    for (int ct = 0; ct < 2; ++ct)
        #pragma unroll
        for (int mt = 0; mt < 4; ++mt)
            #pragma unroll
            for (int r = 0; r < 4; ++r) {
                const int c = 32 * w + 16 * ct + 4 * q + r;
                const int m = m0 + 16 * mt + l15;
                const size_t o = fb + (size_t)c * N_ + m;
                outp[o] = acc[ct][mt][r] + fd32[o];
            }
}

// ===========================================================================
// FALLBACK PATH (exact round-4 kernels) — used when ws_size < E8 requirement.
// ===========================================================================
__global__ __launch_bounds__(512, 2) void lsum_g_kernel(const uchar* __restrict__ xfrag8,
                                                        float* __restrict__ lg) {
    __shared__ float red[8][64];
    __shared__ float dgl[64];
    const int bid = blockIdx.x;
    const int b = (bid >> 1) & 3;
    const int n0 = ((((bid >> 3) << 1) | (bid & 1))) * 64;
    const int t = threadIdx.x, lane = t & 63, w = t >> 6;
    const int l15 = lane & 15, q = lane >> 4;

    long af[4][8];
    #pragma unroll
    for (int ns = 0; ns < 4; ++ns)
        #pragma unroll
        for (int kk = 0; kk < 8; ++kk)
            af[ns][kk] = *(const long*)(xfrag8 + xfi8(b, (n0 >> 4) + ns, kk) + (size_t)lane * 8);

    float dv[4][4];
    #pragma unroll
    for (int ns = 0; ns < 4; ++ns) {
        f32x4 dacc = {0.f, 0.f, 0.f, 0.f};
        #pragma unroll
        for (int kk = 0; kk < 8; ++kk)
            dacc = mfma8(af[ns][kk], af[ns][kk], dacc);
        #pragma unroll
        for (int r = 0; r < 4; ++r)
            dv[ns][r] = __shfl(dacc[r], 20 * q + r, 64);
    }
    if (w == 0 && l15 == 0) {
        #pragma unroll
        for (int ns = 0; ns < 4; ++ns)
            #pragma unroll
            for (int r = 0; r < 4; ++r)
                dgl[16 * ns + 4 * q + r] = dv[ns][r];
    }

    long bn[8];
    #pragma unroll
    for (int kk = 0; kk < 8; ++kk)
        bn[kk] = *(const long*)(xfrag8 + xfi8(b, w, kk) + (size_t)lane * 8);

    float rs[4][4] = {};
    for (int mc = 0; mc < 32; ++mc) {
        const int mtn = (mc + 1 < 32) ? (mc + 1) * 8 + w : w;
        f32x4 a0 = {0.f,0.f,0.f,0.f}, a1 = {0.f,0.f,0.f,0.f};
        f32x4 a2 = {0.f,0.f,0.f,0.f}, a3 = {0.f,0.f,0.f,0.f};
        #pragma unroll
        for (int kk = 0; kk < 8; ++kk) {
            const long bc = bn[kk];
            a0 = mfma8(af[0][kk], bc, a0);
            a1 = mfma8(af[1][kk], bc, a1);
            a2 = mfma8(af[2][kk], bc, a2);
            a3 = mfma8(af[3][kk], bc, a3);
            bn[kk] = *(const long*)(xfrag8 + xfi8(b, mtn, kk) + (size_t)lane * 8);
        }
        #pragma unroll
        for (int r = 0; r < 4; ++r) {
            rs[0][r] += __expf(a0[r] - dv[0][r]);
            rs[1][r] += __expf(a1[r] - dv[1][r]);
            rs[2][r] += __expf(a2[r] - dv[2][r]);
            rs[3][r] += __expf(a3[r] - dv[3][r]);
        }
    }
    #pragma unroll
    for (int off = 1; off < 16; off <<= 1)
        #pragma unroll
        for (int ns = 0; ns < 4; ++ns)
            #pragma unroll
            for (int r = 0; r < 4; ++r)
                rs[ns][r] += __shfl_xor(rs[ns][r], off, 64);
    if (l15 == 0) {
        #pragma unroll
        for (int ns = 0; ns < 4; ++ns)
            #pragma unroll
            for (int r = 0; r < 4; ++r)
                red[w][16 * ns + 4 * q + r] = rs[ns][r];
    }
    __syncthreads();
    if (t < 64) {
        float s = 0.f;
        #pragma unroll
        for (int ww = 0; ww < 8; ++ww) s += red[ww][t];
        lg[b * N_ + n0 + t] = dgl[t] + __logf(s);
    }
}

__global__ __launch_bounds__(512, 2) void out_g_kernel(const uchar* __restrict__ xfrag8,
                                                       const ushort* __restrict__ ffrag,
                                                       const float* __restrict__ gg,
                                                       const float* __restrict__ fd32,
                                                       float* __restrict__ outp) {
    __shared__ ushort ET[2][64][LDE];
    const int bid = blockIdx.x;
    const int b = (bid >> 1) & 3;
    const int m0 = ((((bid >> 3) << 1) | (bid & 1))) * 64;
    const int t = threadIdx.x, lane = t & 63, w = t >> 6;
    const int l15 = lane & 15, q = lane >> 4;
    const int a = w & 3, h = w >> 2;
    const size_t fb = (size_t)b * C_ * N_;

    long bfr[2][8];
    #pragma unroll
    for (int jt = 0; jt < 2; ++jt)
        #pragma unroll
        for (int kk = 0; kk < 8; ++kk)
            bfr[jt][kk] = *(const long*)(xfrag8 + xfi8(b, (m0 >> 4) + 2 * h + jt, kk) + (size_t)lane * 8);

    f32x4 acc[2][4];
    #pragma unroll
    for (int ct = 0; ct < 2; ++ct)
        #pragma unroll
        for (int mt = 0; mt < 4; ++mt)
            acc[ct][mt] = (f32x4){0.f, 0.f, 0.f, 0.f};

    long an[8];
    #pragma unroll
    for (int kk = 0; kk < 8; ++kk)
        an[kk] = *(const long*)(xfrag8 + xfi8(b, a, kk) + (size_t)lane * 8);
    float gn[4];
    #pragma unroll
    for (int r = 0; r < 4; ++r) gn[r] = gg[b * N_ + 16 * a + 4 * q + r];

    int p = 0;
    for (int n0c = 0; n0c < N_; n0c += 64, p ^= 1) {
        const int nc = n0c >> 6;
        short8 fn[2][2];
        #pragma unroll
        for (int ct = 0; ct < 2; ++ct)
            #pragma unroll
            for (int k2 = 0; k2 < 2; ++k2)
                fn[ct][k2] = *(const short8*)(ffrag + ffi(b, nc, 2 * w + ct, k2) + lane * 8);
        float gv[4];
        #pragma unroll
        for (int r = 0; r < 4; ++r) gv[r] = gn[r];
        const int nx = (n0c + 64 < N_) ? n0c + 64 : 0;
        #pragma unroll
        for (int r = 0; r < 4; ++r) gn[r] = gg[b * N_ + nx + 16 * a + 4 * q + r];

        f32x4 s0 = {0.f, 0.f, 0.f, 0.f}, s1 = {0.f, 0.f, 0.f, 0.f};
        #pragma unroll
        for (int kk = 0; kk < 8; ++kk) {
            s0 = mfma8(an[kk], bfr[0][kk], s0);
            s1 = mfma8(an[kk], bfr[1][kk], s1);
            an[kk] = *(const long*)(xfrag8 + xfi8(b, (nx >> 4) + a, kk) + (size_t)lane * 8);
        }
        ushort4 e0, e1;
        e0.x = f2bf(__expf(s0[0] - gv[0])); e0.y = f2bf(__expf(s0[1] - gv[1]));
        e0.z = f2bf(__expf(s0[2] - gv[2])); e0.w = f2bf(__expf(s0[3] - gv[3]));
        e1.x = f2bf(__expf(s1[0] - gv[0])); e1.y = f2bf(__expf(s1[1] - gv[1]));
        e1.z = f2bf(__expf(s1[2] - gv[2])); e1.w = f2bf(__expf(s1[3] - gv[3]));
        *(ushort4*)(&ET[p][32 * h + l15][16 * a + 4 * q])      = e0;
        *(ushort4*)(&ET[p][32 * h + 16 + l15][16 * a + 4 * q]) = e1;

        asm volatile("s_waitcnt lgkmcnt(0)\n\ts_barrier" ::: "memory");

        #pragma unroll
        for (int k2 = 0; k2 < 2; ++k2) {
            #pragma unroll
            for (int mt = 0; mt < 4; ++mt) {
                const short8 be = *(const short8*)(&ET[p][16 * mt + l15][32 * k2 + 8 * q]);
                acc[0][mt] = mfma16(fn[0][k2], be, acc[0][mt]);
                acc[1][mt] = mfma16(fn[1][k2], be, acc[1][mt]);
            }
        }
    }
    #pragma unroll
    for (int ct = 0; ct < 2; ++ct)
        #pragma unroll
        for (int mt = 0; mt < 4; ++mt)
            #pragma unroll
            for (int r = 0; r < 4; ++r) {
                const int c = 32 * w + 16 * ct + 4 * q + r;
                const int m = m0 + 16 * mt + l15;
                const size_t o = fb + (size_t)c * N_ + m;
                outp[o] = acc[ct][mt][r] + fd32[o];
            }
}

// ---------------------------------------------------------------------------
extern "C" void kernel_launch(void* const* d_in, const int* in_sizes, int n_in,
                              void* d_out, int out_size, void* d_ws, size_t ws_size,
                              hipStream_t stream) {
    const float* fm = (const float*)d_in[0];
    const float* fd = (const float*)d_in[1];
    float* outp = (float*)d_out;

    const size_t xb_elts = (size_t)B_ * N_ * C_;                 // 4.19M
    const size_t e_bytes = (size_t)B_ * N_ * N_;                 // 67.1 MB (fp8 E^T)
    const size_t need_e  = xb_elts * 3 + e_bytes;                // ~79.7 MB
    const size_t need_g  = xb_elts * 3 + (size_t)B_ * N_ * 4;    // ~12.6 MB

    uchar*  xfrag8 = (uchar*)d_ws;                    // fp8, 4.19 MB
    ushort* ffrag  = (ushort*)(xfrag8 + xb_elts);     // bf16, 8.39 MB

    if (ws_size >= need_e) {
        uchar* E8 = (uchar*)(xfrag8 + xb_elts * 3);
        prep_kernel<<<dim3(N_ / 64, C_ / 64, B_), 256, 0, stream>>>(fm, fd, xfrag8, ffrag);
        lsum_e_kernel<<<dim3(256), 512, 0, stream>>>(xfrag8, ffrag, E8);
        out_e_kernel<<<dim3(256), 512, 0, stream>>>(E8, ffrag, fd, outp);
    } else if (ws_size >= need_g) {
        float* lg = (float*)(xfrag8 + xb_elts * 3);
        prep_kernel<<<dim3(N_ / 64, C_ / 64, B_), 256, 0, stream>>>(fm, fd, xfrag8, ffrag);
        lsum_g_kernel<<<dim3(256), 512, 0, stream>>>(xfrag8, lg);
        out_g_kernel<<<dim3(256), 512, 0, stream>>>(xfrag8, ffrag, lg, fd, outp);
    }
}

// Round 6
// 126.502 us; speedup vs baseline: 1.5427x; 1.3020x over previous
//
#include <hip/hip_runtime.h>
#include <math.h>

#define B_ 4
#define C_ 256
#define N_ 4096   // H*W
#define LDE 68    // ET row stride (ushorts) — verified, 0 conflicts (fallback path)
#define LDX 72    // prep LDS tile stride (ushorts)

typedef __attribute__((ext_vector_type(8))) short short8;
typedef __attribute__((ext_vector_type(4))) float f32x4;
typedef __attribute__((ext_vector_type(2))) float f32x2;

__device__ inline ushort f2bf(float f) {
    uint u = __float_as_uint(f);
    return (ushort)((u + 0x7fffu + ((u >> 16) & 1u)) >> 16);   // RNE
}
__device__ inline float bf2f(ushort h) { return __uint_as_float(((uint)h) << 16); }

__device__ inline f32x4 mfma16(short8 a, short8 b, f32x4 c) {
    return __builtin_amdgcn_mfma_f32_16x16x32_bf16(a, b, c, 0, 0, 0);
}
__device__ inline f32x4 mfma8(long a, long b, f32x4 c) {
    return __builtin_amdgcn_mfma_f32_16x16x32_fp8_fp8(a, b, c, 0, 0, 0);
}

// Fragment-order layouts (lane l <-> (row l&15, k-group l>>4)):
//   xfrag8[b][nt=0..255][kk=0..7][lane][8 fp8]      (X = fp8(fm+fd), k=c, 512 B/tile)
//   ffrag [b][nc=0..63][ct=0..15][k2=0..1][lane][8] (Fd bf16, k=n within chunk)
//   E8    [b][mt=0..255][ng=0..511][ml=0..15][8]    (E^T fp8: (b, m=16mt+ml, n=8ng+i))
//   zmask [b][nc=0..63][mt=0..255]                  (1 iff E-tile (16m x 64n) nonzero)
__device__ inline size_t xfi8(int b, int nt, int kk) {   // BYTE offset
    return (((size_t)(b * 256 + nt)) * 8 + kk) * 512;
}
__device__ inline size_t ffi(int b, int nc, int ct, int k2) {   // ushort offset
    return ((((size_t)(b * 64 + nc)) * 16 + ct) * 2 + k2) * 512;
}
__device__ inline size_t eti(int b, int mt, int ng) {    // BYTE offset
    return (((size_t)(b * 256 + mt)) * 512 + (size_t)ng) * 128;
}
__device__ inline size_t zmi(int b, int nc, int mt) {    // BYTE offset
    return ((size_t)(b * 64 + nc)) * 256 + mt;
}

// ---------------------------------------------------------------------------
// P0: build xfrag8 (fp8, MFMA-native) + ffrag (bf16). Softmax shift comes
// from the fp8 Gram diagonal in lsum (exp(S[n,n]-dg[n]) == 1 exactly).
// ---------------------------------------------------------------------------
__global__ __launch_bounds__(256) void prep_kernel(const float* __restrict__ fm,
                                                   const float* __restrict__ fd,
                                                   uchar* __restrict__ xfrag8,
                                                   ushort* __restrict__ ffrag) {
    __shared__ ushort xl[64][LDX];   // [c-local][n-local] bf16 X
    __shared__ ushort fl[64][LDX];   // [c-local][n-local] bf16 Fd
    const int b = blockIdx.z, c0 = blockIdx.y * 64, n0 = blockIdx.x * 64;
    const int t = threadIdx.x;
    const int n4 = (t & 15) * 4, cl = t >> 4;
    const size_t base = (size_t)b * C_ * N_;
    #pragma unroll
    for (int p = 0; p < 4; ++p) {
        const int cr = 16 * p + cl;
        const float4 m4 = *(const float4*)(fm + base + (size_t)(c0 + cr) * N_ + n0 + n4);
        const float4 d4 = *(const float4*)(fd + base + (size_t)(c0 + cr) * N_ + n0 + n4);
        ushort4 fo;
        fo.x = f2bf(d4.x); fo.y = f2bf(d4.y); fo.z = f2bf(d4.z); fo.w = f2bf(d4.w);
        *(ushort4*)(&fl[cr][n4]) = fo;
        ushort4 xo;
        xo.x = f2bf(m4.x + d4.x); xo.y = f2bf(m4.y + d4.y);
        xo.z = f2bf(m4.z + d4.z); xo.w = f2bf(m4.w + d4.w);
        *(ushort4*)(&xl[cr][n4]) = xo;
    }
    __syncthreads();
    const int l = t & 63, tl = t >> 6;     // tl = local tile index 0..3
    {   // xfrag8: lane l <- n-row 16*tl+(l&15), c bytes 32*kk+8*(l>>4), fp8 pack
        const int nl = 16 * tl + (l & 15);
        #pragma unroll
        for (int j = 0; j < 2; ++j) {
            const int kk = (c0 >> 5) + j;
            const int cb = 32 * j + 8 * (l >> 4);
            float f[8];
            #pragma unroll
            for (int i = 0; i < 8; ++i) f[i] = bf2f(xl[cb + i][nl]);
            int d0 = __builtin_amdgcn_cvt_pk_fp8_f32(f[0], f[1], 0, 0);
            d0 = __builtin_amdgcn_cvt_pk_fp8_f32(f[2], f[3], d0, 1);
            int d1 = __builtin_amdgcn_cvt_pk_fp8_f32(f[4], f[5], 0, 0);
            d1 = __builtin_amdgcn_cvt_pk_fp8_f32(f[6], f[7], d1, 1);
            uint* dst = (uint*)(xfrag8 + xfi8(b, (n0 >> 4) + tl, kk) + (size_t)l * 8);
            dst[0] = (uint)d0; dst[1] = (uint)d1;
        }
    }
    {   // ffrag: lane l <- c-row 16*tl+(l&15), n ushorts 32*k2+8*(l>>4)
        const int row = 16 * tl + (l & 15);
        #pragma unroll
        for (int k2 = 0; k2 < 2; ++k2) {
            const int col = 32 * k2 + 8 * (l >> 4);
            const ushort4 a0 = *(const ushort4*)(&fl[row][col]);
            const ushort4 a1 = *(const ushort4*)(&fl[row][col + 4]);
            ushort* dst = ffrag + ffi(b, n0 >> 6, (c0 >> 4) + tl, k2) + l * 8;
            *(ushort4*)(dst) = a0; *(ushort4*)(dst + 4) = a1;
        }
    }
}

// ---------------------------------------------------------------------------
// K2e v2: compute S once. Writes E^T = fp8(exp(S[n,m]-dg[n])) to E8 for
// NONZERO tiles only, plus zmask[b][nc][mt] = tile-nonzero byte (exact
// sparsity: skipped tiles are exactly 0 in fp8, contribute +0.0f in PV).
// Then rescales its own ffrag n-slice by s[n] = 1/sum_m exp(...).
// 512 thr (8 waves), grid 256; no loop barriers; bn 1-ahead rotation.
// ---------------------------------------------------------------------------
__global__ __launch_bounds__(512, 2) void lsum_e_kernel(const uchar* __restrict__ xfrag8,
                                                        ushort* __restrict__ ffrag,
                                                        uchar* __restrict__ E8,
                                                        uchar* __restrict__ zmask) {
    __shared__ float red[8][64];
    __shared__ float s_sh[64];
    const int bid = blockIdx.x;
    const int b = (bid >> 1) & 3;
    const int n0 = ((((bid >> 3) << 1) | (bid & 1))) * 64;
    const int t = threadIdx.x, lane = t & 63, w = t >> 6;
    const int l15 = lane & 15, q = lane >> 4;

    long af[4][8];
    #pragma unroll
    for (int ns = 0; ns < 4; ++ns)
        #pragma unroll
        for (int kk = 0; kk < 8; ++kk)
            af[ns][kk] = *(const long*)(xfrag8 + xfi8(b, (n0 >> 4) + ns, kk) + (size_t)lane * 8);

    // diag shift dg = S[n,n] (C/D layout: col=l&15, row=4*(l>>4)+r →
    // diag elem 4q'+r of tile ns lives in lane 20q'+r, reg r)
    float dv[4][4];
    #pragma unroll
    for (int ns = 0; ns < 4; ++ns) {
        f32x4 dacc = {0.f, 0.f, 0.f, 0.f};
        #pragma unroll
        for (int kk = 0; kk < 8; ++kk)
            dacc = mfma8(af[ns][kk], af[ns][kk], dacc);
        #pragma unroll
        for (int r = 0; r < 4; ++r)
            dv[ns][r] = __shfl(dacc[r], 20 * q + r, 64);
    }

    long bn[8];
    #pragma unroll
    for (int kk = 0; kk < 8; ++kk)
        bn[kk] = *(const long*)(xfrag8 + xfi8(b, w, kk) + (size_t)lane * 8);

    const size_t ebl = (size_t)l15 * 8 + 4 * (q & 1);   // lane's byte slot in E8 block
    const int ngb = (n0 >> 3) + (q >> 1);               // lane's base n-group
    const int ncb = n0 >> 6;

    float rs[4][4] = {};
    for (int mc = 0; mc < 32; ++mc) {
        const int mtn = (mc + 1 < 32) ? (mc + 1) * 8 + w : w;   // harmless wrap
        f32x4 a0 = {0.f,0.f,0.f,0.f}, a1 = {0.f,0.f,0.f,0.f};
        f32x4 a2 = {0.f,0.f,0.f,0.f}, a3 = {0.f,0.f,0.f,0.f};
        #pragma unroll
        for (int kk = 0; kk < 8; ++kk) {
            const long bc = bn[kk];
            a0 = mfma8(af[0][kk], bc, a0);
            a1 = mfma8(af[1][kk], bc, a1);
            a2 = mfma8(af[2][kk], bc, a2);
            a3 = mfma8(af[3][kk], bc, a3);
            bn[kk] = *(const long*)(xfrag8 + xfi8(b, mtn, kk) + (size_t)lane * 8);
        }
        const int mt = mc * 8 + w;   // this wave's m-tile (16 m)
        uint dpk[4];
#define EEXP(AA, NS)                                                                   \
        {                                                                              \
            float e0 = __expf(AA[0] - dv[NS][0]), e1 = __expf(AA[1] - dv[NS][1]);      \
            float e2 = __expf(AA[2] - dv[NS][2]), e3 = __expf(AA[3] - dv[NS][3]);      \
            rs[NS][0] += e0; rs[NS][1] += e1; rs[NS][2] += e2; rs[NS][3] += e3;        \
            int d = __builtin_amdgcn_cvt_pk_fp8_f32(e0, e1, 0, 0);                     \
            d = __builtin_amdgcn_cvt_pk_fp8_f32(e2, e3, d, 1);                         \
            dpk[NS] = (uint)d;                                                         \
        }
        EEXP(a0, 0) EEXP(a1, 1) EEXP(a2, 2) EEXP(a3, 3)
#undef EEXP
        const uint nzl = dpk[0] | dpk[1] | dpk[2] | dpk[3];
        const bool nz = (__ballot(nzl != 0u) != 0ULL);    // wave-uniform
        if (lane == 0) zmask[zmi(b, ncb, mt)] = nz ? 1 : 0;
        if (nz) {
            #pragma unroll
            for (int ns = 0; ns < 4; ++ns)
                *(uint*)(E8 + eti(b, mt, ngb + 2 * ns) + ebl) = dpk[ns];
        }
    }
    #pragma unroll
    for (int off = 1; off < 16; off <<= 1)
        #pragma unroll
        for (int ns = 0; ns < 4; ++ns)
            #pragma unroll
            for (int r = 0; r < 4; ++r)
                rs[ns][r] += __shfl_xor(rs[ns][r], off, 64);
    if (l15 == 0) {
        #pragma unroll
        for (int ns = 0; ns < 4; ++ns)
            #pragma unroll
            for (int r = 0; r < 4; ++r)
                red[w][16 * ns + 4 * q + r] = rs[ns][r];
    }
    __syncthreads();
    if (t < 64) {
        float s = 0.f;
        #pragma unroll
        for (int ww = 0; ww < 8; ++ww) s += red[ww][t];
        s_sh[t] = 1.0f / s;
    }
    __syncthreads();
    // rescale this block's ffrag n-slice: fn'[c,n] = bf16(fn[c,n] * s[n])
    const int nc = n0 >> 6;
    #pragma unroll
    for (int ct2 = 0; ct2 < 2; ++ct2) {
        const int ct = 2 * w + ct2;
        #pragma unroll
        for (int k2 = 0; k2 < 2; ++k2) {
            ushort* fp = ffrag + ffi(b, nc, ct, k2) + (size_t)lane * 8;
            ushort4 u0 = *(ushort4*)fp;
            ushort4 u1 = *(ushort4*)(fp + 4);
            const int nb = 32 * k2 + 8 * q;
            ushort4 o0, o1;
            o0.x = f2bf(bf2f(u0.x) * s_sh[nb + 0]);
            o0.y = f2bf(bf2f(u0.y) * s_sh[nb + 1]);
            o0.z = f2bf(bf2f(u0.z) * s_sh[nb + 2]);
            o0.w = f2bf(bf2f(u0.w) * s_sh[nb + 3]);
            o1.x = f2bf(bf2f(u1.x) * s_sh[nb + 4]);
            o1.y = f2bf(bf2f(u1.y) * s_sh[nb + 5]);
            o1.z = f2bf(bf2f(u1.z) * s_sh[nb + 6]);
            o1.w = f2bf(bf2f(u1.w) * s_sh[nb + 7]);
            *(ushort4*)fp = o0;
            *(ushort4*)(fp + 4) = o1;
        }
    }
}

// ---------------------------------------------------------------------------
// K3e v2: out[c,m] = sum_n fn'[c,n] * E[n,m] + fd[c,m], mask-gated:
// n-chunks whose E-tiles are all exactly zero are skipped (bit-identical
// output — skipped terms are exact +0.0f). Masks prefetched 8 per group.
// 512 thr, grid 256, m-tile 64, no barriers.
// ---------------------------------------------------------------------------
__global__ __launch_bounds__(512, 2) void out_e_kernel(const uchar* __restrict__ E8,
                                                       const ushort* __restrict__ ffrag,
                                                       const uchar* __restrict__ zmask,
                                                       const float* __restrict__ fd32,
                                                       float* __restrict__ outp) {
    const int bid = blockIdx.x;
    const int b = (bid >> 1) & 3;
    const int m0 = ((((bid >> 3) << 1) | (bid & 1))) * 64;
    const int t = threadIdx.x, lane = t & 63, w = t >> 6;
    const int l15 = lane & 15, q = lane >> 4;
    const size_t fb = (size_t)b * C_ * N_;
    const uchar* mrow = zmask + zmi(b, 0, m0 >> 4);   // + nc*256 per chunk

    f32x4 acc[2][4];
    #pragma unroll
    for (int ct = 0; ct < 2; ++ct)
        #pragma unroll
        for (int mt = 0; mt < 4; ++mt)
            acc[ct][mt] = (f32x4){0.f, 0.f, 0.f, 0.f};

    for (int g = 0; g < 8; ++g) {
        uint mk[8];
        #pragma unroll
        for (int i = 0; i < 8; ++i)
            mk[i] = *(const uint*)(mrow + (size_t)(8 * g + i) * 256);
        #pragma unroll
        for (int i = 0; i < 8; ++i) {
            if (mk[i] == 0) continue;
            const int nc = 8 * g + i;
            short8 fn[2][2];
            #pragma unroll
            for (int ct = 0; ct < 2; ++ct)
                #pragma unroll
                for (int k2 = 0; k2 < 2; ++k2)
                    fn[ct][k2] = *(const short8*)(ffrag + ffi(b, nc, 2 * w + ct, k2) + (size_t)lane * 8);
            #pragma unroll
            for (int k2 = 0; k2 < 2; ++k2) {
                #pragma unroll
                for (int mt = 0; mt < 4; ++mt) {
                    const long e8 = *(const long*)(E8 + eti(b, (m0 >> 4) + mt, 8 * nc + 4 * k2 + q) + (size_t)l15 * 8);
                    const uint lo = (uint)(unsigned long)e8;
                    const uint hi = (uint)((unsigned long)e8 >> 32);
                    const f32x2 f01 = __builtin_amdgcn_cvt_pk_f32_fp8((int)lo, false);
                    const f32x2 f23 = __builtin_amdgcn_cvt_pk_f32_fp8((int)lo, true);
                    const f32x2 f45 = __builtin_amdgcn_cvt_pk_f32_fp8((int)hi, false);
                    const f32x2 f67 = __builtin_amdgcn_cvt_pk_f32_fp8((int)hi, true);
                    union { uint u[4]; short8 v; } be;
                    asm("v_cvt_pk_bf16_f32 %0, %1, %2" : "=v"(be.u[0]) : "v"(f01.x), "v"(f01.y));
                    asm("v_cvt_pk_bf16_f32 %0, %1, %2" : "=v"(be.u[1]) : "v"(f23.x), "v"(f23.y));
                    asm("v_cvt_pk_bf16_f32 %0, %1, %2" : "=v"(be.u[2]) : "v"(f45.x), "v"(f45.y));
                    asm("v_cvt_pk_bf16_f32 %0, %1, %2" : "=v"(be.u[3]) : "v"(f67.x), "v"(f67.y));
                    acc[0][mt] = mfma16(fn[0][k2], be.v, acc[0][mt]);
                    acc[1][mt] = mfma16(fn[1][k2], be.v, acc[1][mt]);
                }
            }
        }
    }
    #pragma unroll
    for (int ct = 0; ct < 2; ++ct)
        #pragma unroll
        for (int mt = 0; mt < 4; ++mt)
            #pragma unroll
            for (int r = 0; r < 4; ++r) {
                const int c = 32 * w + 16 * ct + 4 * q + r;
                const int m = m0 + 16 * mt + l15;
                const size_t o = fb + (size_t)c * N_ + m;
                outp[o] = acc[ct][mt][r] + fd32[o];
            }
}

// ===========================================================================
// FALLBACK PATH (exact round-4 kernels) — used when ws_size < E8 requirement.
// ===========================================================================
__global__ __launch_bounds__(512, 2) void lsum_g_kernel(const uchar* __restrict__ xfrag8,
                                                        float* __restrict__ lg) {
    __shared__ float red[8][64];
    __shared__ float dgl[64];
    const int bid = blockIdx.x;
    const int b = (bid >> 1) & 3;
    const int n0 = ((((bid >> 3) << 1) | (bid & 1))) * 64;
    const int t = threadIdx.x, lane = t & 63, w = t >> 6;
    const int l15 = lane & 15, q = lane >> 4;

    long af[4][8];
    #pragma unroll
    for (int ns = 0; ns < 4; ++ns)
        #pragma unroll
        for (int kk = 0; kk < 8; ++kk)
            af[ns][kk] = *(const long*)(xfrag8 + xfi8(b, (n0 >> 4) + ns, kk) + (size_t)lane * 8);

    float dv[4][4];
    #pragma unroll
    for (int ns = 0; ns < 4; ++ns) {
        f32x4 dacc = {0.f, 0.f, 0.f, 0.f};
        #pragma unroll
        for (int kk = 0; kk < 8; ++kk)
            dacc = mfma8(af[ns][kk], af[ns][kk], dacc);
        #pragma unroll
        for (int r = 0; r < 4; ++r)
            dv[ns][r] = __shfl(dacc[r], 20 * q + r, 64);
    }
    if (w == 0 && l15 == 0) {
        #pragma unroll
        for (int ns = 0; ns < 4; ++ns)
            #pragma unroll
            for (int r = 0; r < 4; ++r)
                dgl[16 * ns + 4 * q + r] = dv[ns][r];
    }

    long bn[8];
    #pragma unroll
    for (int kk = 0; kk < 8; ++kk)
        bn[kk] = *(const long*)(xfrag8 + xfi8(b, w, kk) + (size_t)lane * 8);

    float rs[4][4] = {};
    for (int mc = 0; mc < 32; ++mc) {
        const int mtn = (mc + 1 < 32) ? (mc + 1) * 8 + w : w;
        f32x4 a0 = {0.f,0.f,0.f,0.f}, a1 = {0.f,0.f,0.f,0.f};
        f32x4 a2 = {0.f,0.f,0.f,0.f}, a3 = {0.f,0.f,0.f,0.f};
        #pragma unroll
        for (int kk = 0; kk < 8; ++kk) {
            const long bc = bn[kk];
            a0 = mfma8(af[0][kk], bc, a0);
            a1 = mfma8(af[1][kk], bc, a1);
            a2 = mfma8(af[2][kk], bc, a2);
            a3 = mfma8(af[3][kk], bc, a3);
            bn[kk] = *(const long*)(xfrag8 + xfi8(b, mtn, kk) + (size_t)lane * 8);
        }
        #pragma unroll
        for (int r = 0; r < 4; ++r) {
            rs[0][r] += __expf(a0[r] - dv[0][r]);
            rs[1][r] += __expf(a1[r] - dv[1][r]);
            rs[2][r] += __expf(a2[r] - dv[2][r]);
            rs[3][r] += __expf(a3[r] - dv[3][r]);
        }
    }
    #pragma unroll
    for (int off = 1; off < 16; off <<= 1)
        #pragma unroll
        for (int ns = 0; ns < 4; ++ns)
            #pragma unroll
            for (int r = 0; r < 4; ++r)
                rs[ns][r] += __shfl_xor(rs[ns][r], off, 64);
    if (l15 == 0) {
        #pragma unroll
        for (int ns = 0; ns < 4; ++ns)
            #pragma unroll
            for (int r = 0; r < 4; ++r)
                red[w][16 * ns + 4 * q + r] = rs[ns][r];
    }
    __syncthreads();
    if (t < 64) {
        float s = 0.f;
        #pragma unroll
        for (int ww = 0; ww < 8; ++ww) s += red[ww][t];
        lg[b * N_ + n0 + t] = dgl[t] + __logf(s);
    }
}

__global__ __launch_bounds__(512, 2) void out_g_kernel(const uchar* __restrict__ xfrag8,
                                                       const ushort* __restrict__ ffrag,
                                                       const float* __restrict__ gg,
                                                       const float* __restrict__ fd32,
                                                       float* __restrict__ outp) {
    __shared__ ushort ET[2][64][LDE];
    const int bid = blockIdx.x;
    const int b = (bid >> 1) & 3;
    const int m0 = ((((bid >> 3) << 1) | (bid & 1))) * 64;
    const int t = threadIdx.x, lane = t & 63, w = t >> 6;
    const int l15 = lane & 15, q = lane >> 4;
    const int a = w & 3, h = w >> 2;
    const size_t fb = (size_t)b * C_ * N_;

    long bfr[2][8];
    #pragma unroll
    for (int jt = 0; jt < 2; ++jt)
        #pragma unroll
        for (int kk = 0; kk < 8; ++kk)
            bfr[jt][kk] = *(const long*)(xfrag8 + xfi8(b, (m0 >> 4) + 2 * h + jt, kk) + (size_t)lane * 8);

    f32x4 acc[2][4];
    #pragma unroll
    for (int ct = 0; ct < 2; ++ct)
        #pragma unroll
        for (int mt = 0; mt < 4; ++mt)
            acc[ct][mt] = (f32x4){0.f, 0.f, 0.f, 0.f};

    long an[8];
    #pragma unroll
    for (int kk = 0; kk < 8; ++kk)
        an[kk] = *(const long*)(xfrag8 + xfi8(b, a, kk) + (size_t)lane * 8);
    float gn[4];
    #pragma unroll
    for (int r = 0; r < 4; ++r) gn[r] = gg[b * N_ + 16 * a + 4 * q + r];

    int p = 0;
    for (int n0c = 0; n0c < N_; n0c += 64, p ^= 1) {
        const int nc = n0c >> 6;
        short8 fn[2][2];
        #pragma unroll
        for (int ct = 0; ct < 2; ++ct)
            #pragma unroll
            for (int k2 = 0; k2 < 2; ++k2)
                fn[ct][k2] = *(const short8*)(ffrag + ffi(b, nc, 2 * w + ct, k2) + lane * 8);
        float gv[4];
        #pragma unroll
        for (int r = 0; r < 4; ++r) gv[r] = gn[r];
        const int nx = (n0c + 64 < N_) ? n0c + 64 : 0;
        #pragma unroll
        for (int r = 0; r < 4; ++r) gn[r] = gg[b * N_ + nx + 16 * a + 4 * q + r];

        f32x4 s0 = {0.f, 0.f, 0.f, 0.f}, s1 = {0.f, 0.f, 0.f, 0.f};
        #pragma unroll
        for (int kk = 0; kk < 8; ++kk) {
            s0 = mfma8(an[kk], bfr[0][kk], s0);
            s1 = mfma8(an[kk], bfr[1][kk], s1);
            an[kk] = *(const long*)(xfrag8 + xfi8(b, (nx >> 4) + a, kk) + (size_t)lane * 8);
        }
        ushort4 e0, e1;
        e0.x = f2bf(__expf(s0[0] - gv[0])); e0.y = f2bf(__expf(s0[1] - gv[1]));
        e0.z = f2bf(__expf(s0[2] - gv[2])); e0.w = f2bf(__expf(s0[3] - gv[3]));
        e1.x = f2bf(__expf(s1[0] - gv[0])); e1.y = f2bf(__expf(s1[1] - gv[1]));
        e1.z = f2bf(__expf(s1[2] - gv[2])); e1.w = f2bf(__expf(s1[3] - gv[3]));
        *(ushort4*)(&ET[p][32 * h + l15][16 * a + 4 * q])      = e0;
        *(ushort4*)(&ET[p][32 * h + 16 + l15][16 * a + 4 * q]) = e1;

        asm volatile("s_waitcnt lgkmcnt(0)\n\ts_barrier" ::: "memory");

        #pragma unroll
        for (int k2 = 0; k2 < 2; ++k2) {
            #pragma unroll
            for (int mt = 0; mt < 4; ++mt) {
                const short8 be = *(const short8*)(&ET[p][16 * mt + l15][32 * k2 + 8 * q]);
                acc[0][mt] = mfma16(fn[0][k2], be, acc[0][mt]);
                acc[1][mt] = mfma16(fn[1][k2], be, acc[1][mt]);
            }
        }
    }
    #pragma unroll
    for (int ct = 0; ct < 2; ++ct)
        #pragma unroll
        for (int mt = 0; mt < 4; ++mt)
            #pragma unroll
            for (int r = 0; r < 4; ++r) {
                const int c = 32 * w + 16 * ct + 4 * q + r;
                const int m = m0 + 16 * mt + l15;
                const size_t o = fb + (size_t)c * N_ + m;
                outp[o] = acc[ct][mt][r] + fd32[o];
            }
}

// ---------------------------------------------------------------------------
extern "C" void kernel_launch(void* const* d_in, const int* in_sizes, int n_in,
                              void* d_out, int out_size, void* d_ws, size_t ws_size,
                              hipStream_t stream) {
    const float* fm = (const float*)d_in[0];
    const float* fd = (const float*)d_in[1];
    float* outp = (float*)d_out;

    const size_t xb_elts = (size_t)B_ * N_ * C_;                 // 4.19M
    const size_t e_bytes = (size_t)B_ * N_ * N_;                 // 67.1 MB (fp8 E^T)
    const size_t z_bytes = (size_t)B_ * 64 * 256;                // 64 KB (zmask)
    const size_t need_e  = xb_elts * 3 + e_bytes + z_bytes;      // ~79.8 MB
    const size_t need_g  = xb_elts * 3 + (size_t)B_ * N_ * 4;    // ~12.6 MB

    uchar*  xfrag8 = (uchar*)d_ws;                    // fp8, 4.19 MB
    ushort* ffrag  = (ushort*)(xfrag8 + xb_elts);     // bf16, 8.39 MB

    if (ws_size >= need_e) {
        uchar* E8 = (uchar*)(xfrag8 + xb_elts * 3);
        uchar* zmask = E8 + e_bytes;
        prep_kernel<<<dim3(N_ / 64, C_ / 64, B_), 256, 0, stream>>>(fm, fd, xfrag8, ffrag);
        lsum_e_kernel<<<dim3(256), 512, 0, stream>>>(xfrag8, ffrag, E8, zmask);
        out_e_kernel<<<dim3(256), 512, 0, stream>>>(E8, ffrag, zmask, fd, outp);
    } else if (ws_size >= need_g) {
        float* lg = (float*)(xfrag8 + xb_elts * 3);
        prep_kernel<<<dim3(N_ / 64, C_ / 64, B_), 256, 0, stream>>>(fm, fd, xfrag8, ffrag);
        lsum_g_kernel<<<dim3(256), 512, 0, stream>>>(xfrag8, lg);
        out_g_kernel<<<dim3(256), 512, 0, stream>>>(xfrag8, ffrag, lg, fd, outp);
    }
}

// Round 7
// 123.665 us; speedup vs baseline: 1.5781x; 1.0229x over previous
//
#include <hip/hip_runtime.h>
#include <math.h>

#define B_ 4
#define C_ 256
#define N_ 4096   // H*W
#define LDE 68    // ET row stride (ushorts) — verified, 0 conflicts (fallback path)
#define LDX 72    // prep LDS tile stride (ushorts)

typedef __attribute__((ext_vector_type(8))) short short8;
typedef __attribute__((ext_vector_type(4))) float f32x4;
typedef __attribute__((ext_vector_type(2))) float f32x2;

__device__ inline ushort f2bf(float f) {
    uint u = __float_as_uint(f);
    return (ushort)((u + 0x7fffu + ((u >> 16) & 1u)) >> 16);   // RNE
}
__device__ inline float bf2f(ushort h) { return __uint_as_float(((uint)h) << 16); }

__device__ inline f32x4 mfma16(short8 a, short8 b, f32x4 c) {
    return __builtin_amdgcn_mfma_f32_16x16x32_bf16(a, b, c, 0, 0, 0);
}
__device__ inline f32x4 mfma8(long a, long b, f32x4 c) {
    return __builtin_amdgcn_mfma_f32_16x16x32_fp8_fp8(a, b, c, 0, 0, 0);
}

// Fragment-order layouts (lane l <-> (row l&15, k-group l>>4)):
//   xfrag8[b][nt=0..255][kk=0..7][lane][8 fp8]      (X = fp8(fm+fd), k=c, 512 B/tile)
//   E8    [b][mt=0..255][ng=0..511][ml=0..15][8]    (E^T fp8: (b, m=16mt+ml, n=8ng+i))
//   zmask [b][nc=0..63][mt=0..255]                  (1 iff E-tile (16m x 64n) nonzero)
//   sinv  [b][n]                                    (1 / sum_m exp(S[n,m]-S[n,n]))
//   ffrag [b][nc][ct][k2][lane][8]                  (Fd bf16 — FALLBACK path only)
__device__ inline size_t xfi8(int b, int nt, int kk) {   // BYTE offset
    return (((size_t)(b * 256 + nt)) * 8 + kk) * 512;
}
__device__ inline size_t ffi(int b, int nc, int ct, int k2) {   // ushort offset
    return ((((size_t)(b * 64 + nc)) * 16 + ct) * 2 + k2) * 512;
}
__device__ inline size_t eti(int b, int mt, int ng) {    // BYTE offset
    return (((size_t)(b * 256 + mt)) * 512 + (size_t)ng) * 128;
}
__device__ inline size_t zmi(int b, int nc, int mt) {    // BYTE offset
    return ((size_t)(b * 64 + nc)) * 256 + mt;
}

// ---------------------------------------------------------------------------
// P0x (e-path): build xfrag8 only. No ffrag (out_e reads fd32 directly for
// its sparse chunks), no dg (diag shift computed in lsum from the fp8 Gram).
// ---------------------------------------------------------------------------
__global__ __launch_bounds__(256) void prep_x_kernel(const float* __restrict__ fm,
                                                     const float* __restrict__ fd,
                                                     uchar* __restrict__ xfrag8) {
    __shared__ ushort xl[64][LDX];   // [c-local][n-local] bf16 X
    const int b = blockIdx.z, c0 = blockIdx.y * 64, n0 = blockIdx.x * 64;
    const int t = threadIdx.x;
    const int n4 = (t & 15) * 4, cl = t >> 4;
    const size_t base = (size_t)b * C_ * N_;
    #pragma unroll
    for (int p = 0; p < 4; ++p) {
        const int cr = 16 * p + cl;
        const float4 m4 = *(const float4*)(fm + base + (size_t)(c0 + cr) * N_ + n0 + n4);
        const float4 d4 = *(const float4*)(fd + base + (size_t)(c0 + cr) * N_ + n0 + n4);
        ushort4 xo;
        xo.x = f2bf(m4.x + d4.x); xo.y = f2bf(m4.y + d4.y);
        xo.z = f2bf(m4.z + d4.z); xo.w = f2bf(m4.w + d4.w);
        *(ushort4*)(&xl[cr][n4]) = xo;
    }
    __syncthreads();
    const int l = t & 63, tl = t >> 6;     // tl = local tile index 0..3
    const int nl = 16 * tl + (l & 15);
    #pragma unroll
    for (int j = 0; j < 2; ++j) {
        const int kk = (c0 >> 5) + j;
        const int cb = 32 * j + 8 * (l >> 4);
        float f[8];
        #pragma unroll
        for (int i = 0; i < 8; ++i) f[i] = bf2f(xl[cb + i][nl]);
        int d0 = __builtin_amdgcn_cvt_pk_fp8_f32(f[0], f[1], 0, 0);
        d0 = __builtin_amdgcn_cvt_pk_fp8_f32(f[2], f[3], d0, 1);
        int d1 = __builtin_amdgcn_cvt_pk_fp8_f32(f[4], f[5], 0, 0);
        d1 = __builtin_amdgcn_cvt_pk_fp8_f32(f[6], f[7], d1, 1);
        uint* dst = (uint*)(xfrag8 + xfi8(b, (n0 >> 4) + tl, kk) + (size_t)l * 8);
        dst[0] = (uint)d0; dst[1] = (uint)d1;
    }
}

// ---------------------------------------------------------------------------
// K2e v3: compute S once. Writes E^T = fp8(exp(S[n,m]-dg[n])) for NONZERO
// tiles only + zmask; writes sinv[n] = 1/rowsum (softmax normalizer — folded
// into out_e's A-operand). m-stream start STAGGERED per block (ph) so the
// 256 blocks don't sweep identical L2/L3 lines in lockstep. Sum-order change
// is exact for underflow-sparse data (skipped/reordered terms are +0.0f).
// 512 thr (8 waves), grid 256; no loop barriers; bn 1-ahead rotation.
// ---------------------------------------------------------------------------
__global__ __launch_bounds__(512, 2) void lsum_e_kernel(const uchar* __restrict__ xfrag8,
                                                        uchar* __restrict__ E8,
                                                        uchar* __restrict__ zmask,
                                                        float* __restrict__ sinv) {
    __shared__ float red[8][64];
    const int bid = blockIdx.x;
    const int b = (bid >> 1) & 3;
    const int n0 = ((((bid >> 3) << 1) | (bid & 1))) * 64;
    const int t = threadIdx.x, lane = t & 63, w = t >> 6;
    const int l15 = lane & 15, q = lane >> 4;
    const int ph = (bid >> 3) & 31;          // per-block m-stream phase

    long af[4][8];
    #pragma unroll
    for (int ns = 0; ns < 4; ++ns)
        #pragma unroll
        for (int kk = 0; kk < 8; ++kk)
            af[ns][kk] = *(const long*)(xfrag8 + xfi8(b, (n0 >> 4) + ns, kk) + (size_t)lane * 8);

    // diag shift dg = S[n,n] (C/D layout: col=l&15, row=4*(l>>4)+r →
    // diag elem 4q'+r of tile ns lives in lane 20q'+r, reg r)
    float dv[4][4];
    #pragma unroll
    for (int ns = 0; ns < 4; ++ns) {
        f32x4 dacc = {0.f, 0.f, 0.f, 0.f};
        #pragma unroll
        for (int kk = 0; kk < 8; ++kk)
            dacc = mfma8(af[ns][kk], af[ns][kk], dacc);
        #pragma unroll
        for (int r = 0; r < 4; ++r)
            dv[ns][r] = __shfl(dacc[r], 20 * q + r, 64);
    }

    long bn[8];
    #pragma unroll
    for (int kk = 0; kk < 8; ++kk)
        bn[kk] = *(const long*)(xfrag8 + xfi8(b, (ph & 31) * 8 + w, kk) + (size_t)lane * 8);

    const size_t ebl = (size_t)l15 * 8 + 4 * (q & 1);   // lane's byte slot in E8 block
    const int ngb = (n0 >> 3) + (q >> 1);               // lane's base n-group
    const int ncb = n0 >> 6;

    float rs[4][4] = {};
    for (int mc = 0; mc < 32; ++mc) {
        const int cur = ((mc + ph) & 31) * 8 + w;        // this iter's m-tile
        const int nxt = ((mc + 1 + ph) & 31) * 8 + w;    // prefetch (wrap harmless)
        f32x4 a0 = {0.f,0.f,0.f,0.f}, a1 = {0.f,0.f,0.f,0.f};
        f32x4 a2 = {0.f,0.f,0.f,0.f}, a3 = {0.f,0.f,0.f,0.f};
        #pragma unroll
        for (int kk = 0; kk < 8; ++kk) {
            const long bc = bn[kk];
            a0 = mfma8(af[0][kk], bc, a0);
            a1 = mfma8(af[1][kk], bc, a1);
            a2 = mfma8(af[2][kk], bc, a2);
            a3 = mfma8(af[3][kk], bc, a3);
            bn[kk] = *(const long*)(xfrag8 + xfi8(b, nxt, kk) + (size_t)lane * 8);
        }
        uint dpk[4];
#define EEXP(AA, NS)                                                                   \
        {                                                                              \
            float e0 = __expf(AA[0] - dv[NS][0]), e1 = __expf(AA[1] - dv[NS][1]);      \
            float e2 = __expf(AA[2] - dv[NS][2]), e3 = __expf(AA[3] - dv[NS][3]);      \
            rs[NS][0] += e0; rs[NS][1] += e1; rs[NS][2] += e2; rs[NS][3] += e3;        \
            int d = __builtin_amdgcn_cvt_pk_fp8_f32(e0, e1, 0, 0);                     \
            d = __builtin_amdgcn_cvt_pk_fp8_f32(e2, e3, d, 1);                         \
            dpk[NS] = (uint)d;                                                         \
        }
        EEXP(a0, 0) EEXP(a1, 1) EEXP(a2, 2) EEXP(a3, 3)
#undef EEXP
        const uint nzl = dpk[0] | dpk[1] | dpk[2] | dpk[3];
        const bool nz = (__ballot(nzl != 0u) != 0ULL);    // wave-uniform
        if (lane == 0) zmask[zmi(b, ncb, cur)] = nz ? 1 : 0;
        if (nz) {
            #pragma unroll
            for (int ns = 0; ns < 4; ++ns)
                *(uint*)(E8 + eti(b, cur, ngb + 2 * ns) + ebl) = dpk[ns];
        }
    }
    #pragma unroll
    for (int off = 1; off < 16; off <<= 1)
        #pragma unroll
        for (int ns = 0; ns < 4; ++ns)
            #pragma unroll
            for (int r = 0; r < 4; ++r)
                rs[ns][r] += __shfl_xor(rs[ns][r], off, 64);
    if (l15 == 0) {
        #pragma unroll
        for (int ns = 0; ns < 4; ++ns)
            #pragma unroll
            for (int r = 0; r < 4; ++r)
                red[w][16 * ns + 4 * q + r] = rs[ns][r];
    }
    __syncthreads();
    if (t < 64) {
        float s = 0.f;
        #pragma unroll
        for (int ww = 0; ww < 8; ++ww) s += red[ww][t];
        sinv[b * N_ + n0 + t] = 1.0f / s;
    }
}

// ---------------------------------------------------------------------------
// K3e v3: out[c,m] = sum_n (fd[c,n]*sinv[n]) * E[n,m] + fd[c,m], mask-gated.
// A-frags built DIRECTLY from fd32 (no ffrag): lane's 8 k-elems are 8
// consecutive n at fixed c = two float4 loads; multiply by sinv, pack bf16.
// Zero chunks skipped (exact: skipped terms are +0.0f). 512 thr, grid 256.
// ---------------------------------------------------------------------------
__global__ __launch_bounds__(512, 2) void out_e_kernel(const uchar* __restrict__ E8,
                                                       const uchar* __restrict__ zmask,
                                                       const float* __restrict__ sinv,
                                                       const float* __restrict__ fd32,
                                                       float* __restrict__ outp) {
    const int bid = blockIdx.x;
    const int b = (bid >> 1) & 3;
    const int m0 = ((((bid >> 3) << 1) | (bid & 1))) * 64;
    const int t = threadIdx.x, lane = t & 63, w = t >> 6;
    const int l15 = lane & 15, q = lane >> 4;
    const size_t fb = (size_t)b * C_ * N_;
    const uchar* mrow = zmask + zmi(b, 0, m0 >> 4);   // + nc*256 per chunk

    f32x4 acc[2][4];
    #pragma unroll
    for (int ct = 0; ct < 2; ++ct)
        #pragma unroll
        for (int mt = 0; mt < 4; ++mt)
            acc[ct][mt] = (f32x4){0.f, 0.f, 0.f, 0.f};

    for (int g = 0; g < 8; ++g) {
        uint mk[8];
        #pragma unroll
        for (int i = 0; i < 8; ++i)
            mk[i] = *(const uint*)(mrow + (size_t)(8 * g + i) * 256);
        #pragma unroll
        for (int i = 0; i < 8; ++i) {
            if (mk[i] == 0) continue;
            const int nc = 8 * g + i;
            // normalizers for this lane's 8 k-elems, both k2 halves
            const float* sv = sinv + b * N_ + 64 * nc + 8 * q;
            float4 s0[2], s1[2];
            #pragma unroll
            for (int k2 = 0; k2 < 2; ++k2) {
                s0[k2] = *(const float4*)(sv + 32 * k2);
                s1[k2] = *(const float4*)(sv + 32 * k2 + 4);
            }
            short8 fn[2][2];
            #pragma unroll
            for (int ct = 0; ct < 2; ++ct) {
                const int c = 32 * w + 16 * ct + l15;
                const float* frow = fd32 + fb + (size_t)c * N_ + 64 * nc + 8 * q;
                #pragma unroll
                for (int k2 = 0; k2 < 2; ++k2) {
                    const float4 fa = *(const float4*)(frow + 32 * k2);
                    const float4 fb4 = *(const float4*)(frow + 32 * k2 + 4);
                    union { ushort us[8]; short8 v; } u;
                    u.us[0] = f2bf(fa.x * s0[k2].x); u.us[1] = f2bf(fa.y * s0[k2].y);
                    u.us[2] = f2bf(fa.z * s0[k2].z); u.us[3] = f2bf(fa.w * s0[k2].w);
                    u.us[4] = f2bf(fb4.x * s1[k2].x); u.us[5] = f2bf(fb4.y * s1[k2].y);
                    u.us[6] = f2bf(fb4.z * s1[k2].z); u.us[7] = f2bf(fb4.w * s1[k2].w);
                    fn[ct][k2] = u.v;
                }
            }
            #pragma unroll
            for (int k2 = 0; k2 < 2; ++k2) {
                #pragma unroll
                for (int mt = 0; mt < 4; ++mt) {
                    const long e8 = *(const long*)(E8 + eti(b, (m0 >> 4) + mt, 8 * nc + 4 * k2 + q) + (size_t)l15 * 8);
                    const uint lo = (uint)(unsigned long)e8;
                    const uint hi = (uint)((unsigned long)e8 >> 32);
                    const f32x2 f01 = __builtin_amdgcn_cvt_pk_f32_fp8((int)lo, false);
                    const f32x2 f23 = __builtin_amdgcn_cvt_pk_f32_fp8((int)lo, true);
                    const f32x2 f45 = __builtin_amdgcn_cvt_pk_f32_fp8((int)hi, false);
                    const f32x2 f67 = __builtin_amdgcn_cvt_pk_f32_fp8((int)hi, true);
                    union { uint u[4]; short8 v; } be;
                    asm("v_cvt_pk_bf16_f32 %0, %1, %2" : "=v"(be.u[0]) : "v"(f01.x), "v"(f01.y));
                    asm("v_cvt_pk_bf16_f32 %0, %1, %2" : "=v"(be.u[1]) : "v"(f23.x), "v"(f23.y));
                    asm("v_cvt_pk_bf16_f32 %0, %1, %2" : "=v"(be.u[2]) : "v"(f45.x), "v"(f45.y));
                    asm("v_cvt_pk_bf16_f32 %0, %1, %2" : "=v"(be.u[3]) : "v"(f67.x), "v"(f67.y));
                    acc[0][mt] = mfma16(fn[0][k2], be.v, acc[0][mt]);
                    acc[1][mt] = mfma16(fn[1][k2], be.v, acc[1][mt]);
                }
            }
        }
    }
    #pragma unroll
    for (int ct = 0; ct < 2; ++ct)
        #pragma unroll
        for (int mt = 0; mt < 4; ++mt)
            #pragma unroll
            for (int r = 0; r < 4; ++r) {
                const int c = 32 * w + 16 * ct + 4 * q + r;
                const int m = m0 + 16 * mt + l15;
                const size_t o = fb + (size_t)c * N_ + m;
                outp[o] = acc[ct][mt][r] + fd32[o];
            }
}

// ===========================================================================
// FALLBACK PATH (exact round-4 kernels) — used when ws_size < E8 requirement.
// ===========================================================================
__global__ __launch_bounds__(256) void prep_kernel(const float* __restrict__ fm,
                                                   const float* __restrict__ fd,
                                                   uchar* __restrict__ xfrag8,
                                                   ushort* __restrict__ ffrag) {
    __shared__ ushort xl[64][LDX];
    __shared__ ushort fl[64][LDX];
    const int b = blockIdx.z, c0 = blockIdx.y * 64, n0 = blockIdx.x * 64;
    const int t = threadIdx.x;
    const int n4 = (t & 15) * 4, cl = t >> 4;
    const size_t base = (size_t)b * C_ * N_;
    #pragma unroll
    for (int p = 0; p < 4; ++p) {
        const int cr = 16 * p + cl;
        const float4 m4 = *(const float4*)(fm + base + (size_t)(c0 + cr) * N_ + n0 + n4);
        const float4 d4 = *(const float4*)(fd + base + (size_t)(c0 + cr) * N_ + n0 + n4);
        ushort4 fo;
        fo.x = f2bf(d4.x); fo.y = f2bf(d4.y); fo.z = f2bf(d4.z); fo.w = f2bf(d4.w);
        *(ushort4*)(&fl[cr][n4]) = fo;
        ushort4 xo;
        xo.x = f2bf(m4.x + d4.x); xo.y = f2bf(m4.y + d4.y);
        xo.z = f2bf(m4.z + d4.z); xo.w = f2bf(m4.w + d4.w);
        *(ushort4*)(&xl[cr][n4]) = xo;
    }
    __syncthreads();
    const int l = t & 63, tl = t >> 6;
    {
        const int nl = 16 * tl + (l & 15);
        #pragma unroll
        for (int j = 0; j < 2; ++j) {
            const int kk = (c0 >> 5) + j;
            const int cb = 32 * j + 8 * (l >> 4);
            float f[8];
            #pragma unroll
            for (int i = 0; i < 8; ++i) f[i] = bf2f(xl[cb + i][nl]);
            int d0 = __builtin_amdgcn_cvt_pk_fp8_f32(f[0], f[1], 0, 0);
            d0 = __builtin_amdgcn_cvt_pk_fp8_f32(f[2], f[3], d0, 1);
            int d1 = __builtin_amdgcn_cvt_pk_fp8_f32(f[4], f[5], 0, 0);
            d1 = __builtin_amdgcn_cvt_pk_fp8_f32(f[6], f[7], d1, 1);
            uint* dst = (uint*)(xfrag8 + xfi8(b, (n0 >> 4) + tl, kk) + (size_t)l * 8);
            dst[0] = (uint)d0; dst[1] = (uint)d1;
        }
    }
    {
        const int row = 16 * tl + (l & 15);
        #pragma unroll
        for (int k2 = 0; k2 < 2; ++k2) {
            const int col = 32 * k2 + 8 * (l >> 4);
            const ushort4 a0 = *(const ushort4*)(&fl[row][col]);
            const ushort4 a1 = *(const ushort4*)(&fl[row][col + 4]);
            ushort* dst = ffrag + ffi(b, n0 >> 6, (c0 >> 4) + tl, k2) + l * 8;
            *(ushort4*)(dst) = a0; *(ushort4*)(dst + 4) = a1;
        }
    }
}

__global__ __launch_bounds__(512, 2) void lsum_g_kernel(const uchar* __restrict__ xfrag8,
                                                        float* __restrict__ lg) {
    __shared__ float red[8][64];
    __shared__ float dgl[64];
    const int bid = blockIdx.x;
    const int b = (bid >> 1) & 3;
    const int n0 = ((((bid >> 3) << 1) | (bid & 1))) * 64;
    const int t = threadIdx.x, lane = t & 63, w = t >> 6;
    const int l15 = lane & 15, q = lane >> 4;

    long af[4][8];
    #pragma unroll
    for (int ns = 0; ns < 4; ++ns)
        #pragma unroll
        for (int kk = 0; kk < 8; ++kk)
            af[ns][kk] = *(const long*)(xfrag8 + xfi8(b, (n0 >> 4) + ns, kk) + (size_t)lane * 8);

    float dv[4][4];
    #pragma unroll
    for (int ns = 0; ns < 4; ++ns) {
        f32x4 dacc = {0.f, 0.f, 0.f, 0.f};
        #pragma unroll
        for (int kk = 0; kk < 8; ++kk)
            dacc = mfma8(af[ns][kk], af[ns][kk], dacc);
        #pragma unroll
        for (int r = 0; r < 4; ++r)
            dv[ns][r] = __shfl(dacc[r], 20 * q + r, 64);
    }
    if (w == 0 && l15 == 0) {
        #pragma unroll
        for (int ns = 0; ns < 4; ++ns)
            #pragma unroll
            for (int r = 0; r < 4; ++r)
                dgl[16 * ns + 4 * q + r] = dv[ns][r];
    }

    long bn[8];
    #pragma unroll
    for (int kk = 0; kk < 8; ++kk)
        bn[kk] = *(const long*)(xfrag8 + xfi8(b, w, kk) + (size_t)lane * 8);

    float rs[4][4] = {};
    for (int mc = 0; mc < 32; ++mc) {
        const int mtn = (mc + 1 < 32) ? (mc + 1) * 8 + w : w;
        f32x4 a0 = {0.f,0.f,0.f,0.f}, a1 = {0.f,0.f,0.f,0.f};
        f32x4 a2 = {0.f,0.f,0.f,0.f}, a3 = {0.f,0.f,0.f,0.f};
        #pragma unroll
        for (int kk = 0; kk < 8; ++kk) {
            const long bc = bn[kk];
            a0 = mfma8(af[0][kk], bc, a0);
            a1 = mfma8(af[1][kk], bc, a1);
            a2 = mfma8(af[2][kk], bc, a2);
            a3 = mfma8(af[3][kk], bc, a3);
            bn[kk] = *(const long*)(xfrag8 + xfi8(b, mtn, kk) + (size_t)lane * 8);
        }
        #pragma unroll
        for (int r = 0; r < 4; ++r) {
            rs[0][r] += __expf(a0[r] - dv[0][r]);
            rs[1][r] += __expf(a1[r] - dv[1][r]);
            rs[2][r] += __expf(a2[r] - dv[2][r]);
            rs[3][r] += __expf(a3[r] - dv[3][r]);
        }
    }
    #pragma unroll
    for (int off = 1; off < 16; off <<= 1)
        #pragma unroll
        for (int ns = 0; ns < 4; ++ns)
            #pragma unroll
            for (int r = 0; r < 4; ++r)
                rs[ns][r] += __shfl_xor(rs[ns][r], off, 64);
    if (l15 == 0) {
        #pragma unroll
        for (int ns = 0; ns < 4; ++ns)
            #pragma unroll
            for (int r = 0; r < 4; ++r)
                red[w][16 * ns + 4 * q + r] = rs[ns][r];
    }
    __syncthreads();
    if (t < 64) {
        float s = 0.f;
        #pragma unroll
        for (int ww = 0; ww < 8; ++ww) s += red[ww][t];
        lg[b * N_ + n0 + t] = dgl[t] + __logf(s);
    }
}

__global__ __launch_bounds__(512, 2) void out_g_kernel(const uchar* __restrict__ xfrag8,
                                                       const ushort* __restrict__ ffrag,
                                                       const float* __restrict__ gg,
                                                       const float* __restrict__ fd32,
                                                       float* __restrict__ outp) {
    __shared__ ushort ET[2][64][LDE];
    const int bid = blockIdx.x;
    const int b = (bid >> 1) & 3;
    const int m0 = ((((bid >> 3) << 1) | (bid & 1))) * 64;
    const int t = threadIdx.x, lane = t & 63, w = t >> 6;
    const int l15 = lane & 15, q = lane >> 4;
    const int a = w & 3, h = w >> 2;
    const size_t fb = (size_t)b * C_ * N_;

    long bfr[2][8];
    #pragma unroll
    for (int jt = 0; jt < 2; ++jt)
        #pragma unroll
        for (int kk = 0; kk < 8; ++kk)
            bfr[jt][kk] = *(const long*)(xfrag8 + xfi8(b, (m0 >> 4) + 2 * h + jt, kk) + (size_t)lane * 8);

    f32x4 acc[2][4];
    #pragma unroll
    for (int ct = 0; ct < 2; ++ct)
        #pragma unroll
        for (int mt = 0; mt < 4; ++mt)
            acc[ct][mt] = (f32x4){0.f, 0.f, 0.f, 0.f};

    long an[8];
    #pragma unroll
    for (int kk = 0; kk < 8; ++kk)
        an[kk] = *(const long*)(xfrag8 + xfi8(b, a, kk) + (size_t)lane * 8);
    float gn[4];
    #pragma unroll
    for (int r = 0; r < 4; ++r) gn[r] = gg[b * N_ + 16 * a + 4 * q + r];

    int p = 0;
    for (int n0c = 0; n0c < N_; n0c += 64, p ^= 1) {
        const int nc = n0c >> 6;
        short8 fn[2][2];
        #pragma unroll
        for (int ct = 0; ct < 2; ++ct)
            #pragma unroll
            for (int k2 = 0; k2 < 2; ++k2)
                fn[ct][k2] = *(const short8*)(ffrag + ffi(b, nc, 2 * w + ct, k2) + lane * 8);
        float gv[4];
        #pragma unroll
        for (int r = 0; r < 4; ++r) gv[r] = gn[r];
        const int nx = (n0c + 64 < N_) ? n0c + 64 : 0;
        #pragma unroll
        for (int r = 0; r < 4; ++r) gn[r] = gg[b * N_ + nx + 16 * a + 4 * q + r];

        f32x4 s0 = {0.f, 0.f, 0.f, 0.f}, s1 = {0.f, 0.f, 0.f, 0.f};
        #pragma unroll
        for (int kk = 0; kk < 8; ++kk) {
            s0 = mfma8(an[kk], bfr[0][kk], s0);
            s1 = mfma8(an[kk], bfr[1][kk], s1);
            an[kk] = *(const long*)(xfrag8 + xfi8(b, (nx >> 4) + a, kk) + (size_t)lane * 8);
        }
        ushort4 e0, e1;
        e0.x = f2bf(__expf(s0[0] - gv[0])); e0.y = f2bf(__expf(s0[1] - gv[1]));
        e0.z = f2bf(__expf(s0[2] - gv[2])); e0.w = f2bf(__expf(s0[3] - gv[3]));
        e1.x = f2bf(__expf(s1[0] - gv[0])); e1.y = f2bf(__expf(s1[1] - gv[1]));
        e1.z = f2bf(__expf(s1[2] - gv[2])); e1.w = f2bf(__expf(s1[3] - gv[3]));
        *(ushort4*)(&ET[p][32 * h + l15][16 * a + 4 * q])      = e0;
        *(ushort4*)(&ET[p][32 * h + 16 + l15][16 * a + 4 * q]) = e1;

        asm volatile("s_waitcnt lgkmcnt(0)\n\ts_barrier" ::: "memory");

        #pragma unroll
        for (int k2 = 0; k2 < 2; ++k2) {
            #pragma unroll
            for (int mt = 0; mt < 4; ++mt) {
                const short8 be = *(const short8*)(&ET[p][16 * mt + l15][32 * k2 + 8 * q]);
                acc[0][mt] = mfma16(fn[0][k2], be, acc[0][mt]);
                acc[1][mt] = mfma16(fn[1][k2], be, acc[1][mt]);
            }
        }
    }
    #pragma unroll
    for (int ct = 0; ct < 2; ++ct)
        #pragma unroll
        for (int mt = 0; mt < 4; ++mt)
            #pragma unroll
            for (int r = 0; r < 4; ++r) {
                const int c = 32 * w + 16 * ct + 4 * q + r;
                const int m = m0 + 16 * mt + l15;
                const size_t o = fb + (size_t)c * N_ + m;
                outp[o] = acc[ct][mt][r] + fd32[o];
            }
}

// ---------------------------------------------------------------------------
extern "C" void kernel_launch(void* const* d_in, const int* in_sizes, int n_in,
                              void* d_out, int out_size, void* d_ws, size_t ws_size,
                              hipStream_t stream) {
    const float* fm = (const float*)d_in[0];
    const float* fd = (const float*)d_in[1];
    float* outp = (float*)d_out;

    const size_t xb_elts = (size_t)B_ * N_ * C_;                 // 4.19M
    const size_t e_bytes = (size_t)B_ * N_ * N_;                 // 67.1 MB (fp8 E^T)
    const size_t z_bytes = (size_t)B_ * 64 * 256;                // 64 KB (zmask)
    const size_t s_bytes = (size_t)B_ * N_ * 4;                  // 64 KB (sinv)
    const size_t need_e  = xb_elts + e_bytes + z_bytes + s_bytes; // ~71.5 MB
    const size_t need_g  = xb_elts * 3 + (size_t)B_ * N_ * 4;    // ~12.6 MB

    uchar* xfrag8 = (uchar*)d_ws;                     // fp8, 4.19 MB

    if (ws_size >= need_e) {
        uchar* E8    = xfrag8 + xb_elts;
        uchar* zmask = E8 + e_bytes;
        float* sinv  = (float*)(zmask + z_bytes);
        prep_x_kernel<<<dim3(N_ / 64, C_ / 64, B_), 256, 0, stream>>>(fm, fd, xfrag8);
        lsum_e_kernel<<<dim3(256), 512, 0, stream>>>(xfrag8, E8, zmask, sinv);
        out_e_kernel<<<dim3(256), 512, 0, stream>>>(E8, zmask, sinv, fd, outp);
    } else if (ws_size >= need_g) {
        ushort* ffrag = (ushort*)(xfrag8 + xb_elts);
        float*  lg    = (float*)(xfrag8 + xb_elts * 3);
        prep_kernel<<<dim3(N_ / 64, C_ / 64, B_), 256, 0, stream>>>(fm, fd, xfrag8, ffrag);
        lsum_g_kernel<<<dim3(256), 512, 0, stream>>>(xfrag8, lg);
        out_g_kernel<<<dim3(256), 512, 0, stream>>>(xfrag8, ffrag, lg, fd, outp);
    }
}

// Round 8
// 121.565 us; speedup vs baseline: 1.6054x; 1.0173x over previous
//
#include <hip/hip_runtime.h>
#include <math.h>

#define B_ 4
#define C_ 256
#define N_ 4096   // H*W
#define LDE 68    // ET row stride (ushorts) — verified, 0 conflicts (fallback path)
#define LDX 72    // prep LDS tile stride (ushorts)

typedef __attribute__((ext_vector_type(8))) short short8;
typedef __attribute__((ext_vector_type(4))) float f32x4;
typedef __attribute__((ext_vector_type(2))) float f32x2;

__device__ inline ushort f2bf(float f) {
    uint u = __float_as_uint(f);
    return (ushort)((u + 0x7fffu + ((u >> 16) & 1u)) >> 16);   // RNE
}
__device__ inline float bf2f(ushort h) { return __uint_as_float(((uint)h) << 16); }

__device__ inline f32x4 mfma16(short8 a, short8 b, f32x4 c) {
    return __builtin_amdgcn_mfma_f32_16x16x32_bf16(a, b, c, 0, 0, 0);
}
__device__ inline f32x4 mfma8(long a, long b, f32x4 c) {
    return __builtin_amdgcn_mfma_f32_16x16x32_fp8_fp8(a, b, c, 0, 0, 0);
}

// Fragment-order layouts (lane l <-> (row l&15, k-group l>>4)):
//   xfrag8[b][nt=0..255][kk=0..7][lane][8 fp8]      (X = fp8(fm+fd), k=c, 512 B/tile)
//   E8    [b][mt=0..255][ng=0..511][ml=0..15][8]    (E^T fp8: (b, m=16mt+ml, n=8ng+i))
//   zmask [b][nc=0..63][mt=0..255]                  (1 iff E-tile (16m x 64n) nonzero)
//   sinv  [b][n]                                    (1 / sum_m exp(S[n,m]-S[n,n]))
//   ffrag [b][nc][ct][k2][lane][8]                  (Fd bf16 — FALLBACK path only)
__device__ inline size_t xfi8(int b, int nt, int kk) {   // BYTE offset
    return (((size_t)(b * 256 + nt)) * 8 + kk) * 512;
}
__device__ inline size_t ffi(int b, int nc, int ct, int k2) {   // ushort offset
    return ((((size_t)(b * 64 + nc)) * 16 + ct) * 2 + k2) * 512;
}
__device__ inline size_t eti(int b, int mt, int ng) {    // BYTE offset
    return (((size_t)(b * 256 + mt)) * 512 + (size_t)ng) * 128;
}
__device__ inline size_t zmi(int b, int nc, int mt) {    // BYTE offset
    return ((size_t)(b * 64 + nc)) * 256 + mt;
}

// ---------------------------------------------------------------------------
// P0x (e-path): build xfrag8 only. No ffrag (out_e reads fd32 directly for
// its sparse chunks), no dg (diag shift computed in lsum from the fp8 Gram).
// ---------------------------------------------------------------------------
__global__ __launch_bounds__(256) void prep_x_kernel(const float* __restrict__ fm,
                                                     const float* __restrict__ fd,
                                                     uchar* __restrict__ xfrag8) {
    __shared__ ushort xl[64][LDX];   // [c-local][n-local] bf16 X
    const int b = blockIdx.z, c0 = blockIdx.y * 64, n0 = blockIdx.x * 64;
    const int t = threadIdx.x;
    const int n4 = (t & 15) * 4, cl = t >> 4;
    const size_t base = (size_t)b * C_ * N_;
    #pragma unroll
    for (int p = 0; p < 4; ++p) {
        const int cr = 16 * p + cl;
        const float4 m4 = *(const float4*)(fm + base + (size_t)(c0 + cr) * N_ + n0 + n4);
        const float4 d4 = *(const float4*)(fd + base + (size_t)(c0 + cr) * N_ + n0 + n4);
        ushort4 xo;
        xo.x = f2bf(m4.x + d4.x); xo.y = f2bf(m4.y + d4.y);
        xo.z = f2bf(m4.z + d4.z); xo.w = f2bf(m4.w + d4.w);
        *(ushort4*)(&xl[cr][n4]) = xo;
    }
    __syncthreads();
    const int l = t & 63, tl = t >> 6;     // tl = local tile index 0..3
    const int nl = 16 * tl + (l & 15);
    #pragma unroll
    for (int j = 0; j < 2; ++j) {
        const int kk = (c0 >> 5) + j;
        const int cb = 32 * j + 8 * (l >> 4);
        float f[8];
        #pragma unroll
        for (int i = 0; i < 8; ++i) f[i] = bf2f(xl[cb + i][nl]);
        int d0 = __builtin_amdgcn_cvt_pk_fp8_f32(f[0], f[1], 0, 0);
        d0 = __builtin_amdgcn_cvt_pk_fp8_f32(f[2], f[3], d0, 1);
        int d1 = __builtin_amdgcn_cvt_pk_fp8_f32(f[4], f[5], 0, 0);
        d1 = __builtin_amdgcn_cvt_pk_fp8_f32(f[6], f[7], d1, 1);
        uint* dst = (uint*)(xfrag8 + xfi8(b, (n0 >> 4) + tl, kk) + (size_t)l * 8);
        dst[0] = (uint)d0; dst[1] = (uint)d1;
    }
}

// ---------------------------------------------------------------------------
// K2e v4: compute S once. NEW: wave-uniform exp-skip — after the MFMA block,
// a fmax-tree + __ballot detects tiles where ALL S-dg <= -30: exp underflows
// below fp8's min subnormal (E=0 exactly) and the rs delta is < 1/2 ulp of
// the 1.0 diagonal term, so skipping {exp, rs, cvt, store} is bit-exact.
// ~97% of tiles skip on real data; degenerate inputs just run dense.
// s_setprio(1) around MFMA cluster (independently-phased waves).
// 512 thr (8 waves), grid 256; no loop barriers; bn 1-ahead rotation.
// ---------------------------------------------------------------------------
__global__ __launch_bounds__(512, 2) void lsum_e_kernel(const uchar* __restrict__ xfrag8,
                                                        uchar* __restrict__ E8,
                                                        uchar* __restrict__ zmask,
                                                        float* __restrict__ sinv) {
    __shared__ float red[8][64];
    const int bid = blockIdx.x;
    const int b = (bid >> 1) & 3;
    const int n0 = ((((bid >> 3) << 1) | (bid & 1))) * 64;
    const int t = threadIdx.x, lane = t & 63, w = t >> 6;
    const int l15 = lane & 15, q = lane >> 4;
    const int ph = (bid >> 3) & 31;          // per-block m-stream phase

    long af[4][8];
    #pragma unroll
    for (int ns = 0; ns < 4; ++ns)
        #pragma unroll
        for (int kk = 0; kk < 8; ++kk)
            af[ns][kk] = *(const long*)(xfrag8 + xfi8(b, (n0 >> 4) + ns, kk) + (size_t)lane * 8);

    // diag shift dg = S[n,n] (C/D layout: col=l&15, row=4*(l>>4)+r →
    // diag elem 4q'+r of tile ns lives in lane 20q'+r, reg r)
    float dv[4][4];
    #pragma unroll
    for (int ns = 0; ns < 4; ++ns) {
        f32x4 dacc = {0.f, 0.f, 0.f, 0.f};
        #pragma unroll
        for (int kk = 0; kk < 8; ++kk)
            dacc = mfma8(af[ns][kk], af[ns][kk], dacc);
        #pragma unroll
        for (int r = 0; r < 4; ++r)
            dv[ns][r] = __shfl(dacc[r], 20 * q + r, 64);
    }

    long bn[8];
    #pragma unroll
    for (int kk = 0; kk < 8; ++kk)
        bn[kk] = *(const long*)(xfrag8 + xfi8(b, (ph & 31) * 8 + w, kk) + (size_t)lane * 8);

    const size_t ebl = (size_t)l15 * 8 + 4 * (q & 1);   // lane's byte slot in E8 block
    const int ngb = (n0 >> 3) + (q >> 1);               // lane's base n-group
    const int ncb = n0 >> 6;

    float rs[4][4] = {};
    for (int mc = 0; mc < 32; ++mc) {
        const int cur = ((mc + ph) & 31) * 8 + w;        // this iter's m-tile
        const int nxt = ((mc + 1 + ph) & 31) * 8 + w;    // prefetch (wrap harmless)
        f32x4 a0 = {0.f,0.f,0.f,0.f}, a1 = {0.f,0.f,0.f,0.f};
        f32x4 a2 = {0.f,0.f,0.f,0.f}, a3 = {0.f,0.f,0.f,0.f};
        __builtin_amdgcn_s_setprio(1);
        #pragma unroll
        for (int kk = 0; kk < 8; ++kk) {
            const long bc = bn[kk];
            a0 = mfma8(af[0][kk], bc, a0);
            a1 = mfma8(af[1][kk], bc, a1);
            a2 = mfma8(af[2][kk], bc, a2);
            a3 = mfma8(af[3][kk], bc, a3);
            bn[kk] = *(const long*)(xfrag8 + xfi8(b, nxt, kk) + (size_t)lane * 8);
        }
        __builtin_amdgcn_s_setprio(0);
        // diffs (needed for both predicate and exp)
        float df[4][4];
#define EDF(AA, NS)                                                    \
        df[NS][0] = AA[0] - dv[NS][0]; df[NS][1] = AA[1] - dv[NS][1];  \
        df[NS][2] = AA[2] - dv[NS][2]; df[NS][3] = AA[3] - dv[NS][3];
        EDF(a0, 0) EDF(a1, 1) EDF(a2, 2) EDF(a3, 3)
#undef EDF
        const float mx = fmaxf(
            fmaxf(fmaxf(fmaxf(df[0][0], df[0][1]), fmaxf(df[0][2], df[0][3])),
                  fmaxf(fmaxf(df[1][0], df[1][1]), fmaxf(df[1][2], df[1][3]))),
            fmaxf(fmaxf(fmaxf(df[2][0], df[2][1]), fmaxf(df[2][2], df[2][3])),
                  fmaxf(fmaxf(df[3][0], df[3][1]), fmaxf(df[3][2], df[3][3]))));
        const bool nz = (__ballot(mx > -30.0f) != 0ULL);   // wave-uniform
        if (lane == 0) zmask[zmi(b, ncb, cur)] = nz ? 1 : 0;
        if (nz) {
            uint dpk[4];
#define EEXP(NS)                                                                       \
            {                                                                          \
                float e0 = __expf(df[NS][0]), e1 = __expf(df[NS][1]);                  \
                float e2 = __expf(df[NS][2]), e3 = __expf(df[NS][3]);                  \
                rs[NS][0] += e0; rs[NS][1] += e1; rs[NS][2] += e2; rs[NS][3] += e3;    \
                int d = __builtin_amdgcn_cvt_pk_fp8_f32(e0, e1, 0, 0);                 \
                d = __builtin_amdgcn_cvt_pk_fp8_f32(e2, e3, d, 1);                     \
                dpk[NS] = (uint)d;                                                     \
            }
            EEXP(0) EEXP(1) EEXP(2) EEXP(3)
#undef EEXP
            #pragma unroll
            for (int ns = 0; ns < 4; ++ns)
                *(uint*)(E8 + eti(b, cur, ngb + 2 * ns) + ebl) = dpk[ns];
        }
    }
    #pragma unroll
    for (int off = 1; off < 16; off <<= 1)
        #pragma unroll
        for (int ns = 0; ns < 4; ++ns)
            #pragma unroll
            for (int r = 0; r < 4; ++r)
                rs[ns][r] += __shfl_xor(rs[ns][r], off, 64);
    if (l15 == 0) {
        #pragma unroll
        for (int ns = 0; ns < 4; ++ns)
            #pragma unroll
            for (int r = 0; r < 4; ++r)
                red[w][16 * ns + 4 * q + r] = rs[ns][r];
    }
    __syncthreads();
    if (t < 64) {
        float s = 0.f;
        #pragma unroll
        for (int ww = 0; ww < 8; ++ww) s += red[ww][t];
        sinv[b * N_ + n0 + t] = 1.0f / s;
    }
}

// ---------------------------------------------------------------------------
// K3e v3: out[c,m] = sum_n (fd[c,n]*sinv[n]) * E[n,m] + fd[c,m], mask-gated.
// A-frags built DIRECTLY from fd32 (no ffrag): lane's 8 k-elems are 8
// consecutive n at fixed c = two float4 loads; multiply by sinv, pack bf16.
// Zero chunks skipped (exact: skipped terms are +0.0f). 512 thr, grid 256.
// ---------------------------------------------------------------------------
__global__ __launch_bounds__(512, 2) void out_e_kernel(const uchar* __restrict__ E8,
                                                       const uchar* __restrict__ zmask,
                                                       const float* __restrict__ sinv,
                                                       const float* __restrict__ fd32,
                                                       float* __restrict__ outp) {
    const int bid = blockIdx.x;
    const int b = (bid >> 1) & 3;
    const int m0 = ((((bid >> 3) << 1) | (bid & 1))) * 64;
    const int t = threadIdx.x, lane = t & 63, w = t >> 6;
    const int l15 = lane & 15, q = lane >> 4;
    const size_t fb = (size_t)b * C_ * N_;
    const uchar* mrow = zmask + zmi(b, 0, m0 >> 4);   // + nc*256 per chunk

    f32x4 acc[2][4];
    #pragma unroll
    for (int ct = 0; ct < 2; ++ct)
        #pragma unroll
        for (int mt = 0; mt < 4; ++mt)
            acc[ct][mt] = (f32x4){0.f, 0.f, 0.f, 0.f};

    for (int g = 0; g < 8; ++g) {
        uint mk[8];
        #pragma unroll
        for (int i = 0; i < 8; ++i)
            mk[i] = *(const uint*)(mrow + (size_t)(8 * g + i) * 256);
        #pragma unroll
        for (int i = 0; i < 8; ++i) {
            if (mk[i] == 0) continue;
            const int nc = 8 * g + i;
            // normalizers for this lane's 8 k-elems, both k2 halves
            const float* sv = sinv + b * N_ + 64 * nc + 8 * q;
            float4 s0[2], s1[2];
            #pragma unroll
            for (int k2 = 0; k2 < 2; ++k2) {
                s0[k2] = *(const float4*)(sv + 32 * k2);
                s1[k2] = *(const float4*)(sv + 32 * k2 + 4);
            }
            short8 fn[2][2];
            #pragma unroll
            for (int ct = 0; ct < 2; ++ct) {
                const int c = 32 * w + 16 * ct + l15;
                const float* frow = fd32 + fb + (size_t)c * N_ + 64 * nc + 8 * q;
                #pragma unroll
                for (int k2 = 0; k2 < 2; ++k2) {
                    const float4 fa = *(const float4*)(frow + 32 * k2);
                    const float4 fb4 = *(const float4*)(frow + 32 * k2 + 4);
                    union { ushort us[8]; short8 v; } u;
                    u.us[0] = f2bf(fa.x * s0[k2].x); u.us[1] = f2bf(fa.y * s0[k2].y);
                    u.us[2] = f2bf(fa.z * s0[k2].z); u.us[3] = f2bf(fa.w * s0[k2].w);
                    u.us[4] = f2bf(fb4.x * s1[k2].x); u.us[5] = f2bf(fb4.y * s1[k2].y);
                    u.us[6] = f2bf(fb4.z * s1[k2].z); u.us[7] = f2bf(fb4.w * s1[k2].w);
                    fn[ct][k2] = u.v;
                }
            }
            #pragma unroll
            for (int k2 = 0; k2 < 2; ++k2) {
                #pragma unroll
                for (int mt = 0; mt < 4; ++mt) {
                    const long e8 = *(const long*)(E8 + eti(b, (m0 >> 4) + mt, 8 * nc + 4 * k2 + q) + (size_t)l15 * 8);
                    const uint lo = (uint)(unsigned long)e8;
                    const uint hi = (uint)((unsigned long)e8 >> 32);
                    const f32x2 f01 = __builtin_amdgcn_cvt_pk_f32_fp8((int)lo, false);
                    const f32x2 f23 = __builtin_amdgcn_cvt_pk_f32_fp8((int)lo, true);
                    const f32x2 f45 = __builtin_amdgcn_cvt_pk_f32_fp8((int)hi, false);
                    const f32x2 f67 = __builtin_amdgcn_cvt_pk_f32_fp8((int)hi, true);
                    union { uint u[4]; short8 v; } be;
                    asm("v_cvt_pk_bf16_f32 %0, %1, %2" : "=v"(be.u[0]) : "v"(f01.x), "v"(f01.y));
                    asm("v_cvt_pk_bf16_f32 %0, %1, %2" : "=v"(be.u[1]) : "v"(f23.x), "v"(f23.y));
                    asm("v_cvt_pk_bf16_f32 %0, %1, %2" : "=v"(be.u[2]) : "v"(f45.x), "v"(f45.y));
                    asm("v_cvt_pk_bf16_f32 %0, %1, %2" : "=v"(be.u[3]) : "v"(f67.x), "v"(f67.y));
                    acc[0][mt] = mfma16(fn[0][k2], be.v, acc[0][mt]);
                    acc[1][mt] = mfma16(fn[1][k2], be.v, acc[1][mt]);
                }
            }
        }
    }
    #pragma unroll
    for (int ct = 0; ct < 2; ++ct)
        #pragma unroll
        for (int mt = 0; mt < 4; ++mt)
            #pragma unroll
            for (int r = 0; r < 4; ++r) {
                const int c = 32 * w + 16 * ct + 4 * q + r;
                const int m = m0 + 16 * mt + l15;
                const size_t o = fb + (size_t)c * N_ + m;
                outp[o] = acc[ct][mt][r] + fd32[o];
            }
}

// ===========================================================================
// FALLBACK PATH (exact round-4 kernels) — used when ws_size < E8 requirement.
// ===========================================================================
__global__ __launch_bounds__(256) void prep_kernel(const float* __restrict__ fm,
                                                   const float* __restrict__ fd,
                                                   uchar* __restrict__ xfrag8,
                                                   ushort* __restrict__ ffrag) {
    __shared__ ushort xl[64][LDX];
    __shared__ ushort fl[64][LDX];
    const int b = blockIdx.z, c0 = blockIdx.y * 64, n0 = blockIdx.x * 64;
    const int t = threadIdx.x;
    const int n4 = (t & 15) * 4, cl = t >> 4;
    const size_t base = (size_t)b * C_ * N_;
    #pragma unroll
    for (int p = 0; p < 4; ++p) {
        const int cr = 16 * p + cl;
        const float4 m4 = *(const float4*)(fm + base + (size_t)(c0 + cr) * N_ + n0 + n4);
        const float4 d4 = *(const float4*)(fd + base + (size_t)(c0 + cr) * N_ + n0 + n4);
        ushort4 fo;
        fo.x = f2bf(d4.x); fo.y = f2bf(d4.y); fo.z = f2bf(d4.z); fo.w = f2bf(d4.w);
        *(ushort4*)(&fl[cr][n4]) = fo;
        ushort4 xo;
        xo.x = f2bf(m4.x + d4.x); xo.y = f2bf(m4.y + d4.y);
        xo.z = f2bf(m4.z + d4.z); xo.w = f2bf(m4.w + d4.w);
        *(ushort4*)(&xl[cr][n4]) = xo;
    }
    __syncthreads();
    const int l = t & 63, tl = t >> 6;
    {
        const int nl = 16 * tl + (l & 15);
        #pragma unroll
        for (int j = 0; j < 2; ++j) {
            const int kk = (c0 >> 5) + j;
            const int cb = 32 * j + 8 * (l >> 4);
            float f[8];
            #pragma unroll
            for (int i = 0; i < 8; ++i) f[i] = bf2f(xl[cb + i][nl]);
            int d0 = __builtin_amdgcn_cvt_pk_fp8_f32(f[0], f[1], 0, 0);
            d0 = __builtin_amdgcn_cvt_pk_fp8_f32(f[2], f[3], d0, 1);
            int d1 = __builtin_amdgcn_cvt_pk_fp8_f32(f[4], f[5], 0, 0);
            d1 = __builtin_amdgcn_cvt_pk_fp8_f32(f[6], f[7], d1, 1);
            uint* dst = (uint*)(xfrag8 + xfi8(b, (n0 >> 4) + tl, kk) + (size_t)l * 8);
            dst[0] = (uint)d0; dst[1] = (uint)d1;
        }
    }
    {
        const int row = 16 * tl + (l & 15);
        #pragma unroll
        for (int k2 = 0; k2 < 2; ++k2) {
            const int col = 32 * k2 + 8 * (l >> 4);
            const ushort4 a0 = *(const ushort4*)(&fl[row][col]);
            const ushort4 a1 = *(const ushort4*)(&fl[row][col + 4]);
            ushort* dst = ffrag + ffi(b, n0 >> 6, (c0 >> 4) + tl, k2) + l * 8;
            *(ushort4*)(dst) = a0; *(ushort4*)(dst + 4) = a1;
        }
    }
}

__global__ __launch_bounds__(512, 2) void lsum_g_kernel(const uchar* __restrict__ xfrag8,
                                                        float* __restrict__ lg) {
    __shared__ float red[8][64];
    __shared__ float dgl[64];
    const int bid = blockIdx.x;
    const int b = (bid >> 1) & 3;
    const int n0 = ((((bid >> 3) << 1) | (bid & 1))) * 64;
    const int t = threadIdx.x, lane = t & 63, w = t >> 6;
    const int l15 = lane & 15, q = lane >> 4;

    long af[4][8];
    #pragma unroll
    for (int ns = 0; ns < 4; ++ns)
        #pragma unroll
        for (int kk = 0; kk < 8; ++kk)
            af[ns][kk] = *(const long*)(xfrag8 + xfi8(b, (n0 >> 4) + ns, kk) + (size_t)lane * 8);

    float dv[4][4];
    #pragma unroll
    for (int ns = 0; ns < 4; ++ns) {
        f32x4 dacc = {0.f, 0.f, 0.f, 0.f};
        #pragma unroll
        for (int kk = 0; kk < 8; ++kk)
            dacc = mfma8(af[ns][kk], af[ns][kk], dacc);
        #pragma unroll
        for (int r = 0; r < 4; ++r)
            dv[ns][r] = __shfl(dacc[r], 20 * q + r, 64);
    }
    if (w == 0 && l15 == 0) {
        #pragma unroll
        for (int ns = 0; ns < 4; ++ns)
            #pragma unroll
            for (int r = 0; r < 4; ++r)
                dgl[16 * ns + 4 * q + r] = dv[ns][r];
    }

    long bn[8];
    #pragma unroll
    for (int kk = 0; kk < 8; ++kk)
        bn[kk] = *(const long*)(xfrag8 + xfi8(b, w, kk) + (size_t)lane * 8);

    float rs[4][4] = {};
    for (int mc = 0; mc < 32; ++mc) {
        const int mtn = (mc + 1 < 32) ? (mc + 1) * 8 + w : w;
        f32x4 a0 = {0.f,0.f,0.f,0.f}, a1 = {0.f,0.f,0.f,0.f};
        f32x4 a2 = {0.f,0.f,0.f,0.f}, a3 = {0.f,0.f,0.f,0.f};
        #pragma unroll
        for (int kk = 0; kk < 8; ++kk) {
            const long bc = bn[kk];
            a0 = mfma8(af[0][kk], bc, a0);
            a1 = mfma8(af[1][kk], bc, a1);
            a2 = mfma8(af[2][kk], bc, a2);
            a3 = mfma8(af[3][kk], bc, a3);
            bn[kk] = *(const long*)(xfrag8 + xfi8(b, mtn, kk) + (size_t)lane * 8);
        }
        #pragma unroll
        for (int r = 0; r < 4; ++r) {
            rs[0][r] += __expf(a0[r] - dv[0][r]);
            rs[1][r] += __expf(a1[r] - dv[1][r]);
            rs[2][r] += __expf(a2[r] - dv[2][r]);
            rs[3][r] += __expf(a3[r] - dv[3][r]);
        }
    }
    #pragma unroll
    for (int off = 1; off < 16; off <<= 1)
        #pragma unroll
        for (int ns = 0; ns < 4; ++ns)
            #pragma unroll
            for (int r = 0; r < 4; ++r)
                rs[ns][r] += __shfl_xor(rs[ns][r], off, 64);
    if (l15 == 0) {
        #pragma unroll
        for (int ns = 0; ns < 4; ++ns)
            #pragma unroll
            for (int r = 0; r < 4; ++r)
                red[w][16 * ns + 4 * q + r] = rs[ns][r];
    }
    __syncthreads();
    if (t < 64) {
        float s = 0.f;
        #pragma unroll
        for (int ww = 0; ww < 8; ++ww) s += red[ww][t];
        lg[b * N_ + n0 + t] = dgl[t] + __logf(s);
    }
}

__global__ __launch_bounds__(512, 2) void out_g_kernel(const uchar* __restrict__ xfrag8,
                                                       const ushort* __restrict__ ffrag,
                                                       const float* __restrict__ gg,
                                                       const float* __restrict__ fd32,
                                                       float* __restrict__ outp) {
    __shared__ ushort ET[2][64][LDE];
    const int bid = blockIdx.x;
    const int b = (bid >> 1) & 3;
    const int m0 = ((((bid >> 3) << 1) | (bid & 1))) * 64;
    const int t = threadIdx.x, lane = t & 63, w = t >> 6;
    const int l15 = lane & 15, q = lane >> 4;
    const int a = w & 3, h = w >> 2;
    const size_t fb = (size_t)b * C_ * N_;

    long bfr[2][8];
    #pragma unroll
    for (int jt = 0; jt < 2; ++jt)
        #pragma unroll
        for (int kk = 0; kk < 8; ++kk)
            bfr[jt][kk] = *(const long*)(xfrag8 + xfi8(b, (m0 >> 4) + 2 * h + jt, kk) + (size_t)lane * 8);

    f32x4 acc[2][4];
    #pragma unroll
    for (int ct = 0; ct < 2; ++ct)
        #pragma unroll
        for (int mt = 0; mt < 4; ++mt)
            acc[ct][mt] = (f32x4){0.f, 0.f, 0.f, 0.f};

    long an[8];
    #pragma unroll
    for (int kk = 0; kk < 8; ++kk)
        an[kk] = *(const long*)(xfrag8 + xfi8(b, a, kk) + (size_t)lane * 8);
    float gn[4];
    #pragma unroll
    for (int r = 0; r < 4; ++r) gn[r] = gg[b * N_ + 16 * a + 4 * q + r];

    int p = 0;
    for (int n0c = 0; n0c < N_; n0c += 64, p ^= 1) {
        const int nc = n0c >> 6;
        short8 fn[2][2];
        #pragma unroll
        for (int ct = 0; ct < 2; ++ct)
            #pragma unroll
            for (int k2 = 0; k2 < 2; ++k2)
                fn[ct][k2] = *(const short8*)(ffrag + ffi(b, nc, 2 * w + ct, k2) + lane * 8);
        float gv[4];
        #pragma unroll
        for (int r = 0; r < 4; ++r) gv[r] = gn[r];
        const int nx = (n0c + 64 < N_) ? n0c + 64 : 0;
        #pragma unroll
        for (int r = 0; r < 4; ++r) gn[r] = gg[b * N_ + nx + 16 * a + 4 * q + r];

        f32x4 s0 = {0.f, 0.f, 0.f, 0.f}, s1 = {0.f, 0.f, 0.f, 0.f};
        #pragma unroll
        for (int kk = 0; kk < 8; ++kk) {
            s0 = mfma8(an[kk], bfr[0][kk], s0);
            s1 = mfma8(an[kk], bfr[1][kk], s1);
            an[kk] = *(const long*)(xfrag8 + xfi8(b, (nx >> 4) + a, kk) + (size_t)lane * 8);
        }
        ushort4 e0, e1;
        e0.x = f2bf(__expf(s0[0] - gv[0])); e0.y = f2bf(__expf(s0[1] - gv[1]));
        e0.z = f2bf(__expf(s0[2] - gv[2])); e0.w = f2bf(__expf(s0[3] - gv[3]));
        e1.x = f2bf(__expf(s1[0] - gv[0])); e1.y = f2bf(__expf(s1[1] - gv[1]));
        e1.z = f2bf(__expf(s1[2] - gv[2])); e1.w = f2bf(__expf(s1[3] - gv[3]));
        *(ushort4*)(&ET[p][32 * h + l15][16 * a + 4 * q])      = e0;
        *(ushort4*)(&ET[p][32 * h + 16 + l15][16 * a + 4 * q]) = e1;

        asm volatile("s_waitcnt lgkmcnt(0)\n\ts_barrier" ::: "memory");

        #pragma unroll
        for (int k2 = 0; k2 < 2; ++k2) {
            #pragma unroll
            for (int mt = 0; mt < 4; ++mt) {
                const short8 be = *(const short8*)(&ET[p][16 * mt + l15][32 * k2 + 8 * q]);
                acc[0][mt] = mfma16(fn[0][k2], be, acc[0][mt]);
                acc[1][mt] = mfma16(fn[1][k2], be, acc[1][mt]);
            }
        }
    }
    #pragma unroll
    for (int ct = 0; ct < 2; ++ct)
        #pragma unroll
        for (int mt = 0; mt < 4; ++mt)
            #pragma unroll
            for (int r = 0; r < 4; ++r) {
                const int c = 32 * w + 16 * ct + 4 * q + r;
                const int m = m0 + 16 * mt + l15;
                const size_t o = fb + (size_t)c * N_ + m;
                outp[o] = acc[ct][mt][r] + fd32[o];
            }
}

// ---------------------------------------------------------------------------
extern "C" void kernel_launch(void* const* d_in, const int* in_sizes, int n_in,
                              void* d_out, int out_size, void* d_ws, size_t ws_size,
                              hipStream_t stream) {
    const float* fm = (const float*)d_in[0];
    const float* fd = (const float*)d_in[1];
    float* outp = (float*)d_out;

    const size_t xb_elts = (size_t)B_ * N_ * C_;                 // 4.19M
    const size_t e_bytes = (size_t)B_ * N_ * N_;                 // 67.1 MB (fp8 E^T)
    const size_t z_bytes = (size_t)B_ * 64 * 256;                // 64 KB (zmask)
    const size_t s_bytes = (size_t)B_ * N_ * 4;                  // 64 KB (sinv)
    const size_t need_e  = xb_elts + e_bytes + z_bytes + s_bytes; // ~71.5 MB
    const size_t need_g  = xb_elts * 3 + (size_t)B_ * N_ * 4;    // ~12.6 MB

    uchar* xfrag8 = (uchar*)d_ws;                     // fp8, 4.19 MB

    if (ws_size >= need_e) {
        uchar* E8    = xfrag8 + xb_elts;
        uchar* zmask = E8 + e_bytes;
        float* sinv  = (float*)(zmask + z_bytes);
        prep_x_kernel<<<dim3(N_ / 64, C_ / 64, B_), 256, 0, stream>>>(fm, fd, xfrag8);
        lsum_e_kernel<<<dim3(256), 512, 0, stream>>>(xfrag8, E8, zmask, sinv);
        out_e_kernel<<<dim3(256), 512, 0, stream>>>(E8, zmask, sinv, fd, outp);
    } else if (ws_size >= need_g) {
        ushort* ffrag = (ushort*)(xfrag8 + xb_elts);
        float*  lg    = (float*)(xfrag8 + xb_elts * 3);
        prep_kernel<<<dim3(N_ / 64, C_ / 64, B_), 256, 0, stream>>>(fm, fd, xfrag8, ffrag);
        lsum_g_kernel<<<dim3(256), 512, 0, stream>>>(xfrag8, lg);
        out_g_kernel<<<dim3(256), 512, 0, stream>>>(xfrag8, ffrag, lg, fd, outp);
    }
}

// Round 9
// 115.057 us; speedup vs baseline: 1.6962x; 1.0566x over previous
//
#include <hip/hip_runtime.h>
#include <math.h>

#define B_ 4
#define C_ 256
#define N_ 4096   // H*W
#define LDE 68    // ET row stride (ushorts) — fallback path
#define LDX 72    // prep LDS tile stride (ushorts)

typedef __attribute__((ext_vector_type(8))) short short8;
typedef __attribute__((ext_vector_type(4))) float f32x4;
typedef __attribute__((ext_vector_type(2))) float f32x2;

__device__ inline ushort f2bf(float f) {
    uint u = __float_as_uint(f);
    return (ushort)((u + 0x7fffu + ((u >> 16) & 1u)) >> 16);   // RNE
}
__device__ inline float bf2f(ushort h) { return __uint_as_float(((uint)h) << 16); }

__device__ inline f32x4 mfma16(short8 a, short8 b, f32x4 c) {
    return __builtin_amdgcn_mfma_f32_16x16x32_bf16(a, b, c, 0, 0, 0);
}
__device__ inline f32x4 mfma8(long a, long b, f32x4 c) {
    return __builtin_amdgcn_mfma_f32_16x16x32_fp8_fp8(a, b, c, 0, 0, 0);
}

// Layouts:
//   xfrag8[b][nt=0..255][kk=0..7][lane][8 fp8]   (X = fp8(fm+fd), k=c)
//   E8    [b][mt=0..255][ng=0..511][ml=0..15][8] (E^T fp8)
//   zmask [b][nc=0..63][mt=0..255]  0=zero, 1=E8 valid, 2=recompute in out_e
//   rsbase/rsadd/dgall [b][n]       row-sum local / atomic remainder / diag shift
__device__ inline size_t xfi8(int b, int nt, int kk) {
    return (((size_t)(b * 256 + nt)) * 8 + kk) * 512;
}
__device__ inline size_t ffi(int b, int nc, int ct, int k2) {   // fallback only
    return ((((size_t)(b * 64 + nc)) * 16 + ct) * 2 + k2) * 512;
}
__device__ inline size_t eti(int b, int mt, int ng) {
    return (((size_t)(b * 256 + mt)) * 512 + (size_t)ng) * 128;
}
__device__ inline size_t zmi(int b, int nc, int mt) {
    return ((size_t)(b * 64 + nc)) * 256 + mt;
}

// ---------------------------------------------------------------------------
// P0x: build xfrag8 only.
// ---------------------------------------------------------------------------
__global__ __launch_bounds__(256) void prep_x_kernel(const float* __restrict__ fm,
                                                     const float* __restrict__ fd,
                                                     uchar* __restrict__ xfrag8) {
    __shared__ ushort xl[64][LDX];
    const int b = blockIdx.z, c0 = blockIdx.y * 64, n0 = blockIdx.x * 64;
    const int t = threadIdx.x;
    const int n4 = (t & 15) * 4, cl = t >> 4;
    const size_t base = (size_t)b * C_ * N_;
    #pragma unroll
    for (int p = 0; p < 4; ++p) {
        const int cr = 16 * p + cl;
        const float4 m4 = *(const float4*)(fm + base + (size_t)(c0 + cr) * N_ + n0 + n4);
        const float4 d4 = *(const float4*)(fd + base + (size_t)(c0 + cr) * N_ + n0 + n4);
        ushort4 xo;
        xo.x = f2bf(m4.x + d4.x); xo.y = f2bf(m4.y + d4.y);
        xo.z = f2bf(m4.z + d4.z); xo.w = f2bf(m4.w + d4.w);
        *(ushort4*)(&xl[cr][n4]) = xo;
    }
    __syncthreads();
    const int l = t & 63, tl = t >> 6;
    const int nl = 16 * tl + (l & 15);
    #pragma unroll
    for (int j = 0; j < 2; ++j) {
        const int kk = (c0 >> 5) + j;
        const int cb = 32 * j + 8 * (l >> 4);
        float f[8];
        #pragma unroll
        for (int i = 0; i < 8; ++i) f[i] = bf2f(xl[cb + i][nl]);
        int d0 = __builtin_amdgcn_cvt_pk_fp8_f32(f[0], f[1], 0, 0);
        d0 = __builtin_amdgcn_cvt_pk_fp8_f32(f[2], f[3], d0, 1);
        int d1 = __builtin_amdgcn_cvt_pk_fp8_f32(f[4], f[5], 0, 0);
        d1 = __builtin_amdgcn_cvt_pk_fp8_f32(f[6], f[7], d1, 1);
        uint* dst = (uint*)(xfrag8 + xfi8(b, (n0 >> 4) + tl, kk) + (size_t)l * 8);
        dst[0] = (uint)d0; dst[1] = (uint)d1;
    }
}

// ---------------------------------------------------------------------------
// K2t: TRIANGULAR Gram. Block (b,j) owns chunk-pairs {j,k} with
// owner = (j+k)%2==0 ? min : max (≈32-33 chunks, balanced). Per owned tile:
//  A-side (rows j, shift dv): exp-skip + E8 store + zmask=1 + local rs (as r8).
//  B-side (rows k, shift dgm from VALU sum-of-squares): skip-test only; if
//  nonzero (never on real data): zmask=2 staged in LDS (out_e recomputes) +
//  atomicAdd col-sums into rsadd. rsbase/dgall stored for out_e.
// Exact for the bench input: all off-diag tiles underflow -> no atomics, no
// type-2; rs order unchanged (extra terms are exact +0.0f).
// ---------------------------------------------------------------------------
__global__ __launch_bounds__(512, 2) void lsum_t_kernel(const uchar* __restrict__ xfrag8,
                                                        uchar* __restrict__ E8,
                                                        uchar* __restrict__ zmask,
                                                        float* __restrict__ rsbase,
                                                        float* __restrict__ rsadd,
                                                        float* __restrict__ dgall) {
    __shared__ float red[8][64];
    __shared__ float dgl[64];
    __shared__ uchar chl[34];
    __shared__ int cnt_s;
    __shared__ uint zst[34];
    const int bid = blockIdx.x;
    const int b = (bid >> 1) & 3;
    const int n0 = ((((bid >> 3) << 1) | (bid & 1))) * 64;
    const int j = n0 >> 6;
    const int t = threadIdx.x, lane = t & 63, w = t >> 6;
    const int l15 = lane & 15, q = lane >> 4;
    const int g = w >> 2, wm = w & 3;

    if (t == 0) {
        int c = 0;
        chl[c++] = (uchar)j;                       // diag first
        for (int k = 0; k < 64; ++k) {
            if (k == j) continue;
            const bool own = (k > j) ? (((j + k) & 1) == 0) : (((j + k) & 1) == 1);
            if (own) chl[c++] = (uchar)k;
        }
        cnt_s = c;
    }
    if (t < 34) zst[t] = 0u;

    long af[4][8];
    #pragma unroll
    for (int ns = 0; ns < 4; ++ns)
        #pragma unroll
        for (int kk = 0; kk < 8; ++kk)
            af[ns][kk] = *(const long*)(xfrag8 + xfi8(b, (n0 >> 4) + ns, kk) + (size_t)lane * 8);

    // diag shift dv (C/D layout: col=l&15, row=4*(l>>4)+r)
    float dv[4][4];
    #pragma unroll
    for (int ns = 0; ns < 4; ++ns) {
        f32x4 dacc = {0.f, 0.f, 0.f, 0.f};
        #pragma unroll
        for (int kk = 0; kk < 8; ++kk)
            dacc = mfma8(af[ns][kk], af[ns][kk], dacc);
        #pragma unroll
        for (int r = 0; r < 4; ++r)
            dv[ns][r] = __shfl(dacc[r], 20 * q + r, 64);
    }
    if (w == 0 && l15 == 0) {
        #pragma unroll
        for (int ns = 0; ns < 4; ++ns)
            #pragma unroll
            for (int r = 0; r < 4; ++r)
                dgl[16 * ns + 4 * q + r] = dv[ns][r];
    }

    __syncthreads();
    const int cnt = cnt_s;

    long bn[8];
    {
        const int mt0 = 4 * (int)chl[g] + wm;      // g < cnt always (cnt >= 32)
        #pragma unroll
        for (int kk = 0; kk < 8; ++kk)
            bn[kk] = *(const long*)(xfrag8 + xfi8(b, mt0, kk) + (size_t)lane * 8);
    }
    const size_t ebl = (size_t)l15 * 8 + 4 * (q & 1);
    const int ngb = (n0 >> 3) + (q >> 1);

    float rs[4][4] = {};
    for (int it = 0; it < 17; ++it) {
        const int idx = 2 * it + g;
        const bool valid = idx < cnt;
        const int kc = chl[valid ? idx : 0];
        const int mt = 4 * kc + wm;
        int idxn = 2 * (it + 1) + g; if (idxn >= cnt) idxn = 0;
        const int mtn = 4 * (int)chl[idxn] + wm;

        f32x4 a0 = {0.f,0.f,0.f,0.f}, a1 = {0.f,0.f,0.f,0.f};
        f32x4 a2 = {0.f,0.f,0.f,0.f}, a3 = {0.f,0.f,0.f,0.f};
        float dg0 = 0.f, dg1 = 0.f, dg2 = 0.f, dg3 = 0.f;   // VALU sum-sq of bc
        __builtin_amdgcn_s_setprio(1);
        #pragma unroll
        for (int kk = 0; kk < 8; ++kk) {
            const long bc = bn[kk];
            a0 = mfma8(af[0][kk], bc, a0);
            a1 = mfma8(af[1][kk], bc, a1);
            a2 = mfma8(af[2][kk], bc, a2);
            a3 = mfma8(af[3][kk], bc, a3);
            bn[kk] = *(const long*)(xfrag8 + xfi8(b, mtn, kk) + (size_t)lane * 8);
            const uint lo = (uint)(unsigned long)bc;
            const uint hi = (uint)((unsigned long)bc >> 32);
            const f32x2 p0 = __builtin_amdgcn_cvt_pk_f32_fp8((int)lo, false);
            const f32x2 p1 = __builtin_amdgcn_cvt_pk_f32_fp8((int)lo, true);
            const f32x2 p2 = __builtin_amdgcn_cvt_pk_f32_fp8((int)hi, false);
            const f32x2 p3 = __builtin_amdgcn_cvt_pk_f32_fp8((int)hi, true);
            dg0 = fmaf(p0.x, p0.x, dg0); dg0 = fmaf(p0.y, p0.y, dg0);
            dg1 = fmaf(p1.x, p1.x, dg1); dg1 = fmaf(p1.y, p1.y, dg1);
            dg2 = fmaf(p2.x, p2.x, dg2); dg2 = fmaf(p2.y, p2.y, dg2);
            dg3 = fmaf(p3.x, p3.x, dg3); dg3 = fmaf(p3.y, p3.y, dg3);
        }
        __builtin_amdgcn_s_setprio(0);

        float df[4][4];
#define EDF(AA, NS)                                                    \
        df[NS][0] = AA[0] - dv[NS][0]; df[NS][1] = AA[1] - dv[NS][1];  \
        df[NS][2] = AA[2] - dv[NS][2]; df[NS][3] = AA[3] - dv[NS][3];
        EDF(a0, 0) EDF(a1, 1) EDF(a2, 2) EDF(a3, 3)
#undef EDF
        const float mxA = fmaxf(
            fmaxf(fmaxf(fmaxf(df[0][0], df[0][1]), fmaxf(df[0][2], df[0][3])),
                  fmaxf(fmaxf(df[1][0], df[1][1]), fmaxf(df[1][2], df[1][3]))),
            fmaxf(fmaxf(fmaxf(df[2][0], df[2][1]), fmaxf(df[2][2], df[2][3])),
                  fmaxf(fmaxf(df[3][0], df[3][1]), fmaxf(df[3][2], df[3][3]))));
        const bool nzA = valid && (__ballot(mxA > -30.0f) != 0ULL);
        if (valid && lane == 0) zmask[zmi(b, j, mt)] = nzA ? 1 : 0;
        if (nzA) {
            uint dpk[4];
#define EEXP(NS)                                                                       \
            {                                                                          \
                float e0 = __expf(df[NS][0]), e1 = __expf(df[NS][1]);                  \
                float e2 = __expf(df[NS][2]), e3 = __expf(df[NS][3]);                  \
                rs[NS][0] += e0; rs[NS][1] += e1; rs[NS][2] += e2; rs[NS][3] += e3;    \
                int d = __builtin_amdgcn_cvt_pk_fp8_f32(e0, e1, 0, 0);                 \
                d = __builtin_amdgcn_cvt_pk_fp8_f32(e2, e3, d, 1);                     \
                dpk[NS] = (uint)d;                                                     \
            }
            EEXP(0) EEXP(1) EEXP(2) EEXP(3)
#undef EEXP
            #pragma unroll
            for (int ns = 0; ns < 4; ++ns)
                *(uint*)(E8 + eti(b, mt, ngb + 2 * ns) + ebl) = dpk[ns];
        }
        // ---- B-side (twin rows k): skip-test + rare atomic remainder ----
        if (valid && kc != j) {
            float dgm = dg0 + dg1 + dg2 + dg3;         // this lane's c-slice
            dgm += __shfl_xor(dgm, 16, 64);
            dgm += __shfl_xor(dgm, 32, 64);            // full |x_m|^2 for row l15 of mt
            float dfB[4][4];
            #pragma unroll
            for (int ns = 0; ns < 4; ++ns) {
                dfB[ns][0] = (ns==0?a0[0]:ns==1?a1[0]:ns==2?a2[0]:a3[0]) - dgm;
                dfB[ns][1] = (ns==0?a0[1]:ns==1?a1[1]:ns==2?a2[1]:a3[1]) - dgm;
                dfB[ns][2] = (ns==0?a0[2]:ns==1?a1[2]:ns==2?a2[2]:a3[2]) - dgm;
                dfB[ns][3] = (ns==0?a0[3]:ns==1?a1[3]:ns==2?a2[3]:a3[3]) - dgm;
            }
            uint bits = 0;
            #pragma unroll
            for (int ns = 0; ns < 4; ++ns) {
                const float m2 = fmaxf(fmaxf(dfB[ns][0], dfB[ns][1]),
                                       fmaxf(dfB[ns][2], dfB[ns][3]));
                if (__ballot(m2 > -30.0f) != 0ULL) bits |= (1u << ns);
            }
            if (bits) {                                 // never on real data
                if (lane == 0) atomicOr(&zst[idx], bits);
                float cs = 0.f;
                #pragma unroll
                for (int ns = 0; ns < 4; ++ns)
                    #pragma unroll
                    for (int r = 0; r < 4; ++r)
                        cs += __expf(dfB[ns][r]);
                cs += __shfl_xor(cs, 16, 64);
                cs += __shfl_xor(cs, 32, 64);
                if (q == 0) atomicAdd(rsadd + b * N_ + 16 * mt + l15, cs);
            }
        }
    }
    #pragma unroll
    for (int off = 1; off < 16; off <<= 1)
        #pragma unroll
        for (int ns = 0; ns < 4; ++ns)
            #pragma unroll
            for (int r = 0; r < 4; ++r)
                rs[ns][r] += __shfl_xor(rs[ns][r], off, 64);
    if (l15 == 0) {
        #pragma unroll
        for (int ns = 0; ns < 4; ++ns)
            #pragma unroll
            for (int r = 0; r < 4; ++r)
                red[w][16 * ns + 4 * q + r] = rs[ns][r];
    }
    __syncthreads();
    if (t < 64) {
        float s = 0.f;
        #pragma unroll
        for (int ww = 0; ww < 8; ++ww) s += red[ww][t];
        rsbase[b * N_ + n0 + t] = s;
        dgall[b * N_ + n0 + t] = dgl[t];
    }
    if (t >= 64 && t < 64 + 33 * 4) {
        const int ii = (t - 64) >> 2, ns = (t - 64) & 3;
        const int idx = ii + 1;
        if (idx < cnt) {
            const int kc = chl[idx];
            zmask[zmi(b, kc, 4 * j + ns)] = (((zst[idx] >> ns) & 1u) != 0u) ? 2 : 0;
        }
    }
}

// ---------------------------------------------------------------------------
// K3e v4: out[c,m] = sum_n (fd[c,n]*sinv[n]) * E[n,m] + fd[c,m].
// sinv = 1/(rsbase+rsadd). Per-mt zmask byte guards: 0=skip, 1=E8, 2(or
// unexpected)=self-recompute from xfrag8+dgall (never on real data).
// ---------------------------------------------------------------------------
__global__ __launch_bounds__(512, 2) void out_e_kernel(const uchar* __restrict__ E8,
                                                       const uchar* __restrict__ zmask,
                                                       const float* __restrict__ rsbase,
                                                       const float* __restrict__ rsadd,
                                                       const float* __restrict__ dgall,
                                                       const uchar* __restrict__ xfrag8,
                                                       const float* __restrict__ fd32,
                                                       float* __restrict__ outp) {
    __shared__ ushort esc[8][16][66];   // per-wave recompute scratch
    const int bid = blockIdx.x;
    const int b = (bid >> 1) & 3;
    const int m0 = ((((bid >> 3) << 1) | (bid & 1))) * 64;
    const int t = threadIdx.x, lane = t & 63, w = t >> 6;
    const int l15 = lane & 15, q = lane >> 4;
    const size_t fb = (size_t)b * C_ * N_;
    const uchar* mrow = zmask + zmi(b, 0, m0 >> 4);

    f32x4 acc[2][4];
    #pragma unroll
    for (int ct = 0; ct < 2; ++ct)
        #pragma unroll
        for (int mt = 0; mt < 4; ++mt)
            acc[ct][mt] = (f32x4){0.f, 0.f, 0.f, 0.f};

    for (int gg = 0; gg < 8; ++gg) {
        uint mk[8];
        #pragma unroll
        for (int i = 0; i < 8; ++i)
            mk[i] = *(const uint*)(mrow + (size_t)(8 * gg + i) * 256);
        #pragma unroll
        for (int i = 0; i < 8; ++i) {
            const uint mki = mk[i];
            if (mki == 0) continue;
            const int nc = 8 * gg + i;
            // sinv for this lane's 16 k-elems (8 per k2 half)
            const float* rb = rsbase + b * N_ + 64 * nc + 8 * q;
            const float* ra = rsadd + b * N_ + 64 * nc + 8 * q;
            float4 s0[2], s1[2];
            #pragma unroll
            for (int k2 = 0; k2 < 2; ++k2) {
                const float4 b0 = *(const float4*)(rb + 32 * k2);
                const float4 b1 = *(const float4*)(rb + 32 * k2 + 4);
                const float4 a0v = *(const float4*)(ra + 32 * k2);
                const float4 a1v = *(const float4*)(ra + 32 * k2 + 4);
                s0[k2].x = 1.0f / (b0.x + a0v.x); s0[k2].y = 1.0f / (b0.y + a0v.y);
                s0[k2].z = 1.0f / (b0.z + a0v.z); s0[k2].w = 1.0f / (b0.w + a0v.w);
                s1[k2].x = 1.0f / (b1.x + a1v.x); s1[k2].y = 1.0f / (b1.y + a1v.y);
                s1[k2].z = 1.0f / (b1.z + a1v.z); s1[k2].w = 1.0f / (b1.w + a1v.w);
            }
            short8 fn[2][2];
            #pragma unroll
            for (int ct = 0; ct < 2; ++ct) {
                const int c = 32 * w + 16 * ct + l15;
                const float* frow = fd32 + fb + (size_t)c * N_ + 64 * nc + 8 * q;
                #pragma unroll
                for (int k2 = 0; k2 < 2; ++k2) {
                    const float4 fa = *(const float4*)(frow + 32 * k2);
                    const float4 fb4 = *(const float4*)(frow + 32 * k2 + 4);
                    union { ushort us[8]; short8 v; } u;
                    u.us[0] = f2bf(fa.x * s0[k2].x); u.us[1] = f2bf(fa.y * s0[k2].y);
                    u.us[2] = f2bf(fa.z * s0[k2].z); u.us[3] = f2bf(fa.w * s0[k2].w);
                    u.us[4] = f2bf(fb4.x * s1[k2].x); u.us[5] = f2bf(fb4.y * s1[k2].y);
                    u.us[6] = f2bf(fb4.z * s1[k2].z); u.us[7] = f2bf(fb4.w * s1[k2].w);
                    fn[ct][k2] = u.v;
                }
            }
            if ((mki & ~0x01010101u) == 0u) {
                // ---- E8 path with per-mt validity ----
                #pragma unroll
                for (int k2 = 0; k2 < 2; ++k2) {
                    #pragma unroll
                    for (int mt = 0; mt < 4; ++mt) {
                        if (((mki >> (8 * mt)) & 0xffu) != 1u) continue;
                        const long e8 = *(const long*)(E8 + eti(b, (m0 >> 4) + mt, 8 * nc + 4 * k2 + q) + (size_t)l15 * 8);
                        const uint lo = (uint)(unsigned long)e8;
                        const uint hi = (uint)((unsigned long)e8 >> 32);
                        const f32x2 f01 = __builtin_amdgcn_cvt_pk_f32_fp8((int)lo, false);
                        const f32x2 f23 = __builtin_amdgcn_cvt_pk_f32_fp8((int)lo, true);
                        const f32x2 f45 = __builtin_amdgcn_cvt_pk_f32_fp8((int)hi, false);
                        const f32x2 f67 = __builtin_amdgcn_cvt_pk_f32_fp8((int)hi, true);
                        union { uint u[4]; short8 v; } be;
                        asm("v_cvt_pk_bf16_f32 %0, %1, %2" : "=v"(be.u[0]) : "v"(f01.x), "v"(f01.y));
                        asm("v_cvt_pk_bf16_f32 %0, %1, %2" : "=v"(be.u[1]) : "v"(f23.x), "v"(f23.y));
                        asm("v_cvt_pk_bf16_f32 %0, %1, %2" : "=v"(be.u[2]) : "v"(f45.x), "v"(f45.y));
                        asm("v_cvt_pk_bf16_f32 %0, %1, %2" : "=v"(be.u[3]) : "v"(f67.x), "v"(f67.y));
                        acc[0][mt] = mfma16(fn[0][k2], be.v, acc[0][mt]);
                        acc[1][mt] = mfma16(fn[1][k2], be.v, acc[1][mt]);
                    }
                }
            } else {
                // ---- recompute path (degenerate inputs only) ----
                #pragma unroll
                for (int mt = 0; mt < 4; ++mt) {
                    long bmf[8];
                    #pragma unroll
                    for (int kk = 0; kk < 8; ++kk)
                        bmf[kk] = *(const long*)(xfrag8 + xfi8(b, (m0 >> 4) + mt, kk) + (size_t)lane * 8);
                    #pragma unroll
                    for (int nt = 0; nt < 4; ++nt) {
                        long anf[8];
                        #pragma unroll
                        for (int kk = 0; kk < 8; ++kk)
                            anf[kk] = *(const long*)(xfrag8 + xfi8(b, 4 * nc + nt, kk) + (size_t)lane * 8);
                        f32x4 sacc = {0.f, 0.f, 0.f, 0.f};
                        #pragma unroll
                        for (int kk = 0; kk < 8; ++kk)
                            sacc = mfma8(anf[kk], bmf[kk], sacc);
                        #pragma unroll
                        for (int r = 0; r < 4; ++r) {
                            const float gv = dgall[b * N_ + 64 * nc + 16 * nt + 4 * q + r];
                            esc[w][l15][16 * nt + 4 * q + r] = f2bf(__expf(sacc[r] - gv));
                        }
                    }
                    #pragma unroll
                    for (int k2 = 0; k2 < 2; ++k2) {
                        const short8 be = *(const short8*)(&esc[w][l15][32 * k2 + 8 * q]);
                        acc[0][mt] = mfma16(fn[0][k2], be, acc[0][mt]);
                        acc[1][mt] = mfma16(fn[1][k2], be, acc[1][mt]);
                    }
                }
            }
        }
    }
    #pragma unroll
    for (int ct = 0; ct < 2; ++ct)
        #pragma unroll
        for (int mt = 0; mt < 4; ++mt)
            #pragma unroll
            for (int r = 0; r < 4; ++r) {
                const int c = 32 * w + 16 * ct + 4 * q + r;
                const int m = m0 + 16 * mt + l15;
                const size_t o = fb + (size_t)c * N_ + m;
                outp[o] = acc[ct][mt][r] + fd32[o];
            }
}

// ===========================================================================
// FALLBACK PATH (round-4 kernels) — used when ws_size < E8 requirement.
// ===========================================================================
__global__ __launch_bounds__(256) void prep_kernel(const float* __restrict__ fm,
                                                   const float* __restrict__ fd,
                                                   uchar* __restrict__ xfrag8,
                                                   ushort* __restrict__ ffrag) {
    __shared__ ushort xl[64][LDX];
    __shared__ ushort fl[64][LDX];
    const int b = blockIdx.z, c0 = blockIdx.y * 64, n0 = blockIdx.x * 64;
    const int t = threadIdx.x;
    const int n4 = (t & 15) * 4, cl = t >> 4;
    const size_t base = (size_t)b * C_ * N_;
    #pragma unroll
    for (int p = 0; p < 4; ++p) {
        const int cr = 16 * p + cl;
        const float4 m4 = *(const float4*)(fm + base + (size_t)(c0 + cr) * N_ + n0 + n4);
        const float4 d4 = *(const float4*)(fd + base + (size_t)(c0 + cr) * N_ + n0 + n4);
        ushort4 fo;
        fo.x = f2bf(d4.x); fo.y = f2bf(d4.y); fo.z = f2bf(d4.z); fo.w = f2bf(d4.w);
        *(ushort4*)(&fl[cr][n4]) = fo;
        ushort4 xo;
        xo.x = f2bf(m4.x + d4.x); xo.y = f2bf(m4.y + d4.y);
        xo.z = f2bf(m4.z + d4.z); xo.w = f2bf(m4.w + d4.w);
        *(ushort4*)(&xl[cr][n4]) = xo;
    }
    __syncthreads();
    const int l = t & 63, tl = t >> 6;
    {
        const int nl = 16 * tl + (l & 15);
        #pragma unroll
        for (int j = 0; j < 2; ++j) {
            const int kk = (c0 >> 5) + j;
            const int cb = 32 * j + 8 * (l >> 4);
            float f[8];
            #pragma unroll
            for (int i = 0; i < 8; ++i) f[i] = bf2f(xl[cb + i][nl]);
            int d0 = __builtin_amdgcn_cvt_pk_fp8_f32(f[0], f[1], 0, 0);
            d0 = __builtin_amdgcn_cvt_pk_fp8_f32(f[2], f[3], d0, 1);
            int d1 = __builtin_amdgcn_cvt_pk_fp8_f32(f[4], f[5], 0, 0);
            d1 = __builtin_amdgcn_cvt_pk_fp8_f32(f[6], f[7], d1, 1);
            uint* dst = (uint*)(xfrag8 + xfi8(b, (n0 >> 4) + tl, kk) + (size_t)l * 8);
            dst[0] = (uint)d0; dst[1] = (uint)d1;
        }
    }
    {
        const int row = 16 * tl + (l & 15);
        #pragma unroll
        for (int k2 = 0; k2 < 2; ++k2) {
            const int col = 32 * k2 + 8 * (l >> 4);
            const ushort4 a0 = *(const ushort4*)(&fl[row][col]);
            const ushort4 a1 = *(const ushort4*)(&fl[row][col + 4]);
            ushort* dst = ffrag + ffi(b, n0 >> 6, (c0 >> 4) + tl, k2) + l * 8;
            *(ushort4*)(dst) = a0; *(ushort4*)(dst + 4) = a1;
        }
    }
}

__global__ __launch_bounds__(512, 2) void lsum_g_kernel(const uchar* __restrict__ xfrag8,
                                                        float* __restrict__ lg) {
    __shared__ float red[8][64];
    __shared__ float dgl[64];
    const int bid = blockIdx.x;
    const int b = (bid >> 1) & 3;
    const int n0 = ((((bid >> 3) << 1) | (bid & 1))) * 64;
    const int t = threadIdx.x, lane = t & 63, w = t >> 6;
    const int l15 = lane & 15, q = lane >> 4;

    long af[4][8];
    #pragma unroll
    for (int ns = 0; ns < 4; ++ns)
        #pragma unroll
        for (int kk = 0; kk < 8; ++kk)
            af[ns][kk] = *(const long*)(xfrag8 + xfi8(b, (n0 >> 4) + ns, kk) + (size_t)lane * 8);

    float dv[4][4];
    #pragma unroll
    for (int ns = 0; ns < 4; ++ns) {
        f32x4 dacc = {0.f, 0.f, 0.f, 0.f};
        #pragma unroll
        for (int kk = 0; kk < 8; ++kk)
            dacc = mfma8(af[ns][kk], af[ns][kk], dacc);
        #pragma unroll
        for (int r = 0; r < 4; ++r)
            dv[ns][r] = __shfl(dacc[r], 20 * q + r, 64);
    }
    if (w == 0 && l15 == 0) {
        #pragma unroll
        for (int ns = 0; ns < 4; ++ns)
            #pragma unroll
            for (int r = 0; r < 4; ++r)
                dgl[16 * ns + 4 * q + r] = dv[ns][r];
    }

    long bn[8];
    #pragma unroll
    for (int kk = 0; kk < 8; ++kk)
        bn[kk] = *(const long*)(xfrag8 + xfi8(b, w, kk) + (size_t)lane * 8);

    float rs[4][4] = {};
    for (int mc = 0; mc < 32; ++mc) {
        const int mtn = (mc + 1 < 32) ? (mc + 1) * 8 + w : w;
        f32x4 a0 = {0.f,0.f,0.f,0.f}, a1 = {0.f,0.f,0.f,0.f};
        f32x4 a2 = {0.f,0.f,0.f,0.f}, a3 = {0.f,0.f,0.f,0.f};
        #pragma unroll
        for (int kk = 0; kk < 8; ++kk) {
            const long bc = bn[kk];
            a0 = mfma8(af[0][kk], bc, a0);
            a1 = mfma8(af[1][kk], bc, a1);
            a2 = mfma8(af[2][kk], bc, a2);
            a3 = mfma8(af[3][kk], bc, a3);
            bn[kk] = *(const long*)(xfrag8 + xfi8(b, mtn, kk) + (size_t)lane * 8);
        }
        #pragma unroll
        for (int r = 0; r < 4; ++r) {
            rs[0][r] += __expf(a0[r] - dv[0][r]);
            rs[1][r] += __expf(a1[r] - dv[1][r]);
            rs[2][r] += __expf(a2[r] - dv[2][r]);
            rs[3][r] += __expf(a3[r] - dv[3][r]);
        }
    }
    #pragma unroll
    for (int off = 1; off < 16; off <<= 1)
        #pragma unroll
        for (int ns = 0; ns < 4; ++ns)
            #pragma unroll
            for (int r = 0; r < 4; ++r)
                rs[ns][r] += __shfl_xor(rs[ns][r], off, 64);
    if (l15 == 0) {
        #pragma unroll
        for (int ns = 0; ns < 4; ++ns)
            #pragma unroll
            for (int r = 0; r < 4; ++r)
                red[w][16 * ns + 4 * q + r] = rs[ns][r];
    }
    __syncthreads();
    if (t < 64) {
        float s = 0.f;
        #pragma unroll
        for (int ww = 0; ww < 8; ++ww) s += red[ww][t];
        lg[b * N_ + n0 + t] = dgl[t] + __logf(s);
    }
}

__global__ __launch_bounds__(512, 2) void out_g_kernel(const uchar* __restrict__ xfrag8,
                                                       const ushort* __restrict__ ffrag,
                                                       const float* __restrict__ gg,
                                                       const float* __restrict__ fd32,
                                                       float* __restrict__ outp) {
    __shared__ ushort ET[2][64][LDE];
    const int bid = blockIdx.x;
    const int b = (bid >> 1) & 3;
    const int m0 = ((((bid >> 3) << 1) | (bid & 1))) * 64;
    const int t = threadIdx.x, lane = t & 63, w = t >> 6;
    const int l15 = lane & 15, q = lane >> 4;
    const int a = w & 3, h = w >> 2;
    const size_t fb = (size_t)b * C_ * N_;

    long bfr[2][8];
    #pragma unroll
    for (int jt = 0; jt < 2; ++jt)
        #pragma unroll
        for (int kk = 0; kk < 8; ++kk)
            bfr[jt][kk] = *(const long*)(xfrag8 + xfi8(b, (m0 >> 4) + 2 * h + jt, kk) + (size_t)lane * 8);

    f32x4 acc[2][4];
    #pragma unroll
    for (int ct = 0; ct < 2; ++ct)
        #pragma unroll
        for (int mt = 0; mt < 4; ++mt)
            acc[ct][mt] = (f32x4){0.f, 0.f, 0.f, 0.f};

    long an[8];
    #pragma unroll
    for (int kk = 0; kk < 8; ++kk)
        an[kk] = *(const long*)(xfrag8 + xfi8(b, a, kk) + (size_t)lane * 8);
    float gn[4];
    #pragma unroll
    for (int r = 0; r < 4; ++r) gn[r] = gg[b * N_ + 16 * a + 4 * q + r];

    int p = 0;
    for (int n0c = 0; n0c < N_; n0c += 64, p ^= 1) {
        const int nc = n0c >> 6;
        short8 fn[2][2];
        #pragma unroll
        for (int ct = 0; ct < 2; ++ct)
            #pragma unroll
            for (int k2 = 0; k2 < 2; ++k2)
                fn[ct][k2] = *(const short8*)(ffrag + ffi(b, nc, 2 * w + ct, k2) + lane * 8);
        float gv[4];
        #pragma unroll
        for (int r = 0; r < 4; ++r) gv[r] = gn[r];
        const int nx = (n0c + 64 < N_) ? n0c + 64 : 0;
        #pragma unroll
        for (int r = 0; r < 4; ++r) gn[r] = gg[b * N_ + nx + 16 * a + 4 * q + r];

        f32x4 s0 = {0.f, 0.f, 0.f, 0.f}, s1 = {0.f, 0.f, 0.f, 0.f};
        #pragma unroll
        for (int kk = 0; kk < 8; ++kk) {
            s0 = mfma8(an[kk], bfr[0][kk], s0);
            s1 = mfma8(an[kk], bfr[1][kk], s1);
            an[kk] = *(const long*)(xfrag8 + xfi8(b, (nx >> 4) + a, kk) + (size_t)lane * 8);
        }
        ushort4 e0, e1;
        e0.x = f2bf(__expf(s0[0] - gv[0])); e0.y = f2bf(__expf(s0[1] - gv[1]));
        e0.z = f2bf(__expf(s0[2] - gv[2])); e0.w = f2bf(__expf(s0[3] - gv[3]));
        e1.x = f2bf(__expf(s1[0] - gv[0])); e1.y = f2bf(__expf(s1[1] - gv[1]));
        e1.z = f2bf(__expf(s1[2] - gv[2])); e1.w = f2bf(__expf(s1[3] - gv[3]));
        *(ushort4*)(&ET[p][32 * h + l15][16 * a + 4 * q])      = e0;
        *(ushort4*)(&ET[p][32 * h + 16 + l15][16 * a + 4 * q]) = e1;

        asm volatile("s_waitcnt lgkmcnt(0)\n\ts_barrier" ::: "memory");

        #pragma unroll
        for (int k2 = 0; k2 < 2; ++k2) {
            #pragma unroll
            for (int mt = 0; mt < 4; ++mt) {
                const short8 be = *(const short8*)(&ET[p][16 * mt + l15][32 * k2 + 8 * q]);
                acc[0][mt] = mfma16(fn[0][k2], be, acc[0][mt]);
                acc[1][mt] = mfma16(fn[1][k2], be, acc[1][mt]);
            }
        }
    }
    #pragma unroll
    for (int ct = 0; ct < 2; ++ct)
        #pragma unroll
        for (int mt = 0; mt < 4; ++mt)
            #pragma unroll
            for (int r = 0; r < 4; ++r) {
                const int c = 32 * w + 16 * ct + 4 * q + r;
                const int m = m0 + 16 * mt + l15;
                const size_t o = fb + (size_t)c * N_ + m;
                outp[o] = acc[ct][mt][r] + fd32[o];
            }
}

// ---------------------------------------------------------------------------
extern "C" void kernel_launch(void* const* d_in, const int* in_sizes, int n_in,
                              void* d_out, int out_size, void* d_ws, size_t ws_size,
                              hipStream_t stream) {
    const float* fm = (const float*)d_in[0];
    const float* fd = (const float*)d_in[1];
    float* outp = (float*)d_out;

    const size_t xb_elts = (size_t)B_ * N_ * C_;                 // 4.19M
    const size_t e_bytes = (size_t)B_ * N_ * N_;                 // 67.1 MB
    const size_t z_bytes = (size_t)B_ * 64 * 256;                // 64 KB
    const size_t f_bytes = (size_t)B_ * N_ * 4;                  // 64 KB each
    const size_t need_e  = xb_elts + e_bytes + z_bytes + 3 * f_bytes;
    const size_t need_g  = xb_elts * 3 + f_bytes;

    uchar* xfrag8 = (uchar*)d_ws;

    if (ws_size >= need_e) {
        uchar* E8     = xfrag8 + xb_elts;
        uchar* zmask  = E8 + e_bytes;
        float* rsbase = (float*)(zmask + z_bytes);
        float* rsadd  = rsbase + (size_t)B_ * N_;
        float* dgall  = rsadd + (size_t)B_ * N_;
        hipMemsetAsync(rsadd, 0, f_bytes, stream);
        prep_x_kernel<<<dim3(N_ / 64, C_ / 64, B_), 256, 0, stream>>>(fm, fd, xfrag8);
        lsum_t_kernel<<<dim3(256), 512, 0, stream>>>(xfrag8, E8, zmask, rsbase, rsadd, dgall);
        out_e_kernel<<<dim3(256), 512, 0, stream>>>(E8, zmask, rsbase, rsadd, dgall, xfrag8, fd, outp);
    } else if (ws_size >= need_g) {
        ushort* ffrag = (ushort*)(xfrag8 + xb_elts);
        float*  lg    = (float*)(xfrag8 + xb_elts * 3);
        prep_kernel<<<dim3(N_ / 64, C_ / 64, B_), 256, 0, stream>>>(fm, fd, xfrag8, ffrag);
        lsum_g_kernel<<<dim3(256), 512, 0, stream>>>(xfrag8, lg);
        out_g_kernel<<<dim3(256), 512, 0, stream>>>(xfrag8, ffrag, lg, fd, outp);
    }
}

// Round 10
// 111.174 us; speedup vs baseline: 1.7554x; 1.0349x over previous
//
#include <hip/hip_runtime.h>
#include <math.h>

#define B_ 4
#define C_ 256
#define N_ 4096   // H*W
#define LDE 68    // ET row stride (ushorts) — fallback path
#define LDX 72    // prep LDS tile stride (ushorts)

typedef __attribute__((ext_vector_type(8))) short short8;
typedef __attribute__((ext_vector_type(4))) float f32x4;
typedef __attribute__((ext_vector_type(2))) float f32x2;

__device__ inline ushort f2bf(float f) {
    uint u = __float_as_uint(f);
    return (ushort)((u + 0x7fffu + ((u >> 16) & 1u)) >> 16);   // RNE
}
__device__ inline float bf2f(ushort h) { return __uint_as_float(((uint)h) << 16); }

__device__ inline f32x4 mfma16(short8 a, short8 b, f32x4 c) {
    return __builtin_amdgcn_mfma_f32_16x16x32_bf16(a, b, c, 0, 0, 0);
}
__device__ inline f32x4 mfma8(long a, long b, f32x4 c) {
    return __builtin_amdgcn_mfma_f32_16x16x32_fp8_fp8(a, b, c, 0, 0, 0);
}

// Layouts:
//   xfrag8[b][nt=0..255][kk=0..7][lane][8 fp8]   (X = fp8(fm+fd), k=c)
//   E8    [b][mt=0..255][ng=0..511][ml=0..15][8] (E^T fp8)
//   zmask [b][nc=0..63][mt=0..255]  0=zero, 1=E8 valid, 2=recompute in out_e
//   rsbase/rsadd/dgall [b][n]       row-sum local / atomic remainder / diag shift
__device__ inline size_t xfi8(int b, int nt, int kk) {
    return (((size_t)(b * 256 + nt)) * 8 + kk) * 512;
}
__device__ inline size_t ffi(int b, int nc, int ct, int k2) {   // fallback only
    return ((((size_t)(b * 64 + nc)) * 16 + ct) * 2 + k2) * 512;
}
__device__ inline size_t eti(int b, int mt, int ng) {
    return (((size_t)(b * 256 + mt)) * 512 + (size_t)ng) * 128;
}
__device__ inline size_t zmi(int b, int nc, int mt) {
    return ((size_t)(b * 64 + nc)) * 256 + mt;
}

// ---------------------------------------------------------------------------
// P0x: build xfrag8 only.
// ---------------------------------------------------------------------------
__global__ __launch_bounds__(256) void prep_x_kernel(const float* __restrict__ fm,
                                                     const float* __restrict__ fd,
                                                     uchar* __restrict__ xfrag8) {
    __shared__ ushort xl[64][LDX];
    const int b = blockIdx.z, c0 = blockIdx.y * 64, n0 = blockIdx.x * 64;
    const int t = threadIdx.x;
    const int n4 = (t & 15) * 4, cl = t >> 4;
    const size_t base = (size_t)b * C_ * N_;
    #pragma unroll
    for (int p = 0; p < 4; ++p) {
        const int cr = 16 * p + cl;
        const float4 m4 = *(const float4*)(fm + base + (size_t)(c0 + cr) * N_ + n0 + n4);
        const float4 d4 = *(const float4*)(fd + base + (size_t)(c0 + cr) * N_ + n0 + n4);
        ushort4 xo;
        xo.x = f2bf(m4.x + d4.x); xo.y = f2bf(m4.y + d4.y);
        xo.z = f2bf(m4.z + d4.z); xo.w = f2bf(m4.w + d4.w);
        *(ushort4*)(&xl[cr][n4]) = xo;
    }
    __syncthreads();
    const int l = t & 63, tl = t >> 6;
    const int nl = 16 * tl + (l & 15);
    #pragma unroll
    for (int j = 0; j < 2; ++j) {
        const int kk = (c0 >> 5) + j;
        const int cb = 32 * j + 8 * (l >> 4);
        float f[8];
        #pragma unroll
        for (int i = 0; i < 8; ++i) f[i] = bf2f(xl[cb + i][nl]);
        int d0 = __builtin_amdgcn_cvt_pk_fp8_f32(f[0], f[1], 0, 0);
        d0 = __builtin_amdgcn_cvt_pk_fp8_f32(f[2], f[3], d0, 1);
        int d1 = __builtin_amdgcn_cvt_pk_fp8_f32(f[4], f[5], 0, 0);
        d1 = __builtin_amdgcn_cvt_pk_fp8_f32(f[6], f[7], d1, 1);
        uint* dst = (uint*)(xfrag8 + xfi8(b, (n0 >> 4) + tl, kk) + (size_t)l * 8);
        dst[0] = (uint)d0; dst[1] = (uint)d1;
    }
}

// ---------------------------------------------------------------------------
// DG: dgall[n] = S[n,n] via the SAME mfma8(af,af) sequence lsum used —
// bitwise identical shift values. Also zeroes rsadd (kills the memset
// dispatch). 1024 waves, reads 4.2 MB: ~2 µs.
// ---------------------------------------------------------------------------
__global__ __launch_bounds__(256) void dg_kernel(const uchar* __restrict__ xfrag8,
                                                 float* __restrict__ dgall,
                                                 float* __restrict__ rsadd) {
    const int t = threadIdx.x, lane = t & 63, w = t >> 6;
    const int tid = blockIdx.x * 4 + w;          // 1024 tiles (b, nt)
    const int b = tid >> 8, nt = tid & 255;
    const int l15 = lane & 15, q = lane >> 4;
    long af[8];
    #pragma unroll
    for (int kk = 0; kk < 8; ++kk)
        af[kk] = *(const long*)(xfrag8 + xfi8(b, nt, kk) + (size_t)lane * 8);
    f32x4 dacc = {0.f, 0.f, 0.f, 0.f};
    #pragma unroll
    for (int kk = 0; kk < 8; ++kk)
        dacc = mfma8(af[kk], af[kk], dacc);
    // diag elem 4q'+r of the tile lives in lane 20q'+r, reg r
    float dvv[4];
    #pragma unroll
    for (int r = 0; r < 4; ++r)
        dvv[r] = __shfl(dacc[r], 20 * q + r, 64);
    if (l15 == 0) {
        #pragma unroll
        for (int r = 0; r < 4; ++r)
            dgall[b * N_ + 16 * nt + 4 * q + r] = dvv[r];
    }
    const int zi = blockIdx.x * 256 + t;
    if (zi < B_ * N_) rsadd[zi] = 0.f;
}

// ---------------------------------------------------------------------------
// K2t v2: TRIANGULAR Gram, diag shifts PRELOADED from dgall (A-side bitwise
// identical to the old in-kernel dv; B-side twin shift is now ONE prefetched
// load per iteration instead of 64 VALU ops). Block (b,j) owns pairs {j,k},
// owner = (j+k)%2==0 ? min : max. A-side: exp-skip + E8 + zmask=1 + local rs.
// B-side: skip-test only; if nonzero (never on real data): zmask=2 via LDS +
// atomicAdd col-sums into rsadd.
// ---------------------------------------------------------------------------
__global__ __launch_bounds__(512, 2) void lsum_t_kernel(const uchar* __restrict__ xfrag8,
                                                        const float* __restrict__ dgall,
                                                        uchar* __restrict__ E8,
                                                        uchar* __restrict__ zmask,
                                                        float* __restrict__ rsbase,
                                                        float* __restrict__ rsadd) {
    __shared__ float red[8][64];
    __shared__ uchar chl[34];
    __shared__ int cnt_s;
    __shared__ uint zst[34];
    const int bid = blockIdx.x;
    const int b = (bid >> 1) & 3;
    const int n0 = ((((bid >> 3) << 1) | (bid & 1))) * 64;
    const int j = n0 >> 6;
    const int t = threadIdx.x, lane = t & 63, w = t >> 6;
    const int l15 = lane & 15, q = lane >> 4;
    const int g = w >> 2, wm = w & 3;

    if (t == 0) {
        int c = 0;
        chl[c++] = (uchar)j;                       // diag first
        for (int k = 0; k < 64; ++k) {
            if (k == j) continue;
            const bool own = (k > j) ? (((j + k) & 1) == 0) : (((j + k) & 1) == 1);
            if (own) chl[c++] = (uchar)k;
        }
        cnt_s = c;
    }
    if (t < 34) zst[t] = 0u;

    long af[4][8];
    #pragma unroll
    for (int ns = 0; ns < 4; ++ns)
        #pragma unroll
        for (int kk = 0; kk < 8; ++kk)
            af[ns][kk] = *(const long*)(xfrag8 + xfi8(b, (n0 >> 4) + ns, kk) + (size_t)lane * 8);

    // A-side diag shift, preloaded (bitwise == old in-kernel mfma8(af,af) dv)
    float dv[4][4];
    #pragma unroll
    for (int ns = 0; ns < 4; ++ns)
        #pragma unroll
        for (int r = 0; r < 4; ++r)
            dv[ns][r] = dgall[b * N_ + n0 + 16 * ns + 4 * q + r];

    __syncthreads();
    const int cnt = cnt_s;

    long bn[8];
    float dgm_cur;
    {
        const int mt0 = 4 * (int)chl[g] + wm;      // g < cnt always (cnt >= 32)
        #pragma unroll
        for (int kk = 0; kk < 8; ++kk)
            bn[kk] = *(const long*)(xfrag8 + xfi8(b, mt0, kk) + (size_t)lane * 8);
        dgm_cur = dgall[b * N_ + 16 * mt0 + l15];
    }
    const size_t ebl = (size_t)l15 * 8 + 4 * (q & 1);
    const int ngb = (n0 >> 3) + (q >> 1);

    float rs[4][4] = {};
    for (int it = 0; it < 17; ++it) {
        const int idx = 2 * it + g;
        const bool valid = idx < cnt;
        const int kc = chl[valid ? idx : 0];
        const int mt = 4 * kc + wm;
        int idxn = 2 * (it + 1) + g; if (idxn >= cnt) idxn = 0;
        const int mtn = 4 * (int)chl[idxn] + wm;

        f32x4 a0 = {0.f,0.f,0.f,0.f}, a1 = {0.f,0.f,0.f,0.f};
        f32x4 a2 = {0.f,0.f,0.f,0.f}, a3 = {0.f,0.f,0.f,0.f};
        __builtin_amdgcn_s_setprio(1);
        #pragma unroll
        for (int kk = 0; kk < 8; ++kk) {
            const long bc = bn[kk];
            a0 = mfma8(af[0][kk], bc, a0);
            a1 = mfma8(af[1][kk], bc, a1);
            a2 = mfma8(af[2][kk], bc, a2);
            a3 = mfma8(af[3][kk], bc, a3);
            bn[kk] = *(const long*)(xfrag8 + xfi8(b, mtn, kk) + (size_t)lane * 8);
        }
        __builtin_amdgcn_s_setprio(0);
        const float dgm = dgm_cur;                 // |x_m|^2 for row l15 of mt
        dgm_cur = dgall[b * N_ + 16 * mtn + l15];  // prefetch next

        float df[4][4];
#define EDF(AA, NS)                                                    \
        df[NS][0] = AA[0] - dv[NS][0]; df[NS][1] = AA[1] - dv[NS][1];  \
        df[NS][2] = AA[2] - dv[NS][2]; df[NS][3] = AA[3] - dv[NS][3];
        EDF(a0, 0) EDF(a1, 1) EDF(a2, 2) EDF(a3, 3)
#undef EDF
        const float mxA = fmaxf(
            fmaxf(fmaxf(fmaxf(df[0][0], df[0][1]), fmaxf(df[0][2], df[0][3])),
                  fmaxf(fmaxf(df[1][0], df[1][1]), fmaxf(df[1][2], df[1][3]))),
            fmaxf(fmaxf(fmaxf(df[2][0], df[2][1]), fmaxf(df[2][2], df[2][3])),
                  fmaxf(fmaxf(df[3][0], df[3][1]), fmaxf(df[3][2], df[3][3]))));
        const bool nzA = valid && (__ballot(mxA > -30.0f) != 0ULL);
        if (valid && lane == 0) zmask[zmi(b, j, mt)] = nzA ? 1 : 0;
        if (nzA) {
            uint dpk[4];
#define EEXP(NS)                                                                       \
            {                                                                          \
                float e0 = __expf(df[NS][0]), e1 = __expf(df[NS][1]);                  \
                float e2 = __expf(df[NS][2]), e3 = __expf(df[NS][3]);                  \
                rs[NS][0] += e0; rs[NS][1] += e1; rs[NS][2] += e2; rs[NS][3] += e3;    \
                int d = __builtin_amdgcn_cvt_pk_fp8_f32(e0, e1, 0, 0);                 \
                d = __builtin_amdgcn_cvt_pk_fp8_f32(e2, e3, d, 1);                     \
                dpk[NS] = (uint)d;                                                     \
            }
            EEXP(0) EEXP(1) EEXP(2) EEXP(3)
#undef EEXP
            #pragma unroll
            for (int ns = 0; ns < 4; ++ns)
                *(uint*)(E8 + eti(b, mt, ngb + 2 * ns) + ebl) = dpk[ns];
        }
        // ---- B-side (twin rows k): skip-test + rare atomic remainder ----
        if (valid && kc != j) {
            float dfB[4][4];
            #pragma unroll
            for (int ns = 0; ns < 4; ++ns) {
                dfB[ns][0] = (ns==0?a0[0]:ns==1?a1[0]:ns==2?a2[0]:a3[0]) - dgm;
                dfB[ns][1] = (ns==0?a0[1]:ns==1?a1[1]:ns==2?a2[1]:a3[1]) - dgm;
                dfB[ns][2] = (ns==0?a0[2]:ns==1?a1[2]:ns==2?a2[2]:a3[2]) - dgm;
                dfB[ns][3] = (ns==0?a0[3]:ns==1?a1[3]:ns==2?a2[3]:a3[3]) - dgm;
            }
            uint bits = 0;
            #pragma unroll
            for (int ns = 0; ns < 4; ++ns) {
                const float m2 = fmaxf(fmaxf(dfB[ns][0], dfB[ns][1]),
                                       fmaxf(dfB[ns][2], dfB[ns][3]));
                if (__ballot(m2 > -30.0f) != 0ULL) bits |= (1u << ns);
            }
            if (bits) {                                 // never on real data
                if (lane == 0) atomicOr(&zst[idx], bits);
                float cs = 0.f;
                #pragma unroll
                for (int ns = 0; ns < 4; ++ns)
                    #pragma unroll
                    for (int r = 0; r < 4; ++r)
                        cs += __expf(dfB[ns][r]);
                cs += __shfl_xor(cs, 16, 64);
                cs += __shfl_xor(cs, 32, 64);
                if (q == 0) atomicAdd(rsadd + b * N_ + 16 * mt + l15, cs);
            }
        }
    }
    #pragma unroll
    for (int off = 1; off < 16; off <<= 1)
        #pragma unroll
        for (int ns = 0; ns < 4; ++ns)
            #pragma unroll
            for (int r = 0; r < 4; ++r)
                rs[ns][r] += __shfl_xor(rs[ns][r], off, 64);
    if (l15 == 0) {
        #pragma unroll
        for (int ns = 0; ns < 4; ++ns)
            #pragma unroll
            for (int r = 0; r < 4; ++r)
                red[w][16 * ns + 4 * q + r] = rs[ns][r];
    }
    __syncthreads();
    if (t < 64) {
        float s = 0.f;
        #pragma unroll
        for (int ww = 0; ww < 8; ++ww) s += red[ww][t];
        rsbase[b * N_ + n0 + t] = s;
    }
    if (t >= 64 && t < 64 + 33 * 4) {
        const int ii = (t - 64) >> 2, ns = (t - 64) & 3;
        const int idx = ii + 1;
        if (idx < cnt) {
            const int kc = chl[idx];
            zmask[zmi(b, kc, 4 * j + ns)] = (((zst[idx] >> ns) & 1u) != 0u) ? 2 : 0;
        }
    }
}

// ---------------------------------------------------------------------------
// K3e v4: out[c,m] = sum_n (fd[c,n]*sinv[n]) * E[n,m] + fd[c,m].
// sinv = 1/(rsbase+rsadd). Per-mt zmask byte guards: 0=skip, 1=E8, 2(or
// unexpected)=self-recompute from xfrag8+dgall (never on real data).
// ---------------------------------------------------------------------------
__global__ __launch_bounds__(512, 2) void out_e_kernel(const uchar* __restrict__ E8,
                                                       const uchar* __restrict__ zmask,
                                                       const float* __restrict__ rsbase,
                                                       const float* __restrict__ rsadd,
                                                       const float* __restrict__ dgall,
                                                       const uchar* __restrict__ xfrag8,
                                                       const float* __restrict__ fd32,
                                                       float* __restrict__ outp) {
    __shared__ ushort esc[8][16][66];   // per-wave recompute scratch
    const int bid = blockIdx.x;
    const int b = (bid >> 1) & 3;
    const int m0 = ((((bid >> 3) << 1) | (bid & 1))) * 64;
    const int t = threadIdx.x, lane = t & 63, w = t >> 6;
    const int l15 = lane & 15, q = lane >> 4;
    const size_t fb = (size_t)b * C_ * N_;
    const uchar* mrow = zmask + zmi(b, 0, m0 >> 4);

    f32x4 acc[2][4];
    #pragma unroll
    for (int ct = 0; ct < 2; ++ct)
        #pragma unroll
        for (int mt = 0; mt < 4; ++mt)
            acc[ct][mt] = (f32x4){0.f, 0.f, 0.f, 0.f};

    for (int gg = 0; gg < 8; ++gg) {
        uint mk[8];
        #pragma unroll
        for (int i = 0; i < 8; ++i)
            mk[i] = *(const uint*)(mrow + (size_t)(8 * gg + i) * 256);
        #pragma unroll
        for (int i = 0; i < 8; ++i) {
            const uint mki = mk[i];
            if (mki == 0) continue;
            const int nc = 8 * gg + i;
            // sinv for this lane's 16 k-elems (8 per k2 half)
            const float* rb = rsbase + b * N_ + 64 * nc + 8 * q;
            const float* ra = rsadd + b * N_ + 64 * nc + 8 * q;
            float4 s0[2], s1[2];
            #pragma unroll
            for (int k2 = 0; k2 < 2; ++k2) {
                const float4 b0 = *(const float4*)(rb + 32 * k2);
                const float4 b1 = *(const float4*)(rb + 32 * k2 + 4);
                const float4 a0v = *(const float4*)(ra + 32 * k2);
                const float4 a1v = *(const float4*)(ra + 32 * k2 + 4);
                s0[k2].x = 1.0f / (b0.x + a0v.x); s0[k2].y = 1.0f / (b0.y + a0v.y);
                s0[k2].z = 1.0f / (b0.z + a0v.z); s0[k2].w = 1.0f / (b0.w + a0v.w);
                s1[k2].x = 1.0f / (b1.x + a1v.x); s1[k2].y = 1.0f / (b1.y + a1v.y);
                s1[k2].z = 1.0f / (b1.z + a1v.z); s1[k2].w = 1.0f / (b1.w + a1v.w);
            }
            short8 fn[2][2];
            #pragma unroll
            for (int ct = 0; ct < 2; ++ct) {
                const int c = 32 * w + 16 * ct + l15;
                const float* frow = fd32 + fb + (size_t)c * N_ + 64 * nc + 8 * q;
                #pragma unroll
                for (int k2 = 0; k2 < 2; ++k2) {
                    const float4 fa = *(const float4*)(frow + 32 * k2);
                    const float4 fb4 = *(const float4*)(frow + 32 * k2 + 4);
                    union { ushort us[8]; short8 v; } u;
                    u.us[0] = f2bf(fa.x * s0[k2].x); u.us[1] = f2bf(fa.y * s0[k2].y);
                    u.us[2] = f2bf(fa.z * s0[k2].z); u.us[3] = f2bf(fa.w * s0[k2].w);
                    u.us[4] = f2bf(fb4.x * s1[k2].x); u.us[5] = f2bf(fb4.y * s1[k2].y);
                    u.us[6] = f2bf(fb4.z * s1[k2].z); u.us[7] = f2bf(fb4.w * s1[k2].w);
                    fn[ct][k2] = u.v;
                }
            }
            if ((mki & ~0x01010101u) == 0u) {
                // ---- E8 path with per-mt validity ----
                #pragma unroll
                for (int k2 = 0; k2 < 2; ++k2) {
                    #pragma unroll
                    for (int mt = 0; mt < 4; ++mt) {
                        if (((mki >> (8 * mt)) & 0xffu) != 1u) continue;
                        const long e8 = *(const long*)(E8 + eti(b, (m0 >> 4) + mt, 8 * nc + 4 * k2 + q) + (size_t)l15 * 8);
                        const uint lo = (uint)(unsigned long)e8;
                        const uint hi = (uint)((unsigned long)e8 >> 32);
                        const f32x2 f01 = __builtin_amdgcn_cvt_pk_f32_fp8((int)lo, false);
                        const f32x2 f23 = __builtin_amdgcn_cvt_pk_f32_fp8((int)lo, true);
                        const f32x2 f45 = __builtin_amdgcn_cvt_pk_f32_fp8((int)hi, false);
                        const f32x2 f67 = __builtin_amdgcn_cvt_pk_f32_fp8((int)hi, true);
                        union { uint u[4]; short8 v; } be;
                        asm("v_cvt_pk_bf16_f32 %0, %1, %2" : "=v"(be.u[0]) : "v"(f01.x), "v"(f01.y));
                        asm("v_cvt_pk_bf16_f32 %0, %1, %2" : "=v"(be.u[1]) : "v"(f23.x), "v"(f23.y));
                        asm("v_cvt_pk_bf16_f32 %0, %1, %2" : "=v"(be.u[2]) : "v"(f45.x), "v"(f45.y));
                        asm("v_cvt_pk_bf16_f32 %0, %1, %2" : "=v"(be.u[3]) : "v"(f67.x), "v"(f67.y));
                        acc[0][mt] = mfma16(fn[0][k2], be.v, acc[0][mt]);
                        acc[1][mt] = mfma16(fn[1][k2], be.v, acc[1][mt]);
                    }
                }
            } else {
                // ---- recompute path (degenerate inputs only) ----
                #pragma unroll
                for (int mt = 0; mt < 4; ++mt) {
                    long bmf[8];
                    #pragma unroll
                    for (int kk = 0; kk < 8; ++kk)
                        bmf[kk] = *(const long*)(xfrag8 + xfi8(b, (m0 >> 4) + mt, kk) + (size_t)lane * 8);
                    #pragma unroll
                    for (int nt = 0; nt < 4; ++nt) {
                        long anf[8];
                        #pragma unroll
                        for (int kk = 0; kk < 8; ++kk)
                            anf[kk] = *(const long*)(xfrag8 + xfi8(b, 4 * nc + nt, kk) + (size_t)lane * 8);
                        f32x4 sacc = {0.f, 0.f, 0.f, 0.f};
                        #pragma unroll
                        for (int kk = 0; kk < 8; ++kk)
                            sacc = mfma8(anf[kk], bmf[kk], sacc);
                        #pragma unroll
                        for (int r = 0; r < 4; ++r) {
                            const float gv = dgall[b * N_ + 64 * nc + 16 * nt + 4 * q + r];
                            esc[w][l15][16 * nt + 4 * q + r] = f2bf(__expf(sacc[r] - gv));
                        }
                    }
                    #pragma unroll
                    for (int k2 = 0; k2 < 2; ++k2) {
                        const short8 be = *(const short8*)(&esc[w][l15][32 * k2 + 8 * q]);
                        acc[0][mt] = mfma16(fn[0][k2], be, acc[0][mt]);
                        acc[1][mt] = mfma16(fn[1][k2], be, acc[1][mt]);
                    }
                }
            }
        }
    }
    #pragma unroll
    for (int ct = 0; ct < 2; ++ct)
        #pragma unroll
        for (int mt = 0; mt < 4; ++mt)
            #pragma unroll
            for (int r = 0; r < 4; ++r) {
                const int c = 32 * w + 16 * ct + 4 * q + r;
                const int m = m0 + 16 * mt + l15;
                const size_t o = fb + (size_t)c * N_ + m;
                outp[o] = acc[ct][mt][r] + fd32[o];
            }
}

// ===========================================================================
// FALLBACK PATH (round-4 kernels) — used when ws_size < E8 requirement.
// ===========================================================================
__global__ __launch_bounds__(256) void prep_kernel(const float* __restrict__ fm,
                                                   const float* __restrict__ fd,
                                                   uchar* __restrict__ xfrag8,
                                                   ushort* __restrict__ ffrag) {
    __shared__ ushort xl[64][LDX];
    __shared__ ushort fl[64][LDX];
    const int b = blockIdx.z, c0 = blockIdx.y * 64, n0 = blockIdx.x * 64;
    const int t = threadIdx.x;
    const int n4 = (t & 15) * 4, cl = t >> 4;
    const size_t base = (size_t)b * C_ * N_;
    #pragma unroll
    for (int p = 0; p < 4; ++p) {
        const int cr = 16 * p + cl;
        const float4 m4 = *(const float4*)(fm + base + (size_t)(c0 + cr) * N_ + n0 + n4);
        const float4 d4 = *(const float4*)(fd + base + (size_t)(c0 + cr) * N_ + n0 + n4);
        ushort4 fo;
        fo.x = f2bf(d4.x); fo.y = f2bf(d4.y); fo.z = f2bf(d4.z); fo.w = f2bf(d4.w);
        *(ushort4*)(&fl[cr][n4]) = fo;
        ushort4 xo;
        xo.x = f2bf(m4.x + d4.x); xo.y = f2bf(m4.y + d4.y);
        xo.z = f2bf(m4.z + d4.z); xo.w = f2bf(m4.w + d4.w);
        *(ushort4*)(&xl[cr][n4]) = xo;
    }
    __syncthreads();
    const int l = t & 63, tl = t >> 6;
    {
        const int nl = 16 * tl + (l & 15);
        #pragma unroll
        for (int j = 0; j < 2; ++j) {
            const int kk = (c0 >> 5) + j;
            const int cb = 32 * j + 8 * (l >> 4);
            float f[8];
            #pragma unroll
            for (int i = 0; i < 8; ++i) f[i] = bf2f(xl[cb + i][nl]);
            int d0 = __builtin_amdgcn_cvt_pk_fp8_f32(f[0], f[1], 0, 0);
            d0 = __builtin_amdgcn_cvt_pk_fp8_f32(f[2], f[3], d0, 1);
            int d1 = __builtin_amdgcn_cvt_pk_fp8_f32(f[4], f[5], 0, 0);
            d1 = __builtin_amdgcn_cvt_pk_fp8_f32(f[6], f[7], d1, 1);
            uint* dst = (uint*)(xfrag8 + xfi8(b, (n0 >> 4) + tl, kk) + (size_t)l * 8);
            dst[0] = (uint)d0; dst[1] = (uint)d1;
        }
    }
    {
        const int row = 16 * tl + (l & 15);
        #pragma unroll
        for (int k2 = 0; k2 < 2; ++k2) {
            const int col = 32 * k2 + 8 * (l >> 4);
            const ushort4 a0 = *(const ushort4*)(&fl[row][col]);
            const ushort4 a1 = *(const ushort4*)(&fl[row][col + 4]);
            ushort* dst = ffrag + ffi(b, n0 >> 6, (c0 >> 4) + tl, k2) + l * 8;
            *(ushort4*)(dst) = a0; *(ushort4*)(dst + 4) = a1;
        }
    }
}

__global__ __launch_bounds__(512, 2) void lsum_g_kernel(const uchar* __restrict__ xfrag8,
                                                        float* __restrict__ lg) {
    __shared__ float red[8][64];
    __shared__ float dgl[64];
    const int bid = blockIdx.x;
    const int b = (bid >> 1) & 3;
    const int n0 = ((((bid >> 3) << 1) | (bid & 1))) * 64;
    const int t = threadIdx.x, lane = t & 63, w = t >> 6;
    const int l15 = lane & 15, q = lane >> 4;

    long af[4][8];
    #pragma unroll
    for (int ns = 0; ns < 4; ++ns)
        #pragma unroll
        for (int kk = 0; kk < 8; ++kk)
            af[ns][kk] = *(const long*)(xfrag8 + xfi8(b, (n0 >> 4) + ns, kk) + (size_t)lane * 8);

    float dv[4][4];
    #pragma unroll
    for (int ns = 0; ns < 4; ++ns) {
        f32x4 dacc = {0.f, 0.f, 0.f, 0.f};
        #pragma unroll
        for (int kk = 0; kk < 8; ++kk)
            dacc = mfma8(af[ns][kk], af[ns][kk], dacc);
        #pragma unroll
        for (int r = 0; r < 4; ++r)
            dv[ns][r] = __shfl(dacc[r], 20 * q + r, 64);
    }
    if (w == 0 && l15 == 0) {
        #pragma unroll
        for (int ns = 0; ns < 4; ++ns)
            #pragma unroll
            for (int r = 0; r < 4; ++r)
                dgl[16 * ns + 4 * q + r] = dv[ns][r];
    }

    long bn[8];
    #pragma unroll
    for (int kk = 0; kk < 8; ++kk)
        bn[kk] = *(const long*)(xfrag8 + xfi8(b, w, kk) + (size_t)lane * 8);

    float rs[4][4] = {};
    for (int mc = 0; mc < 32; ++mc) {
        const int mtn = (mc + 1 < 32) ? (mc + 1) * 8 + w : w;
        f32x4 a0 = {0.f,0.f,0.f,0.f}, a1 = {0.f,0.f,0.f,0.f};
        f32x4 a2 = {0.f,0.f,0.f,0.f}, a3 = {0.f,0.f,0.f,0.f};
        #pragma unroll
        for (int kk = 0; kk < 8; ++kk) {
            const long bc = bn[kk];
            a0 = mfma8(af[0][kk], bc, a0);
            a1 = mfma8(af[1][kk], bc, a1);
            a2 = mfma8(af[2][kk], bc, a2);
            a3 = mfma8(af[3][kk], bc, a3);
            bn[kk] = *(const long*)(xfrag8 + xfi8(b, mtn, kk) + (size_t)lane * 8);
        }
        #pragma unroll
        for (int r = 0; r < 4; ++r) {
            rs[0][r] += __expf(a0[r] - dv[0][r]);
            rs[1][r] += __expf(a1[r] - dv[1][r]);
            rs[2][r] += __expf(a2[r] - dv[2][r]);
            rs[3][r] += __expf(a3[r] - dv[3][r]);
        }
    }
    #pragma unroll
    for (int off = 1; off < 16; off <<= 1)
        #pragma unroll
        for (int ns = 0; ns < 4; ++ns)
            #pragma unroll
            for (int r = 0; r < 4; ++r)
                rs[ns][r] += __shfl_xor(rs[ns][r], off, 64);
    if (l15 == 0) {
        #pragma unroll
        for (int ns = 0; ns < 4; ++ns)
            #pragma unroll
            for (int r = 0; r < 4; ++r)
                red[w][16 * ns + 4 * q + r] = rs[ns][r];
    }
    __syncthreads();
    if (t < 64) {
        float s = 0.f;
        #pragma unroll
        for (int ww = 0; ww < 8; ++ww) s += red[ww][t];
        lg[b * N_ + n0 + t] = dgl[t] + __logf(s);
    }
}

__global__ __launch_bounds__(512, 2) void out_g_kernel(const uchar* __restrict__ xfrag8,
                                                       const ushort* __restrict__ ffrag,
                                                       const float* __restrict__ gg,
                                                       const float* __restrict__ fd32,
                                                       float* __restrict__ outp) {
    __shared__ ushort ET[2][64][LDE];
    const int bid = blockIdx.x;
    const int b = (bid >> 1) & 3;
    const int m0 = ((((bid >> 3) << 1) | (bid & 1))) * 64;
    const int t = threadIdx.x, lane = t & 63, w = t >> 6;
    const int l15 = lane & 15, q = lane >> 4;
    const int a = w & 3, h = w >> 2;
    const size_t fb = (size_t)b * C_ * N_;

    long bfr[2][8];
    #pragma unroll
    for (int jt = 0; jt < 2; ++jt)
        #pragma unroll
        for (int kk = 0; kk < 8; ++kk)
            bfr[jt][kk] = *(const long*)(xfrag8 + xfi8(b, (m0 >> 4) + 2 * h + jt, kk) + (size_t)lane * 8);

    f32x4 acc[2][4];
    #pragma unroll
    for (int ct = 0; ct < 2; ++ct)
        #pragma unroll
        for (int mt = 0; mt < 4; ++mt)
            acc[ct][mt] = (f32x4){0.f, 0.f, 0.f, 0.f};

    long an[8];
    #pragma unroll
    for (int kk = 0; kk < 8; ++kk)
        an[kk] = *(const long*)(xfrag8 + xfi8(b, a, kk) + (size_t)lane * 8);
    float gn[4];
    #pragma unroll
    for (int r = 0; r < 4; ++r) gn[r] = gg[b * N_ + 16 * a + 4 * q + r];

    int p = 0;
    for (int n0c = 0; n0c < N_; n0c += 64, p ^= 1) {
        const int nc = n0c >> 6;
        short8 fn[2][2];
        #pragma unroll
        for (int ct = 0; ct < 2; ++ct)
            #pragma unroll
            for (int k2 = 0; k2 < 2; ++k2)
                fn[ct][k2] = *(const short8*)(ffrag + ffi(b, nc, 2 * w + ct, k2) + lane * 8);
        float gv[4];
        #pragma unroll
        for (int r = 0; r < 4; ++r) gv[r] = gn[r];
        const int nx = (n0c + 64 < N_) ? n0c + 64 : 0;
        #pragma unroll
        for (int r = 0; r < 4; ++r) gn[r] = gg[b * N_ + nx + 16 * a + 4 * q + r];

        f32x4 s0 = {0.f, 0.f, 0.f, 0.f}, s1 = {0.f, 0.f, 0.f, 0.f};
        #pragma unroll
        for (int kk = 0; kk < 8; ++kk) {
            s0 = mfma8(an[kk], bfr[0][kk], s0);
            s1 = mfma8(an[kk], bfr[1][kk], s1);
            an[kk] = *(const long*)(xfrag8 + xfi8(b, (nx >> 4) + a, kk) + (size_t)lane * 8);
        }
        ushort4 e0, e1;
        e0.x = f2bf(__expf(s0[0] - gv[0])); e0.y = f2bf(__expf(s0[1] - gv[1]));
        e0.z = f2bf(__expf(s0[2] - gv[2])); e0.w = f2bf(__expf(s0[3] - gv[3]));
        e1.x = f2bf(__expf(s1[0] - gv[0])); e1.y = f2bf(__expf(s1[1] - gv[1]));
        e1.z = f2bf(__expf(s1[2] - gv[2])); e1.w = f2bf(__expf(s1[3] - gv[3]));
        *(ushort4*)(&ET[p][32 * h + l15][16 * a + 4 * q])      = e0;
        *(ushort4*)(&ET[p][32 * h + 16 + l15][16 * a + 4 * q]) = e1;

        asm volatile("s_waitcnt lgkmcnt(0)\n\ts_barrier" ::: "memory");

        #pragma unroll
        for (int k2 = 0; k2 < 2; ++k2) {
            #pragma unroll
            for (int mt = 0; mt < 4; ++mt) {
                const short8 be = *(const short8*)(&ET[p][16 * mt + l15][32 * k2 + 8 * q]);
                acc[0][mt] = mfma16(fn[0][k2], be, acc[0][mt]);
                acc[1][mt] = mfma16(fn[1][k2], be, acc[1][mt]);
            }
        }
    }
    #pragma unroll
    for (int ct = 0; ct < 2; ++ct)
        #pragma unroll
        for (int mt = 0; mt < 4; ++mt)
            #pragma unroll
            for (int r = 0; r < 4; ++r) {
                const int c = 32 * w + 16 * ct + 4 * q + r;
                const int m = m0 + 16 * mt + l15;
                const size_t o = fb + (size_t)c * N_ + m;
                outp[o] = acc[ct][mt][r] + fd32[o];
            }
}

// ---------------------------------------------------------------------------
extern "C" void kernel_launch(void* const* d_in, const int* in_sizes, int n_in,
                              void* d_out, int out_size, void* d_ws, size_t ws_size,
                              hipStream_t stream) {
    const float* fm = (const float*)d_in[0];
    const float* fd = (const float*)d_in[1];
    float* outp = (float*)d_out;

    const size_t xb_elts = (size_t)B_ * N_ * C_;                 // 4.19M
    const size_t e_bytes = (size_t)B_ * N_ * N_;                 // 67.1 MB
    const size_t z_bytes = (size_t)B_ * 64 * 256;                // 64 KB
    const size_t f_bytes = (size_t)B_ * N_ * 4;                  // 64 KB each
    const size_t need_e  = xb_elts + e_bytes + z_bytes + 3 * f_bytes;
    const size_t need_g  = xb_elts * 3 + f_bytes;

    uchar* xfrag8 = (uchar*)d_ws;

    if (ws_size >= need_e) {
        uchar* E8     = xfrag8 + xb_elts;
        uchar* zmask  = E8 + e_bytes;
        float* rsbase = (float*)(zmask + z_bytes);
        float* rsadd  = rsbase + (size_t)B_ * N_;
        float* dgall  = rsadd + (size_t)B_ * N_;
        prep_x_kernel<<<dim3(N_ / 64, C_ / 64, B_), 256, 0, stream>>>(fm, fd, xfrag8);
        dg_kernel<<<dim3(256), 256, 0, stream>>>(xfrag8, dgall, rsadd);
        lsum_t_kernel<<<dim3(256), 512, 0, stream>>>(xfrag8, dgall, E8, zmask, rsbase, rsadd);
        out_e_kernel<<<dim3(256), 512, 0, stream>>>(E8, zmask, rsbase, rsadd, dgall, xfrag8, fd, outp);
    } else if (ws_size >= need_g) {
        ushort* ffrag = (ushort*)(xfrag8 + xb_elts);
        float*  lg    = (float*)(xfrag8 + xb_elts * 3);
        prep_kernel<<<dim3(N_ / 64, C_ / 64, B_), 256, 0, stream>>>(fm, fd, xfrag8, ffrag);
        lsum_g_kernel<<<dim3(256), 512, 0, stream>>>(xfrag8, lg);
        out_g_kernel<<<dim3(256), 512, 0, stream>>>(xfrag8, ffrag, lg, fd, outp);
    }
}

// Round 11
// 109.125 us; speedup vs baseline: 1.7884x; 1.0188x over previous
//
#include <hip/hip_runtime.h>
#include <math.h>

#define B_ 4
#define C_ 256
#define N_ 4096   // H*W
#define LDE 68    // ET row stride (ushorts) — fallback path
#define LDX 72    // prep LDS tile stride (ushorts)

typedef __attribute__((ext_vector_type(8))) short short8;
typedef __attribute__((ext_vector_type(4))) float f32x4;
typedef __attribute__((ext_vector_type(2))) float f32x2;
typedef __attribute__((ext_vector_type(2))) long long2v;

__device__ inline ushort f2bf(float f) {
    uint u = __float_as_uint(f);
    return (ushort)((u + 0x7fffu + ((u >> 16) & 1u)) >> 16);   // RNE
}
__device__ inline float bf2f(ushort h) { return __uint_as_float(((uint)h) << 16); }

__device__ inline f32x4 mfma16(short8 a, short8 b, f32x4 c) {
    return __builtin_amdgcn_mfma_f32_16x16x32_bf16(a, b, c, 0, 0, 0);
}
__device__ inline f32x4 mfma8(long a, long b, f32x4 c) {
    return __builtin_amdgcn_mfma_f32_16x16x32_fp8_fp8(a, b, c, 0, 0, 0);
}

// E-path layouts:
//   xfrag8[b][nt=0..255][kk2=0..3][lane][16 fp8]  (two k-frags kk=2*kk2,2*kk2+1
//                                                  packed per lane -> dwordx4 loads)
//   E8    [b][mt=0..255][ng=0..511][ml=0..15][8]  (E^T fp8)
//   zmask [b][nc=0..63][mt=0..255]  0=zero, 1=E8 valid, 2=recompute in out_e
//   rsbase/rsadd/dgall [b][n]
__device__ inline size_t xfi16(int b, int nt, int kk2) {   // BYTE offset, no lane
    return (((size_t)(b * 256 + nt)) * 4 + kk2) * 1024;
}
__device__ inline size_t xfi8(int b, int nt, int kk) {     // FALLBACK layout
    return (((size_t)(b * 256 + nt)) * 8 + kk) * 512;
}
__device__ inline size_t ffi(int b, int nc, int ct, int k2) {   // fallback only
    return ((((size_t)(b * 64 + nc)) * 16 + ct) * 2 + k2) * 512;
}
__device__ inline size_t eti(int b, int mt, int ng) {
    return (((size_t)(b * 256 + mt)) * 512 + (size_t)ng) * 128;
}
__device__ inline size_t zmi(int b, int nc, int mt) {
    return ((size_t)(b * 64 + nc)) * 256 + mt;
}

// ---------------------------------------------------------------------------
// P0x: build xfrag8 (packed 16B/lane layout). One dwordx4 store per lane.
// ---------------------------------------------------------------------------
__global__ __launch_bounds__(256) void prep_x_kernel(const float* __restrict__ fm,
                                                     const float* __restrict__ fd,
                                                     uchar* __restrict__ xfrag8) {
    __shared__ ushort xl[64][LDX];
    const int b = blockIdx.z, c0 = blockIdx.y * 64, n0 = blockIdx.x * 64;
    const int t = threadIdx.x;
    const int n4 = (t & 15) * 4, cl = t >> 4;
    const size_t base = (size_t)b * C_ * N_;
    #pragma unroll
    for (int p = 0; p < 4; ++p) {
        const int cr = 16 * p + cl;
        const float4 m4 = *(const float4*)(fm + base + (size_t)(c0 + cr) * N_ + n0 + n4);
        const float4 d4 = *(const float4*)(fd + base + (size_t)(c0 + cr) * N_ + n0 + n4);
        ushort4 xo;
        xo.x = f2bf(m4.x + d4.x); xo.y = f2bf(m4.y + d4.y);
        xo.z = f2bf(m4.z + d4.z); xo.w = f2bf(m4.w + d4.w);
        *(ushort4*)(&xl[cr][n4]) = xo;
    }
    __syncthreads();
    const int l = t & 63, tl = t >> 6;
    const int nl = 16 * tl + (l & 15);
    uint dd[4];
    #pragma unroll
    for (int j = 0; j < 2; ++j) {          // j = kk&1 within this c-block
        const int cb = 32 * j + 8 * (l >> 4);
        float f[8];
        #pragma unroll
        for (int i = 0; i < 8; ++i) f[i] = bf2f(xl[cb + i][nl]);
        int d0 = __builtin_amdgcn_cvt_pk_fp8_f32(f[0], f[1], 0, 0);
        d0 = __builtin_amdgcn_cvt_pk_fp8_f32(f[2], f[3], d0, 1);
        int d1 = __builtin_amdgcn_cvt_pk_fp8_f32(f[4], f[5], 0, 0);
        d1 = __builtin_amdgcn_cvt_pk_fp8_f32(f[6], f[7], d1, 1);
        dd[2 * j] = (uint)d0; dd[2 * j + 1] = (uint)d1;
    }
    uint* dst = (uint*)(xfrag8 + xfi16(b, (n0 >> 4) + tl, c0 >> 6) + (size_t)l * 16);
    dst[0] = dd[0]; dst[1] = dd[1]; dst[2] = dd[2]; dst[3] = dd[3];
}

// ---------------------------------------------------------------------------
// DG: dgall[n] = S[n,n] via same-order mfma8 chain (bitwise == lsum's old dv).
// Also zeroes rsadd AND zmask (lsum now writes zmask sparsely).
// ---------------------------------------------------------------------------
__global__ __launch_bounds__(256) void dg_kernel(const uchar* __restrict__ xfrag8,
                                                 float* __restrict__ dgall,
                                                 float* __restrict__ rsadd,
                                                 uchar* __restrict__ zmask) {
    const int t = threadIdx.x, lane = t & 63, w = t >> 6;
    const int tid = blockIdx.x * 4 + w;          // 1024 tiles (b, nt)
    const int b = tid >> 8, nt = tid & 255;
    const int l15 = lane & 15, q = lane >> 4;
    long2v af[4];
    #pragma unroll
    for (int kk2 = 0; kk2 < 4; ++kk2)
        af[kk2] = *(const long2v*)(xfrag8 + xfi16(b, nt, kk2) + (size_t)lane * 16);
    f32x4 dacc = {0.f, 0.f, 0.f, 0.f};
    #pragma unroll
    for (int kk2 = 0; kk2 < 4; ++kk2) {
        dacc = mfma8(af[kk2].x, af[kk2].x, dacc);
        dacc = mfma8(af[kk2].y, af[kk2].y, dacc);
    }
    float dvv[4];
    #pragma unroll
    for (int r = 0; r < 4; ++r)
        dvv[r] = __shfl(dacc[r], 20 * q + r, 64);
    if (l15 == 0) {
        #pragma unroll
        for (int r = 0; r < 4; ++r)
            dgall[b * N_ + 16 * nt + 4 * q + r] = dvv[r];
    }
    const int zi = blockIdx.x * 256 + t;
    if (zi < B_ * N_) rsadd[zi] = 0.f;
    zmask[zi] = 0;                                // 65536 threads == 65536 bytes
}

// ---------------------------------------------------------------------------
// K2t v3: TRIANGULAR Gram, packed dwordx4 B-loads (4/iter instead of 8) and a
// wave-uniform whole-iteration gate: gmax(a) - min(dvmin, dgm) <= -30 (ballot)
// proves BOTH sides' tiles all-zero -> skip everything but loads+MFMA.
// zmask pre-zeroed; only nonzero tiles written. Full per-tile path otherwise.
// ---------------------------------------------------------------------------
__global__ __launch_bounds__(512, 2) void lsum_t_kernel(const uchar* __restrict__ xfrag8,
                                                        const float* __restrict__ dgall,
                                                        uchar* __restrict__ E8,
                                                        uchar* __restrict__ zmask,
                                                        float* __restrict__ rsbase,
                                                        float* __restrict__ rsadd) {
    __shared__ float red[8][64];
    __shared__ uchar chl[34];
    __shared__ int cnt_s;
    __shared__ uint zst[34];
    const int bid = blockIdx.x;
    const int b = (bid >> 1) & 3;
    const int n0 = ((((bid >> 3) << 1) | (bid & 1))) * 64;
    const int j = n0 >> 6;
    const int t = threadIdx.x, lane = t & 63, w = t >> 6;
    const int l15 = lane & 15, q = lane >> 4;
    const int g = w >> 2, wm = w & 3;

    if (t == 0) {
        int c = 0;
        chl[c++] = (uchar)j;                       // diag first
        for (int k = 0; k < 64; ++k) {
            if (k == j) continue;
            const bool own = (k > j) ? (((j + k) & 1) == 0) : (((j + k) & 1) == 1);
            if (own) chl[c++] = (uchar)k;
        }
        cnt_s = c;
    }
    if (t < 34) zst[t] = 0u;

    long2v af[4][4];                               // [ns][kk2]
    #pragma unroll
    for (int ns = 0; ns < 4; ++ns)
        #pragma unroll
        for (int kk2 = 0; kk2 < 4; ++kk2)
            af[ns][kk2] = *(const long2v*)(xfrag8 + xfi16(b, (n0 >> 4) + ns, kk2) + (size_t)lane * 16);

    float dv[4][4];
    #pragma unroll
    for (int ns = 0; ns < 4; ++ns)
        #pragma unroll
        for (int r = 0; r < 4; ++r)
            dv[ns][r] = dgall[b * N_ + n0 + 16 * ns + 4 * q + r];
    float dvmin = dv[0][0];
    #pragma unroll
    for (int ns = 0; ns < 4; ++ns)
        #pragma unroll
        for (int r = 0; r < 4; ++r)
            dvmin = fminf(dvmin, dv[ns][r]);

    __syncthreads();
    const int cnt = cnt_s;

    long2v bn[4];
    float dgm_cur;
    {
        const int mt0 = 4 * (int)chl[g] + wm;
        #pragma unroll
        for (int kk2 = 0; kk2 < 4; ++kk2)
            bn[kk2] = *(const long2v*)(xfrag8 + xfi16(b, mt0, kk2) + (size_t)lane * 16);
        dgm_cur = dgall[b * N_ + 16 * mt0 + l15];
    }
    const size_t ebl = (size_t)l15 * 8 + 4 * (q & 1);
    const int ngb = (n0 >> 3) + (q >> 1);

    float rs[4][4] = {};
    for (int it = 0; it < 17; ++it) {
        const int idx = 2 * it + g;
        const bool valid = idx < cnt;
        const int kc = chl[valid ? idx : 0];
        const int mt = 4 * kc + wm;
        int idxn = 2 * (it + 1) + g; if (idxn >= cnt) idxn = 0;
        const int mtn = 4 * (int)chl[idxn] + wm;

        f32x4 a0 = {0.f,0.f,0.f,0.f}, a1 = {0.f,0.f,0.f,0.f};
        f32x4 a2 = {0.f,0.f,0.f,0.f}, a3 = {0.f,0.f,0.f,0.f};
        __builtin_amdgcn_s_setprio(1);
        #pragma unroll
        for (int kk2 = 0; kk2 < 4; ++kk2) {
            const long2v bc = bn[kk2];
            a0 = mfma8(af[0][kk2].x, bc.x, a0);
            a1 = mfma8(af[1][kk2].x, bc.x, a1);
            a2 = mfma8(af[2][kk2].x, bc.x, a2);
            a3 = mfma8(af[3][kk2].x, bc.x, a3);
            a0 = mfma8(af[0][kk2].y, bc.y, a0);
            a1 = mfma8(af[1][kk2].y, bc.y, a1);
            a2 = mfma8(af[2][kk2].y, bc.y, a2);
            a3 = mfma8(af[3][kk2].y, bc.y, a3);
            bn[kk2] = *(const long2v*)(xfrag8 + xfi16(b, mtn, kk2) + (size_t)lane * 16);
        }
        __builtin_amdgcn_s_setprio(0);
        const float dgm = dgm_cur;
        dgm_cur = dgall[b * N_ + 16 * mtn + l15];

        // ---- wave-uniform whole-iteration gate (superset of both sides) ----
        const float gmax = fmaxf(
            fmaxf(fmaxf(fmaxf(a0[0], a0[1]), fmaxf(a0[2], a0[3])),
                  fmaxf(fmaxf(a1[0], a1[1]), fmaxf(a1[2], a1[3]))),
            fmaxf(fmaxf(fmaxf(a2[0], a2[1]), fmaxf(a2[2], a2[3])),
                  fmaxf(fmaxf(a3[0], a3[1]), fmaxf(a3[2], a3[3]))));
        const bool hot = valid && (__ballot(gmax - fminf(dvmin, dgm) > -30.0f) != 0ULL);
        if (!hot) continue;

        // ---- full per-tile path (diag chunk + rare borderline) ----
        float df[4][4];
#define EDF(AA, NS)                                                    \
        df[NS][0] = AA[0] - dv[NS][0]; df[NS][1] = AA[1] - dv[NS][1];  \
        df[NS][2] = AA[2] - dv[NS][2]; df[NS][3] = AA[3] - dv[NS][3];
        EDF(a0, 0) EDF(a1, 1) EDF(a2, 2) EDF(a3, 3)
#undef EDF
        const float mxA = fmaxf(
            fmaxf(fmaxf(fmaxf(df[0][0], df[0][1]), fmaxf(df[0][2], df[0][3])),
                  fmaxf(fmaxf(df[1][0], df[1][1]), fmaxf(df[1][2], df[1][3]))),
            fmaxf(fmaxf(fmaxf(df[2][0], df[2][1]), fmaxf(df[2][2], df[2][3])),
                  fmaxf(fmaxf(df[3][0], df[3][1]), fmaxf(df[3][2], df[3][3]))));
        const bool nzA = (__ballot(mxA > -30.0f) != 0ULL);
        if (nzA) {
            if (lane == 0) zmask[zmi(b, j, mt)] = 1;
            uint dpk[4];
#define EEXP(NS)                                                                       \
            {                                                                          \
                float e0 = __expf(df[NS][0]), e1 = __expf(df[NS][1]);                  \
                float e2 = __expf(df[NS][2]), e3 = __expf(df[NS][3]);                  \
                rs[NS][0] += e0; rs[NS][1] += e1; rs[NS][2] += e2; rs[NS][3] += e3;    \
                int d = __builtin_amdgcn_cvt_pk_fp8_f32(e0, e1, 0, 0);                 \
                d = __builtin_amdgcn_cvt_pk_fp8_f32(e2, e3, d, 1);                     \
                dpk[NS] = (uint)d;                                                     \
            }
            EEXP(0) EEXP(1) EEXP(2) EEXP(3)
#undef EEXP
            #pragma unroll
            for (int ns = 0; ns < 4; ++ns)
                *(uint*)(E8 + eti(b, mt, ngb + 2 * ns) + ebl) = dpk[ns];
        }
        // ---- B-side (twin rows k): skip-test + rare atomic remainder ----
        if (kc != j) {
            float dfB[4][4];
            #pragma unroll
            for (int ns = 0; ns < 4; ++ns) {
                dfB[ns][0] = (ns==0?a0[0]:ns==1?a1[0]:ns==2?a2[0]:a3[0]) - dgm;
                dfB[ns][1] = (ns==0?a0[1]:ns==1?a1[1]:ns==2?a2[1]:a3[1]) - dgm;
                dfB[ns][2] = (ns==0?a0[2]:ns==1?a1[2]:ns==2?a2[2]:a3[2]) - dgm;
                dfB[ns][3] = (ns==0?a0[3]:ns==1?a1[3]:ns==2?a2[3]:a3[3]) - dgm;
            }
            uint bits = 0;
            #pragma unroll
            for (int ns = 0; ns < 4; ++ns) {
                const float m2 = fmaxf(fmaxf(dfB[ns][0], dfB[ns][1]),
                                       fmaxf(dfB[ns][2], dfB[ns][3]));
                if (__ballot(m2 > -30.0f) != 0ULL) bits |= (1u << ns);
            }
            if (bits) {                                 // never on real data
                if (lane == 0) atomicOr(&zst[idx], bits);
                float cs = 0.f;
                #pragma unroll
                for (int ns = 0; ns < 4; ++ns)
                    #pragma unroll
                    for (int r = 0; r < 4; ++r)
                        cs += __expf(dfB[ns][r]);
                cs += __shfl_xor(cs, 16, 64);
                cs += __shfl_xor(cs, 32, 64);
                if (q == 0) atomicAdd(rsadd + b * N_ + 16 * mt + l15, cs);
            }
        }
    }
    #pragma unroll
    for (int off = 1; off < 16; off <<= 1)
        #pragma unroll
        for (int ns = 0; ns < 4; ++ns)
            #pragma unroll
            for (int r = 0; r < 4; ++r)
                rs[ns][r] += __shfl_xor(rs[ns][r], off, 64);
    if (l15 == 0) {
        #pragma unroll
        for (int ns = 0; ns < 4; ++ns)
            #pragma unroll
            for (int r = 0; r < 4; ++r)
                red[w][16 * ns + 4 * q + r] = rs[ns][r];
    }
    __syncthreads();
    if (t < 64) {
        float s = 0.f;
        #pragma unroll
        for (int ww = 0; ww < 8; ++ww) s += red[ww][t];
        rsbase[b * N_ + n0 + t] = s;
    }
    if (t >= 64 && t < 64 + 33 * 4) {
        const int ii = (t - 64) >> 2, ns = (t - 64) & 3;
        const int idx = ii + 1;
        if (idx < cnt) {
            const int kc = chl[idx];
            if ((zst[idx] >> ns) & 1u) zmask[zmi(b, kc, 4 * j + ns)] = 2;
        }
    }
}

// ---------------------------------------------------------------------------
// K3e v5: out[c,m] = sum_n (fd[c,n]*sinv[n]) * E[n,m] + fd[c,m].
// sinv = 1/(rsbase+rsadd); zmask byte guards (0/1/2); recompute path uses the
// packed xfrag16 layout (never taken on real data).
// ---------------------------------------------------------------------------
__global__ __launch_bounds__(512, 2) void out_e_kernel(const uchar* __restrict__ E8,
                                                       const uchar* __restrict__ zmask,
                                                       const float* __restrict__ rsbase,
                                                       const float* __restrict__ rsadd,
                                                       const float* __restrict__ dgall,
                                                       const uchar* __restrict__ xfrag8,
                                                       const float* __restrict__ fd32,
                                                       float* __restrict__ outp) {
    __shared__ ushort esc[8][16][66];   // per-wave recompute scratch
    const int bid = blockIdx.x;
    const int b = (bid >> 1) & 3;
    const int m0 = ((((bid >> 3) << 1) | (bid & 1))) * 64;
    const int t = threadIdx.x, lane = t & 63, w = t >> 6;
    const int l15 = lane & 15, q = lane >> 4;
    const size_t fb = (size_t)b * C_ * N_;
    const uchar* mrow = zmask + zmi(b, 0, m0 >> 4);

    f32x4 acc[2][4];
    #pragma unroll
    for (int ct = 0; ct < 2; ++ct)
        #pragma unroll
        for (int mt = 0; mt < 4; ++mt)
            acc[ct][mt] = (f32x4){0.f, 0.f, 0.f, 0.f};

    for (int gg = 0; gg < 8; ++gg) {
        uint mk[8];
        #pragma unroll
        for (int i = 0; i < 8; ++i)
            mk[i] = *(const uint*)(mrow + (size_t)(8 * gg + i) * 256);
        #pragma unroll
        for (int i = 0; i < 8; ++i) {
            const uint mki = mk[i];
            if (mki == 0) continue;
            const int nc = 8 * gg + i;
            const float* rb = rsbase + b * N_ + 64 * nc + 8 * q;
            const float* ra = rsadd + b * N_ + 64 * nc + 8 * q;
            float4 s0[2], s1[2];
            #pragma unroll
            for (int k2 = 0; k2 < 2; ++k2) {
                const float4 b0 = *(const float4*)(rb + 32 * k2);
                const float4 b1 = *(const float4*)(rb + 32 * k2 + 4);
                const float4 a0v = *(const float4*)(ra + 32 * k2);
                const float4 a1v = *(const float4*)(ra + 32 * k2 + 4);
                s0[k2].x = 1.0f / (b0.x + a0v.x); s0[k2].y = 1.0f / (b0.y + a0v.y);
                s0[k2].z = 1.0f / (b0.z + a0v.z); s0[k2].w = 1.0f / (b0.w + a0v.w);
                s1[k2].x = 1.0f / (b1.x + a1v.x); s1[k2].y = 1.0f / (b1.y + a1v.y);
                s1[k2].z = 1.0f / (b1.z + a1v.z); s1[k2].w = 1.0f / (b1.w + a1v.w);
            }
            short8 fn[2][2];
            #pragma unroll
            for (int ct = 0; ct < 2; ++ct) {
                const int c = 32 * w + 16 * ct + l15;
                const float* frow = fd32 + fb + (size_t)c * N_ + 64 * nc + 8 * q;
                #pragma unroll
                for (int k2 = 0; k2 < 2; ++k2) {
                    const float4 fa = *(const float4*)(frow + 32 * k2);
                    const float4 fb4 = *(const float4*)(frow + 32 * k2 + 4);
                    union { ushort us[8]; short8 v; } u;
                    u.us[0] = f2bf(fa.x * s0[k2].x); u.us[1] = f2bf(fa.y * s0[k2].y);
                    u.us[2] = f2bf(fa.z * s0[k2].z); u.us[3] = f2bf(fa.w * s0[k2].w);
                    u.us[4] = f2bf(fb4.x * s1[k2].x); u.us[5] = f2bf(fb4.y * s1[k2].y);
                    u.us[6] = f2bf(fb4.z * s1[k2].z); u.us[7] = f2bf(fb4.w * s1[k2].w);
                    fn[ct][k2] = u.v;
                }
            }
            if ((mki & ~0x01010101u) == 0u) {
                #pragma unroll
                for (int k2 = 0; k2 < 2; ++k2) {
                    #pragma unroll
                    for (int mt = 0; mt < 4; ++mt) {
                        if (((mki >> (8 * mt)) & 0xffu) != 1u) continue;
                        const long e8 = *(const long*)(E8 + eti(b, (m0 >> 4) + mt, 8 * nc + 4 * k2 + q) + (size_t)l15 * 8);
                        const uint lo = (uint)(unsigned long)e8;
                        const uint hi = (uint)((unsigned long)e8 >> 32);
                        const f32x2 f01 = __builtin_amdgcn_cvt_pk_f32_fp8((int)lo, false);
                        const f32x2 f23 = __builtin_amdgcn_cvt_pk_f32_fp8((int)lo, true);
                        const f32x2 f45 = __builtin_amdgcn_cvt_pk_f32_fp8((int)hi, false);
                        const f32x2 f67 = __builtin_amdgcn_cvt_pk_f32_fp8((int)hi, true);
                        union { uint u[4]; short8 v; } be;
                        asm("v_cvt_pk_bf16_f32 %0, %1, %2" : "=v"(be.u[0]) : "v"(f01.x), "v"(f01.y));
                        asm("v_cvt_pk_bf16_f32 %0, %1, %2" : "=v"(be.u[1]) : "v"(f23.x), "v"(f23.y));
                        asm("v_cvt_pk_bf16_f32 %0, %1, %2" : "=v"(be.u[2]) : "v"(f45.x), "v"(f45.y));
                        asm("v_cvt_pk_bf16_f32 %0, %1, %2" : "=v"(be.u[3]) : "v"(f67.x), "v"(f67.y));
                        acc[0][mt] = mfma16(fn[0][k2], be.v, acc[0][mt]);
                        acc[1][mt] = mfma16(fn[1][k2], be.v, acc[1][mt]);
                    }
                }
            } else {
                // ---- recompute path (degenerate inputs only) ----
                #pragma unroll
                for (int mt = 0; mt < 4; ++mt) {
                    long2v bmf[4];
                    #pragma unroll
                    for (int kk2 = 0; kk2 < 4; ++kk2)
                        bmf[kk2] = *(const long2v*)(xfrag8 + xfi16(b, (m0 >> 4) + mt, kk2) + (size_t)lane * 16);
                    #pragma unroll
                    for (int nt = 0; nt < 4; ++nt) {
                        long2v anf[4];
                        #pragma unroll
                        for (int kk2 = 0; kk2 < 4; ++kk2)
                            anf[kk2] = *(const long2v*)(xfrag8 + xfi16(b, 4 * nc + nt, kk2) + (size_t)lane * 16);
                        f32x4 sacc = {0.f, 0.f, 0.f, 0.f};
                        #pragma unroll
                        for (int kk2 = 0; kk2 < 4; ++kk2) {
                            sacc = mfma8(anf[kk2].x, bmf[kk2].x, sacc);
                            sacc = mfma8(anf[kk2].y, bmf[kk2].y, sacc);
                        }
                        #pragma unroll
                        for (int r = 0; r < 4; ++r) {
                            const float gv = dgall[b * N_ + 64 * nc + 16 * nt + 4 * q + r];
                            esc[w][l15][16 * nt + 4 * q + r] = f2bf(__expf(sacc[r] - gv));
                        }
                    }
                    #pragma unroll
                    for (int k2 = 0; k2 < 2; ++k2) {
                        const short8 be = *(const short8*)(&esc[w][l15][32 * k2 + 8 * q]);
                        acc[0][mt] = mfma16(fn[0][k2], be, acc[0][mt]);
                        acc[1][mt] = mfma16(fn[1][k2], be, acc[1][mt]);
                    }
                }
            }
        }
    }
    #pragma unroll
    for (int ct = 0; ct < 2; ++ct)
        #pragma unroll
        for (int mt = 0; mt < 4; ++mt)
            #pragma unroll
            for (int r = 0; r < 4; ++r) {
                const int c = 32 * w + 16 * ct + 4 * q + r;
                const int m = m0 + 16 * mt + l15;
                const size_t o = fb + (size_t)c * N_ + m;
                outp[o] = acc[ct][mt][r] + fd32[o];
            }
}

// ===========================================================================
// FALLBACK PATH (round-4 kernels, OLD xfi8 layout, self-consistent).
// ===========================================================================
__global__ __launch_bounds__(256) void prep_kernel(const float* __restrict__ fm,
                                                   const float* __restrict__ fd,
                                                   uchar* __restrict__ xfrag8,
                                                   ushort* __restrict__ ffrag) {
    __shared__ ushort xl[64][LDX];
    __shared__ ushort fl[64][LDX];
    const int b = blockIdx.z, c0 = blockIdx.y * 64, n0 = blockIdx.x * 64;
    const int t = threadIdx.x;
    const int n4 = (t & 15) * 4, cl = t >> 4;
    const size_t base = (size_t)b * C_ * N_;
    #pragma unroll
    for (int p = 0; p < 4; ++p) {
        const int cr = 16 * p + cl;
        const float4 m4 = *(const float4*)(fm + base + (size_t)(c0 + cr) * N_ + n0 + n4);
        const float4 d4 = *(const float4*)(fd + base + (size_t)(c0 + cr) * N_ + n0 + n4);
        ushort4 fo;
        fo.x = f2bf(d4.x); fo.y = f2bf(d4.y); fo.z = f2bf(d4.z); fo.w = f2bf(d4.w);
        *(ushort4*)(&fl[cr][n4]) = fo;
        ushort4 xo;
        xo.x = f2bf(m4.x + d4.x); xo.y = f2bf(m4.y + d4.y);
        xo.z = f2bf(m4.z + d4.z); xo.w = f2bf(m4.w + d4.w);
        *(ushort4*)(&xl[cr][n4]) = xo;
    }
    __syncthreads();
    const int l = t & 63, tl = t >> 6;
    {
        const int nl = 16 * tl + (l & 15);
        #pragma unroll
        for (int j = 0; j < 2; ++j) {
            const int kk = (c0 >> 5) + j;
            const int cb = 32 * j + 8 * (l >> 4);
            float f[8];
            #pragma unroll
            for (int i = 0; i < 8; ++i) f[i] = bf2f(xl[cb + i][nl]);
            int d0 = __builtin_amdgcn_cvt_pk_fp8_f32(f[0], f[1], 0, 0);
            d0 = __builtin_amdgcn_cvt_pk_fp8_f32(f[2], f[3], d0, 1);
            int d1 = __builtin_amdgcn_cvt_pk_fp8_f32(f[4], f[5], 0, 0);
            d1 = __builtin_amdgcn_cvt_pk_fp8_f32(f[6], f[7], d1, 1);
            uint* dst = (uint*)(xfrag8 + xfi8(b, (n0 >> 4) + tl, kk) + (size_t)l * 8);
            dst[0] = (uint)d0; dst[1] = (uint)d1;
        }
    }
    {
        const int row = 16 * tl + (l & 15);
        #pragma unroll
        for (int k2 = 0; k2 < 2; ++k2) {
            const int col = 32 * k2 + 8 * (l >> 4);
            const ushort4 a0 = *(const ushort4*)(&fl[row][col]);
            const ushort4 a1 = *(const ushort4*)(&fl[row][col + 4]);
            ushort* dst = ffrag + ffi(b, n0 >> 6, (c0 >> 4) + tl, k2) + l * 8;
            *(ushort4*)(dst) = a0; *(ushort4*)(dst + 4) = a1;
        }
    }
}

__global__ __launch_bounds__(512, 2) void lsum_g_kernel(const uchar* __restrict__ xfrag8,
                                                        float* __restrict__ lg) {
    __shared__ float red[8][64];
    __shared__ float dgl[64];
    const int bid = blockIdx.x;
    const int b = (bid >> 1) & 3;
    const int n0 = ((((bid >> 3) << 1) | (bid & 1))) * 64;
    const int t = threadIdx.x, lane = t & 63, w = t >> 6;
    const int l15 = lane & 15, q = lane >> 4;

    long af[4][8];
    #pragma unroll
    for (int ns = 0; ns < 4; ++ns)
        #pragma unroll
        for (int kk = 0; kk < 8; ++kk)
            af[ns][kk] = *(const long*)(xfrag8 + xfi8(b, (n0 >> 4) + ns, kk) + (size_t)lane * 8);

    float dv[4][4];
    #pragma unroll
    for (int ns = 0; ns < 4; ++ns) {
        f32x4 dacc = {0.f, 0.f, 0.f, 0.f};
        #pragma unroll
        for (int kk = 0; kk < 8; ++kk)
            dacc = mfma8(af[ns][kk], af[ns][kk], dacc);
        #pragma unroll
        for (int r = 0; r < 4; ++r)
            dv[ns][r] = __shfl(dacc[r], 20 * q + r, 64);
    }
    if (w == 0 && l15 == 0) {
        #pragma unroll
        for (int ns = 0; ns < 4; ++ns)
            #pragma unroll
            for (int r = 0; r < 4; ++r)
                dgl[16 * ns + 4 * q + r] = dv[ns][r];
    }

    long bn[8];
    #pragma unroll
    for (int kk = 0; kk < 8; ++kk)
        bn[kk] = *(const long*)(xfrag8 + xfi8(b, w, kk) + (size_t)lane * 8);

    float rs[4][4] = {};
    for (int mc = 0; mc < 32; ++mc) {
        const int mtn = (mc + 1 < 32) ? (mc + 1) * 8 + w : w;
        f32x4 a0 = {0.f,0.f,0.f,0.f}, a1 = {0.f,0.f,0.f,0.f};
        f32x4 a2 = {0.f,0.f,0.f,0.f}, a3 = {0.f,0.f,0.f,0.f};
        #pragma unroll
        for (int kk = 0; kk < 8; ++kk) {
            const long bc = bn[kk];
            a0 = mfma8(af[0][kk], bc, a0);
            a1 = mfma8(af[1][kk], bc, a1);
            a2 = mfma8(af[2][kk], bc, a2);
            a3 = mfma8(af[3][kk], bc, a3);
            bn[kk] = *(const long*)(xfrag8 + xfi8(b, mtn, kk) + (size_t)lane * 8);
        }
        #pragma unroll
        for (int r = 0; r < 4; ++r) {
            rs[0][r] += __expf(a0[r] - dv[0][r]);
            rs[1][r] += __expf(a1[r] - dv[1][r]);
            rs[2][r] += __expf(a2[r] - dv[2][r]);
            rs[3][r] += __expf(a3[r] - dv[3][r]);
        }
    }
    #pragma unroll
    for (int off = 1; off < 16; off <<= 1)
        #pragma unroll
        for (int ns = 0; ns < 4; ++ns)
            #pragma unroll
            for (int r = 0; r < 4; ++r)
                rs[ns][r] += __shfl_xor(rs[ns][r], off, 64);
    if (l15 == 0) {
        #pragma unroll
        for (int ns = 0; ns < 4; ++ns)
            #pragma unroll
            for (int r = 0; r < 4; ++r)
                red[w][16 * ns + 4 * q + r] = rs[ns][r];
    }
    __syncthreads();
    if (t < 64) {
        float s = 0.f;
        #pragma unroll
        for (int ww = 0; ww < 8; ++ww) s += red[ww][t];
        lg[b * N_ + n0 + t] = dgl[t] + __logf(s);
    }
}

__global__ __launch_bounds__(512, 2) void out_g_kernel(const uchar* __restrict__ xfrag8,
                                                       const ushort* __restrict__ ffrag,
                                                       const float* __restrict__ gg,
                                                       const float* __restrict__ fd32,
                                                       float* __restrict__ outp) {
    __shared__ ushort ET[2][64][LDE];
    const int bid = blockIdx.x;
    const int b = (bid >> 1) & 3;
    const int m0 = ((((bid >> 3) << 1) | (bid & 1))) * 64;
    const int t = threadIdx.x, lane = t & 63, w = t >> 6;
    const int l15 = lane & 15, q = lane >> 4;
    const int a = w & 3, h = w >> 2;
    const size_t fb = (size_t)b * C_ * N_;

    long bfr[2][8];
    #pragma unroll
    for (int jt = 0; jt < 2; ++jt)
        #pragma unroll
        for (int kk = 0; kk < 8; ++kk)
            bfr[jt][kk] = *(const long*)(xfrag8 + xfi8(b, (m0 >> 4) + 2 * h + jt, kk) + (size_t)lane * 8);

    f32x4 acc[2][4];
    #pragma unroll
    for (int ct = 0; ct < 2; ++ct)
        #pragma unroll
        for (int mt = 0; mt < 4; ++mt)
            acc[ct][mt] = (f32x4){0.f, 0.f, 0.f, 0.f};

    long an[8];
    #pragma unroll
    for (int kk = 0; kk < 8; ++kk)
        an[kk] = *(const long*)(xfrag8 + xfi8(b, a, kk) + (size_t)lane * 8);
    float gn[4];
    #pragma unroll
    for (int r = 0; r < 4; ++r) gn[r] = gg[b * N_ + 16 * a + 4 * q + r];

    int p = 0;
    for (int n0c = 0; n0c < N_; n0c += 64, p ^= 1) {
        const int nc = n0c >> 6;
        short8 fn[2][2];
        #pragma unroll
        for (int ct = 0; ct < 2; ++ct)
            #pragma unroll
            for (int k2 = 0; k2 < 2; ++k2)
                fn[ct][k2] = *(const short8*)(ffrag + ffi(b, nc, 2 * w + ct, k2) + lane * 8);
        float gv[4];
        #pragma unroll
        for (int r = 0; r < 4; ++r) gv[r] = gn[r];
        const int nx = (n0c + 64 < N_) ? n0c + 64 : 0;
        #pragma unroll
        for (int r = 0; r < 4; ++r) gn[r] = gg[b * N_ + nx + 16 * a + 4 * q + r];

        f32x4 s0 = {0.f, 0.f, 0.f, 0.f}, s1 = {0.f, 0.f, 0.f, 0.f};
        #pragma unroll
        for (int kk = 0; kk < 8; ++kk) {
            s0 = mfma8(an[kk], bfr[0][kk], s0);
            s1 = mfma8(an[kk], bfr[1][kk], s1);
            an[kk] = *(const long*)(xfrag8 + xfi8(b, (nx >> 4) + a, kk) + (size_t)lane * 8);
        }
        ushort4 e0, e1;
        e0.x = f2bf(__expf(s0[0] - gv[0])); e0.y = f2bf(__expf(s0[1] - gv[1]));
        e0.z = f2bf(__expf(s0[2] - gv[2])); e0.w = f2bf(__expf(s0[3] - gv[3]));
        e1.x = f2bf(__expf(s1[0] - gv[0])); e1.y = f2bf(__expf(s1[1] - gv[1]));
        e1.z = f2bf(__expf(s1[2] - gv[2])); e1.w = f2bf(__expf(s1[3] - gv[3]));
        *(ushort4*)(&ET[p][32 * h + l15][16 * a + 4 * q])      = e0;
        *(ushort4*)(&ET[p][32 * h + 16 + l15][16 * a + 4 * q]) = e1;

        asm volatile("s_waitcnt lgkmcnt(0)\n\ts_barrier" ::: "memory");

        #pragma unroll
        for (int k2 = 0; k2 < 2; ++k2) {
            #pragma unroll
            for (int mt = 0; mt < 4; ++mt) {
                const short8 be = *(const short8*)(&ET[p][16 * mt + l15][32 * k2 + 8 * q]);
                acc[0][mt] = mfma16(fn[0][k2], be, acc[0][mt]);
                acc[1][mt] = mfma16(fn[1][k2], be, acc[1][mt]);
            }
        }
    }
    #pragma unroll
    for (int ct = 0; ct < 2; ++ct)
        #pragma unroll
        for (int mt = 0; mt < 4; ++mt)
            #pragma unroll
            for (int r = 0; r < 4; ++r) {
                const int c = 32 * w + 16 * ct + 4 * q + r;
                const int m = m0 + 16 * mt + l15;
                const size_t o = fb + (size_t)c * N_ + m;
                outp[o] = acc[ct][mt][r] + fd32[o];
            }
}

// ---------------------------------------------------------------------------
extern "C" void kernel_launch(void* const* d_in, const int* in_sizes, int n_in,
                              void* d_out, int out_size, void* d_ws, size_t ws_size,
                              hipStream_t stream) {
    const float* fm = (const float*)d_in[0];
    const float* fd = (const float*)d_in[1];
    float* outp = (float*)d_out;

    const size_t xb_elts = (size_t)B_ * N_ * C_;                 // 4.19M
    const size_t e_bytes = (size_t)B_ * N_ * N_;                 // 67.1 MB
    const size_t z_bytes = (size_t)B_ * 64 * 256;                // 64 KB
    const size_t f_bytes = (size_t)B_ * N_ * 4;                  // 64 KB each
    const size_t need_e  = xb_elts + e_bytes + z_bytes + 3 * f_bytes;
    const size_t need_g  = xb_elts * 3 + f_bytes;

    uchar* xfrag8 = (uchar*)d_ws;

    if (ws_size >= need_e) {
        uchar* E8     = xfrag8 + xb_elts;
        uchar* zmask  = E8 + e_bytes;
        float* rsbase = (float*)(zmask + z_bytes);
        float* rsadd  = rsbase + (size_t)B_ * N_;
        float* dgall  = rsadd + (size_t)B_ * N_;
        prep_x_kernel<<<dim3(N_ / 64, C_ / 64, B_), 256, 0, stream>>>(fm, fd, xfrag8);
        dg_kernel<<<dim3(256), 256, 0, stream>>>(xfrag8, dgall, rsadd, zmask);
        lsum_t_kernel<<<dim3(256), 512, 0, stream>>>(xfrag8, dgall, E8, zmask, rsbase, rsadd);
        out_e_kernel<<<dim3(256), 512, 0, stream>>>(E8, zmask, rsbase, rsadd, dgall, xfrag8, fd, outp);
    } else if (ws_size >= need_g) {
        ushort* ffrag = (ushort*)(xfrag8 + xb_elts);
        float*  lg    = (float*)(xfrag8 + xb_elts * 3);
        prep_kernel<<<dim3(N_ / 64, C_ / 64, B_), 256, 0, stream>>>(fm, fd, xfrag8, ffrag);
        lsum_g_kernel<<<dim3(256), 512, 0, stream>>>(xfrag8, lg);
        out_g_kernel<<<dim3(256), 512, 0, stream>>>(xfrag8, ffrag, lg, fd, outp);
    }
}

// Round 13
// 103.197 us; speedup vs baseline: 1.8911x; 1.0574x over previous
//
#include <hip/hip_runtime.h>
#include <math.h>

#define B_ 4
#define C_ 256
#define N_ 4096   // H*W
#define LDE 68    // ET row stride (ushorts) — verified, 0 conflicts
#define LDX 72    // prep LDS tile stride (ushorts)

typedef __attribute__((ext_vector_type(8))) short short8;
typedef __attribute__((ext_vector_type(4))) float f32x4;
typedef __attribute__((ext_vector_type(2))) float f32x2;
typedef __attribute__((ext_vector_type(2))) long long2v;

__device__ inline ushort f2bf(float f) {
    uint u = __float_as_uint(f);
    return (ushort)((u + 0x7fffu + ((u >> 16) & 1u)) >> 16);   // RNE
}
__device__ inline float bf2f(ushort h) { return __uint_as_float(((uint)h) << 16); }

__device__ inline f32x4 mfma16(short8 a, short8 b, f32x4 c) {
    return __builtin_amdgcn_mfma_f32_16x16x32_bf16(a, b, c, 0, 0, 0);
}
__device__ inline f32x4 mfma8(long a, long b, f32x4 c) {
    return __builtin_amdgcn_mfma_f32_16x16x32_fp8_fp8(a, b, c, 0, 0, 0);
}

// E-path layouts:
//   xfrag8[b][nt=0..255][kk2=0..3][lane][16 fp8]  (packed dwordx4 loads)
//   E8    [b][mt=0..255][ng=0..511][ml=0..15][8]  (E^T fp8)
//   zmask [b][nc=0..63][mt=0..255]  0=zero, 1=E8 valid, 2=recompute
//   rsbase/rsadd/dgall [b][n]
__device__ inline size_t xfi16(int b, int nt, int kk2) {   // BYTE offset, no lane
    return (((size_t)(b * 256 + nt)) * 4 + kk2) * 1024;
}
__device__ inline size_t xfi8(int b, int nt, int kk) {     // FALLBACK layout
    return (((size_t)(b * 256 + nt)) * 8 + kk) * 512;
}
__device__ inline size_t ffi(int b, int nc, int ct, int k2) {   // fallback only
    return ((((size_t)(b * 64 + nc)) * 16 + ct) * 2 + k2) * 512;
}
__device__ inline size_t eti(int b, int mt, int ng) {
    return (((size_t)(b * 256 + mt)) * 512 + (size_t)ng) * 128;
}
__device__ inline size_t zmi(int b, int nc, int mt) {
    return ((size_t)(b * 64 + nc)) * 256 + mt;
}

// ---------------------------------------------------------------------------
// P0x: build xfrag8 (packed 16B/lane layout). One dwordx4 store per lane.
// ---------------------------------------------------------------------------
__global__ __launch_bounds__(256) void prep_x_kernel(const float* __restrict__ fm,
                                                     const float* __restrict__ fd,
                                                     uchar* __restrict__ xfrag8) {
    __shared__ ushort xl[64][LDX];
    const int b = blockIdx.z, c0 = blockIdx.y * 64, n0 = blockIdx.x * 64;
    const int t = threadIdx.x;
    const int n4 = (t & 15) * 4, cl = t >> 4;
    const size_t base = (size_t)b * C_ * N_;
    #pragma unroll
    for (int p = 0; p < 4; ++p) {
        const int cr = 16 * p + cl;
        const float4 m4 = *(const float4*)(fm + base + (size_t)(c0 + cr) * N_ + n0 + n4);
        const float4 d4 = *(const float4*)(fd + base + (size_t)(c0 + cr) * N_ + n0 + n4);
        ushort4 xo;
        xo.x = f2bf(m4.x + d4.x); xo.y = f2bf(m4.y + d4.y);
        xo.z = f2bf(m4.z + d4.z); xo.w = f2bf(m4.w + d4.w);
        *(ushort4*)(&xl[cr][n4]) = xo;
    }
    __syncthreads();
    const int l = t & 63, tl = t >> 6;
    const int nl = 16 * tl + (l & 15);
    uint dd[4];
    #pragma unroll
    for (int j = 0; j < 2; ++j) {
        const int cb = 32 * j + 8 * (l >> 4);
        float f[8];
        #pragma unroll
        for (int i = 0; i < 8; ++i) f[i] = bf2f(xl[cb + i][nl]);
        int d0 = __builtin_amdgcn_cvt_pk_fp8_f32(f[0], f[1], 0, 0);
        d0 = __builtin_amdgcn_cvt_pk_fp8_f32(f[2], f[3], d0, 1);
        int d1 = __builtin_amdgcn_cvt_pk_fp8_f32(f[4], f[5], 0, 0);
        d1 = __builtin_amdgcn_cvt_pk_fp8_f32(f[6], f[7], d1, 1);
        dd[2 * j] = (uint)d0; dd[2 * j + 1] = (uint)d1;
    }
    uint* dst = (uint*)(xfrag8 + xfi16(b, (n0 >> 4) + tl, c0 >> 6) + (size_t)l * 16);
    dst[0] = dd[0]; dst[1] = dd[1]; dst[2] = dd[2]; dst[3] = dd[3];
}

// ---------------------------------------------------------------------------
// DG: dgall[n] = S[n,n] via same-order mfma8 chain. Zeroes rsadd + zmask.
// ---------------------------------------------------------------------------
__global__ __launch_bounds__(256) void dg_kernel(const uchar* __restrict__ xfrag8,
                                                 float* __restrict__ dgall,
                                                 float* __restrict__ rsadd,
                                                 uchar* __restrict__ zmask) {
    const int t = threadIdx.x, lane = t & 63, w = t >> 6;
    const int tid = blockIdx.x * 4 + w;
    const int b = tid >> 8, nt = tid & 255;
    const int l15 = lane & 15, q = lane >> 4;
    long2v af[4];
    #pragma unroll
    for (int kk2 = 0; kk2 < 4; ++kk2)
        af[kk2] = *(const long2v*)(xfrag8 + xfi16(b, nt, kk2) + (size_t)lane * 16);
    f32x4 dacc = {0.f, 0.f, 0.f, 0.f};
    #pragma unroll
    for (int kk2 = 0; kk2 < 4; ++kk2) {
        dacc = mfma8(af[kk2].x, af[kk2].x, dacc);
        dacc = mfma8(af[kk2].y, af[kk2].y, dacc);
    }
    float dvv[4];
    #pragma unroll
    for (int r = 0; r < 4; ++r)
        dvv[r] = __shfl(dacc[r], 20 * q + r, 64);
    if (l15 == 0) {
        #pragma unroll
        for (int r = 0; r < 4; ++r)
            dgall[b * N_ + 16 * nt + 4 * q + r] = dvv[r];
    }
    const int zi = blockIdx.x * 256 + t;
    if (zi < B_ * N_) rsadd[zi] = 0.f;
    zmask[zi] = 0;
}

// ---------------------------------------------------------------------------
// FUSED: triangular Gram + local softmax + PV for the block's own m-chunk.
// Block (b,j): sweep owned pairs (gated, packed loads, as r11). Diag-pair E
// additionally staged bf16 -> ET LDS. After rowsum: sinv_l = 1/rsbase (exact
// on real data; degenerate inputs corrected by out_fix). PV phase computes
// out[c, m in chunk j] = sum_{n in j} (fd*sinv)[c,n]*E[n,m] + fd[c,m].
// E8/zmask/rsbase/rsadd still written for out_fix's general path.
// ---------------------------------------------------------------------------
__global__ __launch_bounds__(512, 2) void fused_kernel(const uchar* __restrict__ xfrag8,
                                                       const float* __restrict__ dgall,
                                                       uchar* __restrict__ E8,
                                                       uchar* __restrict__ zmask,
                                                       float* __restrict__ rsbase,
                                                       float* __restrict__ rsadd,
                                                       const float* __restrict__ fd32,
                                                       float* __restrict__ outp) {
    __shared__ float red[8][64];
    __shared__ float sv_l[64];
    __shared__ ushort ET[64][LDE];
    __shared__ uchar chl[34];
    __shared__ int cnt_s;
    __shared__ uint zst[34];
    const int bid = blockIdx.x;
    const int b = (bid >> 1) & 3;
    const int n0 = ((((bid >> 3) << 1) | (bid & 1))) * 64;
    const int j = n0 >> 6;
    const int t = threadIdx.x, lane = t & 63, w = t >> 6;
    const int l15 = lane & 15, q = lane >> 4;
    const int g = w >> 2, wm = w & 3;
    const size_t fb = (size_t)b * C_ * N_;

    if (t == 0) {
        int c = 0;
        chl[c++] = (uchar)j;                       // diag first
        for (int k = 0; k < 64; ++k) {
            if (k == j) continue;
            const bool own = (k > j) ? (((j + k) & 1) == 0) : (((j + k) & 1) == 1);
            if (own) chl[c++] = (uchar)k;
        }
        cnt_s = c;
    }
    if (t < 34) zst[t] = 0u;

    long2v af[4][4];
    #pragma unroll
    for (int ns = 0; ns < 4; ++ns)
        #pragma unroll
        for (int kk2 = 0; kk2 < 4; ++kk2)
            af[ns][kk2] = *(const long2v*)(xfrag8 + xfi16(b, (n0 >> 4) + ns, kk2) + (size_t)lane * 16);

    float dv[4][4];
    #pragma unroll
    for (int ns = 0; ns < 4; ++ns)
        #pragma unroll
        for (int r = 0; r < 4; ++r)
            dv[ns][r] = dgall[b * N_ + n0 + 16 * ns + 4 * q + r];
    float dvmin = dv[0][0];
    #pragma unroll
    for (int ns = 0; ns < 4; ++ns)
        #pragma unroll
        for (int r = 0; r < 4; ++r)
            dvmin = fminf(dvmin, dv[ns][r]);

    __syncthreads();
    const int cnt = cnt_s;

    long2v bn[4];
    float dgm_cur;
    {
        const int mt0 = 4 * (int)chl[g] + wm;
        #pragma unroll
        for (int kk2 = 0; kk2 < 4; ++kk2)
            bn[kk2] = *(const long2v*)(xfrag8 + xfi16(b, mt0, kk2) + (size_t)lane * 16);
        dgm_cur = dgall[b * N_ + 16 * mt0 + l15];
    }
    const size_t ebl = (size_t)l15 * 8 + 4 * (q & 1);
    const int ngb = (n0 >> 3) + (q >> 1);

    float rs[4][4] = {};
    for (int it = 0; it < 17; ++it) {
        const int idx = 2 * it + g;
        const bool valid = idx < cnt;
        const int kc = chl[valid ? idx : 0];
        const int mt = 4 * kc + wm;
        int idxn = 2 * (it + 1) + g; if (idxn >= cnt) idxn = 0;
        const int mtn = 4 * (int)chl[idxn] + wm;

        f32x4 a0 = {0.f,0.f,0.f,0.f}, a1 = {0.f,0.f,0.f,0.f};
        f32x4 a2 = {0.f,0.f,0.f,0.f}, a3 = {0.f,0.f,0.f,0.f};
        __builtin_amdgcn_s_setprio(1);
        #pragma unroll
        for (int kk2 = 0; kk2 < 4; ++kk2) {
            const long2v bc = bn[kk2];
            a0 = mfma8(af[0][kk2].x, bc.x, a0);
            a1 = mfma8(af[1][kk2].x, bc.x, a1);
            a2 = mfma8(af[2][kk2].x, bc.x, a2);
            a3 = mfma8(af[3][kk2].x, bc.x, a3);
            a0 = mfma8(af[0][kk2].y, bc.y, a0);
            a1 = mfma8(af[1][kk2].y, bc.y, a1);
            a2 = mfma8(af[2][kk2].y, bc.y, a2);
            a3 = mfma8(af[3][kk2].y, bc.y, a3);
            bn[kk2] = *(const long2v*)(xfrag8 + xfi16(b, mtn, kk2) + (size_t)lane * 16);
        }
        __builtin_amdgcn_s_setprio(0);
        const float dgm = dgm_cur;
        dgm_cur = dgall[b * N_ + 16 * mtn + l15];

        // wave-uniform whole-iteration gate (superset of both sides)
        const float gmax = fmaxf(
            fmaxf(fmaxf(fmaxf(a0[0], a0[1]), fmaxf(a0[2], a0[3])),
                  fmaxf(fmaxf(a1[0], a1[1]), fmaxf(a1[2], a1[3]))),
            fmaxf(fmaxf(fmaxf(a2[0], a2[1]), fmaxf(a2[2], a2[3])),
                  fmaxf(fmaxf(a3[0], a3[1]), fmaxf(a3[2], a3[3]))));
        const bool hot = valid && (__ballot(gmax - fminf(dvmin, dgm) > -30.0f) != 0ULL);
        if (!hot) continue;

        float df[4][4];
#define EDF(AA, NS)                                                    \
        df[NS][0] = AA[0] - dv[NS][0]; df[NS][1] = AA[1] - dv[NS][1];  \
        df[NS][2] = AA[2] - dv[NS][2]; df[NS][3] = AA[3] - dv[NS][3];
        EDF(a0, 0) EDF(a1, 1) EDF(a2, 2) EDF(a3, 3)
#undef EDF
        const float mxA = fmaxf(
            fmaxf(fmaxf(fmaxf(df[0][0], df[0][1]), fmaxf(df[0][2], df[0][3])),
                  fmaxf(fmaxf(df[1][0], df[1][1]), fmaxf(df[1][2], df[1][3]))),
            fmaxf(fmaxf(fmaxf(df[2][0], df[2][1]), fmaxf(df[2][2], df[2][3])),
                  fmaxf(fmaxf(df[3][0], df[3][1]), fmaxf(df[3][2], df[3][3]))));
        const bool nzA = (__ballot(mxA > -30.0f) != 0ULL);
        if (nzA) {
            if (lane == 0) zmask[zmi(b, j, mt)] = 1;
            const bool dia = (kc == j);            // wave-uniform; only idx==0
            uint dpk[4];
#define EEXP(NS)                                                                       \
            {                                                                          \
                float e0 = __expf(df[NS][0]), e1 = __expf(df[NS][1]);                  \
                float e2 = __expf(df[NS][2]), e3 = __expf(df[NS][3]);                  \
                rs[NS][0] += e0; rs[NS][1] += e1; rs[NS][2] += e2; rs[NS][3] += e3;    \
                int d = __builtin_amdgcn_cvt_pk_fp8_f32(e0, e1, 0, 0);                 \
                d = __builtin_amdgcn_cvt_pk_fp8_f32(e2, e3, d, 1);                     \
                dpk[NS] = (uint)d;                                                     \
                if (dia) {                                                             \
                    ushort4 ev;                                                        \
                    ev.x = f2bf(e0); ev.y = f2bf(e1);                                  \
                    ev.z = f2bf(e2); ev.w = f2bf(e3);                                  \
                    *(ushort4*)(&ET[16 * wm + l15][16 * NS + 4 * q]) = ev;             \
                }                                                                      \
            }
            EEXP(0) EEXP(1) EEXP(2) EEXP(3)
#undef EEXP
            #pragma unroll
            for (int ns = 0; ns < 4; ++ns)
                *(uint*)(E8 + eti(b, mt, ngb + 2 * ns) + ebl) = dpk[ns];
        }
        // B-side (twin rows k): skip-test + rare atomic remainder
        if (kc != j) {
            float dfB[4][4];
            #pragma unroll
            for (int ns = 0; ns < 4; ++ns) {
                dfB[ns][0] = (ns==0?a0[0]:ns==1?a1[0]:ns==2?a2[0]:a3[0]) - dgm;
                dfB[ns][1] = (ns==0?a0[1]:ns==1?a1[1]:ns==2?a2[1]:a3[1]) - dgm;
                dfB[ns][2] = (ns==0?a0[2]:ns==1?a1[2]:ns==2?a2[2]:a3[2]) - dgm;
                dfB[ns][3] = (ns==0?a0[3]:ns==1?a1[3]:ns==2?a2[3]:a3[3]) - dgm;
            }
            uint bits = 0;
            #pragma unroll
            for (int ns = 0; ns < 4; ++ns) {
                const float m2 = fmaxf(fmaxf(dfB[ns][0], dfB[ns][1]),
                                       fmaxf(dfB[ns][2], dfB[ns][3]));
                if (__ballot(m2 > -30.0f) != 0ULL) bits |= (1u << ns);
            }
            if (bits) {                                 // never on real data
                if (lane == 0) atomicOr(&zst[idx], bits);
                float cs = 0.f;
                #pragma unroll
                for (int ns = 0; ns < 4; ++ns)
                    #pragma unroll
                    for (int r = 0; r < 4; ++r)
                        cs += __expf(dfB[ns][r]);
                cs += __shfl_xor(cs, 16, 64);
                cs += __shfl_xor(cs, 32, 64);
                if (q == 0) atomicAdd(rsadd + b * N_ + 16 * mt + l15, cs);
            }
        }
    }
    #pragma unroll
    for (int off = 1; off < 16; off <<= 1)
        #pragma unroll
        for (int ns = 0; ns < 4; ++ns)
            #pragma unroll
            for (int r = 0; r < 4; ++r)
                rs[ns][r] += __shfl_xor(rs[ns][r], off, 64);
    if (l15 == 0) {
        #pragma unroll
        for (int ns = 0; ns < 4; ++ns)
            #pragma unroll
            for (int r = 0; r < 4; ++r)
                red[w][16 * ns + 4 * q + r] = rs[ns][r];
    }
    __syncthreads();
    if (t < 64) {
        float s = 0.f;
        #pragma unroll
        for (int ww = 0; ww < 8; ++ww) s += red[ww][t];
        rsbase[b * N_ + n0 + t] = s;
        sv_l[t] = 1.0f / s;        // exact on real data (rsadd == +0.0f)
    }
    if (t >= 64 && t < 64 + 33 * 4) {
        const int ii = (t - 64) >> 2, ns = (t - 64) & 3;
        const int idx = ii + 1;
        if (idx < cnt) {
            const int kc = chl[idx];
            if ((zst[idx] >> ns) & 1u) zmask[zmi(b, kc, 4 * j + ns)] = 2;
        }
    }
    __syncthreads();   // ET + sv_l ready

    // ---- fused PV: out[c, m in chunk j] += diag-chunk contribution ----
    {
        f32x4 pacc[2][4];
        #pragma unroll
        for (int ct = 0; ct < 2; ++ct)
            #pragma unroll
            for (int mtl = 0; mtl < 4; ++mtl)
                pacc[ct][mtl] = (f32x4){0.f, 0.f, 0.f, 0.f};
        short8 pfn[2][2];
        #pragma unroll
        for (int ct = 0; ct < 2; ++ct) {
            const int c = 32 * w + 16 * ct + l15;
            const float* frow = fd32 + fb + (size_t)c * N_ + 64 * j + 8 * q;
            #pragma unroll
            for (int k2 = 0; k2 < 2; ++k2) {
                const float4 fa = *(const float4*)(frow + 32 * k2);
                const float4 fb4 = *(const float4*)(frow + 32 * k2 + 4);
                const int nb = 32 * k2 + 8 * q;
                union { ushort us[8]; short8 v; } u;
                u.us[0] = f2bf(fa.x * sv_l[nb + 0]); u.us[1] = f2bf(fa.y * sv_l[nb + 1]);
                u.us[2] = f2bf(fa.z * sv_l[nb + 2]); u.us[3] = f2bf(fa.w * sv_l[nb + 3]);
                u.us[4] = f2bf(fb4.x * sv_l[nb + 4]); u.us[5] = f2bf(fb4.y * sv_l[nb + 5]);
                u.us[6] = f2bf(fb4.z * sv_l[nb + 6]); u.us[7] = f2bf(fb4.w * sv_l[nb + 7]);
                pfn[ct][k2] = u.v;
            }
        }
        #pragma unroll
        for (int k2 = 0; k2 < 2; ++k2) {
            #pragma unroll
            for (int mtl = 0; mtl < 4; ++mtl) {
                const short8 be = *(const short8*)(&ET[16 * mtl + l15][32 * k2 + 8 * q]);
                pacc[0][mtl] = mfma16(pfn[0][k2], be, pacc[0][mtl]);
                pacc[1][mtl] = mfma16(pfn[1][k2], be, pacc[1][mtl]);
            }
        }
        #pragma unroll
        for (int ct = 0; ct < 2; ++ct)
            #pragma unroll
            for (int mtl = 0; mtl < 4; ++mtl)
                #pragma unroll
                for (int r = 0; r < 4; ++r) {
                    const int c = 32 * w + 16 * ct + 4 * q + r;
                    const int m = 64 * j + 16 * mtl + l15;
                    const size_t o = fb + (size_t)c * N_ + m;
                    outp[o] = pacc[ct][mtl][r] + fd32[o];
                }
    }
}

// ---------------------------------------------------------------------------
// OUT_FIX: scan zmask; on real data every block early-exits (fused PV result
// stands). If any non-diagonal nonzero tile or zmask=2 exists (degenerate
// inputs), redo this m-chunk with the full general path (complete sinv =
// 1/(rsbase+rsadd), E8 tiles, recompute path) — overwrites fused output.
// ---------------------------------------------------------------------------
__global__ __launch_bounds__(512, 2) void out_fix_kernel(const uchar* __restrict__ E8,
                                                         const uchar* __restrict__ zmask,
                                                         const float* __restrict__ rsbase,
                                                         const float* __restrict__ rsadd,
                                                         const float* __restrict__ dgall,
                                                         const uchar* __restrict__ xfrag8,
                                                         const float* __restrict__ fd32,
                                                         float* __restrict__ outp) {
    __shared__ ushort esc[8][16][66];
    __shared__ int needfix;
    const int bid = blockIdx.x;
    const int b = (bid >> 1) & 3;
    const int m0 = ((((bid >> 3) << 1) | (bid & 1))) * 64;
    const int M = m0 >> 6;
    const int t = threadIdx.x, lane = t & 63, w = t >> 6;
    const int l15 = lane & 15, q = lane >> 4;
    const size_t fb = (size_t)b * C_ * N_;
    const uchar* mrow = zmask + zmi(b, 0, m0 >> 4);

    if (t == 0) needfix = 0;
    __syncthreads();
    if (t < 64) {
        const uint ck = *(const uint*)(zmask + zmi(b, t, m0 >> 4));   // (nc=t, mt in M)
        bool bad = (t != M) && (ck != 0u);
        const uint rk = *(const uint*)(zmask + zmi(b, M, 4 * t));     // row M, all mt
        bad |= ((rk & 0x02020202u) != 0u);
        if (bad) needfix = 1;
    }
    __syncthreads();
    if (needfix == 0) return;

    // ---- general path (degenerate inputs only) ----
    f32x4 acc[2][4];
    #pragma unroll
    for (int ct = 0; ct < 2; ++ct)
        #pragma unroll
        for (int mt = 0; mt < 4; ++mt)
            acc[ct][mt] = (f32x4){0.f, 0.f, 0.f, 0.f};

    for (int gg = 0; gg < 8; ++gg) {
        uint mk[8];
        #pragma unroll
        for (int i = 0; i < 8; ++i)
            mk[i] = *(const uint*)(mrow + (size_t)(8 * gg + i) * 256);
        #pragma unroll
        for (int i = 0; i < 8; ++i) {
            const uint mki = mk[i];
            if (mki == 0) continue;
            const int nc = 8 * gg + i;
            const float* rb = rsbase + b * N_ + 64 * nc + 8 * q;
            const float* ra = rsadd + b * N_ + 64 * nc + 8 * q;
            float4 s0[2], s1[2];
            #pragma unroll
            for (int k2 = 0; k2 < 2; ++k2) {
                const float4 b0 = *(const float4*)(rb + 32 * k2);
                const float4 b1 = *(const float4*)(rb + 32 * k2 + 4);
                const float4 a0v = *(const float4*)(ra + 32 * k2);
                const float4 a1v = *(const float4*)(ra + 32 * k2 + 4);
                s0[k2].x = 1.0f / (b0.x + a0v.x); s0[k2].y = 1.0f / (b0.y + a0v.y);
                s0[k2].z = 1.0f / (b0.z + a0v.z); s0[k2].w = 1.0f / (b0.w + a0v.w);
                s1[k2].x = 1.0f / (b1.x + a1v.x); s1[k2].y = 1.0f / (b1.y + a1v.y);
                s1[k2].z = 1.0f / (b1.z + a1v.z); s1[k2].w = 1.0f / (b1.w + a1v.w);
            }
            short8 fn[2][2];
            #pragma unroll
            for (int ct = 0; ct < 2; ++ct) {
                const int c = 32 * w + 16 * ct + l15;
                const float* frow = fd32 + fb + (size_t)c * N_ + 64 * nc + 8 * q;
                #pragma unroll
                for (int k2 = 0; k2 < 2; ++k2) {
                    const float4 fa = *(const float4*)(frow + 32 * k2);
                    const float4 fb4 = *(const float4*)(frow + 32 * k2 + 4);
                    union { ushort us[8]; short8 v; } u;
                    u.us[0] = f2bf(fa.x * s0[k2].x); u.us[1] = f2bf(fa.y * s0[k2].y);
                    u.us[2] = f2bf(fa.z * s0[k2].z); u.us[3] = f2bf(fa.w * s0[k2].w);
                    u.us[4] = f2bf(fb4.x * s1[k2].x); u.us[5] = f2bf(fb4.y * s1[k2].y);
                    u.us[6] = f2bf(fb4.z * s1[k2].z); u.us[7] = f2bf(fb4.w * s1[k2].w);
                    fn[ct][k2] = u.v;
                }
            }
            if ((mki & ~0x01010101u) == 0u) {
                #pragma unroll
                for (int k2 = 0; k2 < 2; ++k2) {
                    #pragma unroll
                    for (int mt = 0; mt < 4; ++mt) {
                        if (((mki >> (8 * mt)) & 0xffu) != 1u) continue;
                        const long e8 = *(const long*)(E8 + eti(b, (m0 >> 4) + mt, 8 * nc + 4 * k2 + q) + (size_t)l15 * 8);
                        const uint lo = (uint)(unsigned long)e8;
                        const uint hi = (uint)((unsigned long)e8 >> 32);
                        const f32x2 f01 = __builtin_amdgcn_cvt_pk_f32_fp8((int)lo, false);
                        const f32x2 f23 = __builtin_amdgcn_cvt_pk_f32_fp8((int)lo, true);
                        const f32x2 f45 = __builtin_amdgcn_cvt_pk_f32_fp8((int)hi, false);
                        const f32x2 f67 = __builtin_amdgcn_cvt_pk_f32_fp8((int)hi, true);
                        union { uint u[4]; short8 v; } be;
                        asm("v_cvt_pk_bf16_f32 %0, %1, %2" : "=v"(be.u[0]) : "v"(f01.x), "v"(f01.y));
                        asm("v_cvt_pk_bf16_f32 %0, %1, %2" : "=v"(be.u[1]) : "v"(f23.x), "v"(f23.y));
                        asm("v_cvt_pk_bf16_f32 %0, %1, %2" : "=v"(be.u[2]) : "v"(f45.x), "v"(f45.y));
                        asm("v_cvt_pk_bf16_f32 %0, %1, %2" : "=v"(be.u[3]) : "v"(f67.x), "v"(f67.y));
                        acc[0][mt] = mfma16(fn[0][k2], be.v, acc[0][mt]);
                        acc[1][mt] = mfma16(fn[1][k2], be.v, acc[1][mt]);
                    }
                }
            } else {
                #pragma unroll
                for (int mt = 0; mt < 4; ++mt) {
                    long2v bmf[4];
                    #pragma unroll
                    for (int kk2 = 0; kk2 < 4; ++kk2)
                        bmf[kk2] = *(const long2v*)(xfrag8 + xfi16(b, (m0 >> 4) + mt, kk2) + (size_t)lane * 16);
                    #pragma unroll
                    for (int nt = 0; nt < 4; ++nt) {
                        long2v anf[4];
                        #pragma unroll
                        for (int kk2 = 0; kk2 < 4; ++kk2)
                            anf[kk2] = *(const long2v*)(xfrag8 + xfi16(b, 4 * nc + nt, kk2) + (size_t)lane * 16);
                        f32x4 sacc = {0.f, 0.f, 0.f, 0.f};
                        #pragma unroll
                        for (int kk2 = 0; kk2 < 4; ++kk2) {
                            sacc = mfma8(anf[kk2].x, bmf[kk2].x, sacc);
                            sacc = mfma8(anf[kk2].y, bmf[kk2].y, sacc);
                        }
                        #pragma unroll
                        for (int r = 0; r < 4; ++r) {
                            const float gv = dgall[b * N_ + 64 * nc + 16 * nt + 4 * q + r];
                            esc[w][l15][16 * nt + 4 * q + r] = f2bf(__expf(sacc[r] - gv));
                        }
                    }
                    #pragma unroll
                    for (int k2 = 0; k2 < 2; ++k2) {
                        const short8 be = *(const short8*)(&esc[w][l15][32 * k2 + 8 * q]);
                        acc[0][mt] = mfma16(fn[0][k2], be, acc[0][mt]);
                        acc[1][mt] = mfma16(fn[1][k2], be, acc[1][mt]);
                    }
                }
            }
        }
    }
    #pragma unroll
    for (int ct = 0; ct < 2; ++ct)
        #pragma unroll
        for (int mt = 0; mt < 4; ++mt)
            #pragma unroll
            for (int r = 0; r < 4; ++r) {
                const int c = 32 * w + 16 * ct + 4 * q + r;
                const int m = m0 + 16 * mt + l15;
                const size_t o = fb + (size_t)c * N_ + m;
                outp[o] = acc[ct][mt][r] + fd32[o];
            }
}

// ===========================================================================
// FALLBACK PATH (round-4 kernels, OLD xfi8 layout, self-consistent).
// ===========================================================================
__global__ __launch_bounds__(256) void prep_kernel(const float* __restrict__ fm,
                                                   const float* __restrict__ fd,
                                                   uchar* __restrict__ xfrag8,
                                                   ushort* __restrict__ ffrag) {
    __shared__ ushort xl[64][LDX];
    __shared__ ushort fl[64][LDX];
    const int b = blockIdx.z, c0 = blockIdx.y * 64, n0 = blockIdx.x * 64;
    const int t = threadIdx.x;
    const int n4 = (t & 15) * 4, cl = t >> 4;
    const size_t base = (size_t)b * C_ * N_;
    #pragma unroll
    for (int p = 0; p < 4; ++p) {
        const int cr = 16 * p + cl;
        const float4 m4 = *(const float4*)(fm + base + (size_t)(c0 + cr) * N_ + n0 + n4);
        const float4 d4 = *(const float4*)(fd + base + (size_t)(c0 + cr) * N_ + n0 + n4);
        ushort4 fo;
        fo.x = f2bf(d4.x); fo.y = f2bf(d4.y); fo.z = f2bf(d4.z); fo.w = f2bf(d4.w);
        *(ushort4*)(&fl[cr][n4]) = fo;
        ushort4 xo;
        xo.x = f2bf(m4.x + d4.x); xo.y = f2bf(m4.y + d4.y);
        xo.z = f2bf(m4.z + d4.z); xo.w = f2bf(m4.w + d4.w);
        *(ushort4*)(&xl[cr][n4]) = xo;
    }
    __syncthreads();
    const int l = t & 63, tl = t >> 6;
    {
        const int nl = 16 * tl + (l & 15);
        #pragma unroll
        for (int j = 0; j < 2; ++j) {
            const int kk = (c0 >> 5) + j;
            const int cb = 32 * j + 8 * (l >> 4);
            float f[8];
            #pragma unroll
            for (int i = 0; i < 8; ++i) f[i] = bf2f(xl[cb + i][nl]);
            int d0 = __builtin_amdgcn_cvt_pk_fp8_f32(f[0], f[1], 0, 0);
            d0 = __builtin_amdgcn_cvt_pk_fp8_f32(f[2], f[3], d0, 1);
            int d1 = __builtin_amdgcn_cvt_pk_fp8_f32(f[4], f[5], 0, 0);
            d1 = __builtin_amdgcn_cvt_pk_fp8_f32(f[6], f[7], d1, 1);
            uint* dst = (uint*)(xfrag8 + xfi8(b, (n0 >> 4) + tl, kk) + (size_t)l * 8);
            dst[0] = (uint)d0; dst[1] = (uint)d1;
        }
    }
    {
        const int row = 16 * tl + (l & 15);
        #pragma unroll
        for (int k2 = 0; k2 < 2; ++k2) {
            const int col = 32 * k2 + 8 * (l >> 4);
            const ushort4 a0 = *(const ushort4*)(&fl[row][col]);
            const ushort4 a1 = *(const ushort4*)(&fl[row][col + 4]);
            ushort* dst = ffrag + ffi(b, n0 >> 6, (c0 >> 4) + tl, k2) + l * 8;
            *(ushort4*)(dst) = a0; *(ushort4*)(dst + 4) = a1;
        }
    }
}

__global__ __launch_bounds__(512, 2) void lsum_g_kernel(const uchar* __restrict__ xfrag8,
                                                        float* __restrict__ lg) {
    __shared__ float red[8][64];
    __shared__ float dgl[64];
    const int bid = blockIdx.x;
    const int b = (bid >> 1) & 3;
    const int n0 = ((((bid >> 3) << 1) | (bid & 1))) * 64;
    const int t = threadIdx.x, lane = t & 63, w = t >> 6;
    const int l15 = lane & 15, q = lane >> 4;

    long af[4][8];
    #pragma unroll
    for (int ns = 0; ns < 4; ++ns)
        #pragma unroll
        for (int kk = 0; kk < 8; ++kk)
            af[ns][kk] = *(const long*)(xfrag8 + xfi8(b, (n0 >> 4) + ns, kk) + (size_t)lane * 8);

    float dv[4][4];
    #pragma unroll
    for (int ns = 0; ns < 4; ++ns) {
        f32x4 dacc = {0.f, 0.f, 0.f, 0.f};
        #pragma unroll
        for (int kk = 0; kk < 8; ++kk)
            dacc = mfma8(af[ns][kk], af[ns][kk], dacc);
        #pragma unroll
        for (int r = 0; r < 4; ++r)
            dv[ns][r] = __shfl(dacc[r], 20 * q + r, 64);
    }
    if (w == 0 && l15 == 0) {
        #pragma unroll
        for (int ns = 0; ns < 4; ++ns)
            #pragma unroll
            for (int r = 0; r < 4; ++r)
                dgl[16 * ns + 4 * q + r] = dv[ns][r];
    }

    long bn[8];
    #pragma unroll
    for (int kk = 0; kk < 8; ++kk)
        bn[kk] = *(const long*)(xfrag8 + xfi8(b, w, kk) + (size_t)lane * 8);

    float rs[4][4] = {};
    for (int mc = 0; mc < 32; ++mc) {
        const int mtn = (mc + 1 < 32) ? (mc + 1) * 8 + w : w;
        f32x4 a0 = {0.f,0.f,0.f,0.f}, a1 = {0.f,0.f,0.f,0.f};
        f32x4 a2 = {0.f,0.f,0.f,0.f}, a3 = {0.f,0.f,0.f,0.f};
        #pragma unroll
        for (int kk = 0; kk < 8; ++kk) {
            const long bc = bn[kk];
            a0 = mfma8(af[0][kk], bc, a0);
            a1 = mfma8(af[1][kk], bc, a1);
            a2 = mfma8(af[2][kk], bc, a2);
            a3 = mfma8(af[3][kk], bc, a3);
            bn[kk] = *(const long*)(xfrag8 + xfi8(b, mtn, kk) + (size_t)lane * 8);
        }
        #pragma unroll
        for (int r = 0; r < 4; ++r) {
            rs[0][r] += __expf(a0[r] - dv[0][r]);
            rs[1][r] += __expf(a1[r] - dv[1][r]);
            rs[2][r] += __expf(a2[r] - dv[2][r]);
            rs[3][r] += __expf(a3[r] - dv[3][r]);
        }
    }
    #pragma unroll
    for (int off = 1; off < 16; off <<= 1)
        #pragma unroll
        for (int ns = 0; ns < 4; ++ns)
            #pragma unroll
            for (int r = 0; r < 4; ++r)
                rs[ns][r] += __shfl_xor(rs[ns][r], off, 64);
    if (l15 == 0) {
        #pragma unroll
        for (int ns = 0; ns < 4; ++ns)
            #pragma unroll
            for (int r = 0; r < 4; ++r)
                red[w][16 * ns + 4 * q + r] = rs[ns][r];
    }
    __syncthreads();
    if (t < 64) {
        float s = 0.f;
        #pragma unroll
        for (int ww = 0; ww < 8; ++ww) s += red[ww][t];
        lg[b * N_ + n0 + t] = dgl[t] + __logf(s);
    }
}

__global__ __launch_bounds__(512, 2) void out_g_kernel(const uchar* __restrict__ xfrag8,
                                                       const ushort* __restrict__ ffrag,
                                                       const float* __restrict__ gg,
                                                       const float* __restrict__ fd32,
                                                       float* __restrict__ outp) {
    __shared__ ushort ET[2][64][LDE];
    const int bid = blockIdx.x;
    const int b = (bid >> 1) & 3;
    const int m0 = ((((bid >> 3) << 1) | (bid & 1))) * 64;
    const int t = threadIdx.x, lane = t & 63, w = t >> 6;
    const int l15 = lane & 15, q = lane >> 4;
    const int a = w & 3, h = w >> 2;
    const size_t fb = (size_t)b * C_ * N_;

    long bfr[2][8];
    #pragma unroll
    for (int jt = 0; jt < 2; ++jt)
        #pragma unroll
        for (int kk = 0; kk < 8; ++kk)
            bfr[jt][kk] = *(const long*)(xfrag8 + xfi8(b, (m0 >> 4) + 2 * h + jt, kk) + (size_t)lane * 8);

    f32x4 acc[2][4];
    #pragma unroll
    for (int ct = 0; ct < 2; ++ct)
        #pragma unroll
        for (int mt = 0; mt < 4; ++mt)
            acc[ct][mt] = (f32x4){0.f, 0.f, 0.f, 0.f};

    long an[8];
    #pragma unroll
    for (int kk = 0; kk < 8; ++kk)
        an[kk] = *(const long*)(xfrag8 + xfi8(b, a, kk) + (size_t)lane * 8);
    float gn[4];
    #pragma unroll
    for (int r = 0; r < 4; ++r) gn[r] = gg[b * N_ + 16 * a + 4 * q + r];

    int p = 0;
    for (int n0c = 0; n0c < N_; n0c += 64, p ^= 1) {
        const int nc = n0c >> 6;
        short8 fn[2][2];
        #pragma unroll
        for (int ct = 0; ct < 2; ++ct)
            #pragma unroll
            for (int k2 = 0; k2 < 2; ++k2)
                fn[ct][k2] = *(const short8*)(ffrag + ffi(b, nc, 2 * w + ct, k2) + lane * 8);
        float gv[4];
        #pragma unroll
        for (int r = 0; r < 4; ++r) gv[r] = gn[r];
        const int nx = (n0c + 64 < N_) ? n0c + 64 : 0;
        #pragma unroll
        for (int r = 0; r < 4; ++r) gn[r] = gg[b * N_ + nx + 16 * a + 4 * q + r];

        f32x4 s0 = {0.f, 0.f, 0.f, 0.f}, s1 = {0.f, 0.f, 0.f, 0.f};
        #pragma unroll
        for (int kk = 0; kk < 8; ++kk) {
            s0 = mfma8(an[kk], bfr[0][kk], s0);
            s1 = mfma8(an[kk], bfr[1][kk], s1);
            an[kk] = *(const long*)(xfrag8 + xfi8(b, (nx >> 4) + a, kk) + (size_t)lane * 8);
        }
        ushort4 e0, e1;
        e0.x = f2bf(__expf(s0[0] - gv[0])); e0.y = f2bf(__expf(s0[1] - gv[1]));
        e0.z = f2bf(__expf(s0[2] - gv[2])); e0.w = f2bf(__expf(s0[3] - gv[3]));
        e1.x = f2bf(__expf(s1[0] - gv[0])); e1.y = f2bf(__expf(s1[1] - gv[1]));
        e1.z = f2bf(__expf(s1[2] - gv[2])); e1.w = f2bf(__expf(s1[3] - gv[3]));
        *(ushort4*)(&ET[p][32 * h + l15][16 * a + 4 * q])      = e0;
        *(ushort4*)(&ET[p][32 * h + 16 + l15][16 * a + 4 * q]) = e1;

        asm volatile("s_waitcnt lgkmcnt(0)\n\ts_barrier" ::: "memory");

        #pragma unroll
        for (int k2 = 0; k2 < 2; ++k2) {
            #pragma unroll
            for (int mt = 0; mt < 4; ++mt) {
                const short8 be = *(const short8*)(&ET[p][16 * mt + l15][32 * k2 + 8 * q]);
                acc[0][mt] = mfma16(fn[0][k2], be, acc[0][mt]);
                acc[1][mt] = mfma16(fn[1][k2], be, acc[1][mt]);
            }
        }
    }
    #pragma unroll
    for (int ct = 0; ct < 2; ++ct)
        #pragma unroll
        for (int mt = 0; mt < 4; ++mt)
            #pragma unroll
            for (int r = 0; r < 4; ++r) {
                const int c = 32 * w + 16 * ct + 4 * q + r;
                const int m = m0 + 16 * mt + l15;
                const size_t o = fb + (size_t)c * N_ + m;
                outp[o] = acc[ct][mt][r] + fd32[o];
            }
}

// ---------------------------------------------------------------------------
extern "C" void kernel_launch(void* const* d_in, const int* in_sizes, int n_in,
                              void* d_out, int out_size, void* d_ws, size_t ws_size,
                              hipStream_t stream) {
    const float* fm = (const float*)d_in[0];
    const float* fd = (const float*)d_in[1];
    float* outp = (float*)d_out;

    const size_t xb_elts = (size_t)B_ * N_ * C_;                 // 4.19M
    const size_t e_bytes = (size_t)B_ * N_ * N_;                 // 67.1 MB
    const size_t z_bytes = (size_t)B_ * 64 * 256;                // 64 KB
    const size_t f_bytes = (size_t)B_ * N_ * 4;                  // 64 KB each
    const size_t need_e  = xb_elts + e_bytes + z_bytes + 3 * f_bytes;
    const size_t need_g  = xb_elts * 3 + f_bytes;

    uchar* xfrag8 = (uchar*)d_ws;

    if (ws_size >= need_e) {
        uchar* E8     = xfrag8 + xb_elts;
        uchar* zmask  = E8 + e_bytes;
        float* rsbase = (float*)(zmask + z_bytes);
        float* rsadd  = rsbase + (size_t)B_ * N_;
        float* dgall  = rsadd + (size_t)B_ * N_;
        prep_x_kernel<<<dim3(N_ / 64, C_ / 64, B_), 256, 0, stream>>>(fm, fd, xfrag8);
        dg_kernel<<<dim3(256), 256, 0, stream>>>(xfrag8, dgall, rsadd, zmask);
        fused_kernel<<<dim3(256), 512, 0, stream>>>(xfrag8, dgall, E8, zmask, rsbase, rsadd, fd, outp);
        out_fix_kernel<<<dim3(256), 512, 0, stream>>>(E8, zmask, rsbase, rsadd, dgall, xfrag8, fd, outp);
    } else if (ws_size >= need_g) {
        ushort* ffrag = (ushort*)(xfrag8 + xb_elts);
        float*  lg    = (float*)(xfrag8 + xb_elts * 3);
        prep_kernel<<<dim3(N_ / 64, C_ / 64, B_), 256, 0, stream>>>(fm, fd, xfrag8, ffrag);
        lsum_g_kernel<<<dim3(256), 512, 0, stream>>>(xfrag8, lg);
        out_g_kernel<<<dim3(256), 512, 0, stream>>>(xfrag8, ffrag, lg, fd, outp);
    }
}